// Round 14
// baseline (275.398 us; speedup 1.0000x reference)
//
#include <hip/hip_runtime.h>

typedef unsigned short u16;
typedef unsigned int   u32;
using bf16x8 = __attribute__((ext_vector_type(8))) short;
using f32x4  = __attribute__((ext_vector_type(4))) float;
using f32x16 = __attribute__((ext_vector_type(16))) float;
using u32x4  = __attribute__((ext_vector_type(4))) u32;

static constexpr int Bb = 8, Ll = 1024, Cc = 1024, Hh = 16, Dd = 64;
static constexpr int Mrows = Bb * Ll;   // 8192
static constexpr int N3    = 3 * Cc;    // 3072
// exp(S/8) = 2^(S * 0.125*log2(e)); fold into q at the QKV epilogue
static constexpr float QSCALE = 0.125f * 1.44269504088896f;

__device__ __forceinline__ u16 f2b(float f) {  // fp32 -> bf16 RNE
    u32 u = __builtin_bit_cast(u32, f);
    u += 0x7FFFu + ((u >> 16) & 1u);
    return (u16)(u >> 16);
}
__device__ __forceinline__ float b2f(u16 u) {
    return __builtin_bit_cast(float, (u32)u << 16);
}
__device__ __forceinline__ u32 pack2bf(float a, float b) {
    return (u32)f2b(a) | ((u32)f2b(b) << 16);
}
// async global->LDS, 16B/lane; LDS dest is wave-uniform base (lane*16 HW-added)
__device__ __forceinline__ void gload16(const u16* g, u16* l) {
    __builtin_amdgcn_global_load_lds(
        (const __attribute__((address_space(1))) void*)g,
        (__attribute__((address_space(3))) void*)l, 16, 0, 0);
}

// ---------------- fp32 -> bf16 convert, 16 elems/thread ----------------
__global__ void k_f32_to_bf16(const float* __restrict__ in, u16* __restrict__ out, int n16) {
    int idx = blockIdx.x * blockDim.x + threadIdx.x;
    if (idx >= n16) return;
    #pragma unroll
    for (int h = 0; h < 2; ++h) {
        f32x4 v0 = *((const f32x4*)in + idx * 4 + h * 2);
        f32x4 v1 = *((const f32x4*)in + idx * 4 + h * 2 + 1);
        u32x4 o;
        o[0] = pack2bf(v0[0], v0[1]);
        o[1] = pack2bf(v0[2], v0[3]);
        o[2] = pack2bf(v1[0], v1[1]);
        o[3] = pack2bf(v1[2], v1[3]);
        *((u32x4*)out + idx * 2 + h) = o;
    }
}

// ---- fused weight transpose+convert: W_qkv (1024x3072) and W_proj (1024x1024) ----
__global__ void k_transpose_w(const float* __restrict__ Wqkv, u16* __restrict__ WqkvT,
                              const float* __restrict__ Wproj, u16* __restrict__ WprojT) {
    __shared__ float tile[32][33];
    int bx = blockIdx.x;
    const float* in; u16* out; int Cn;
    if (bx < 96) { in = Wqkv;  out = WqkvT;  Cn = N3; }
    else         { in = Wproj; out = WprojT; Cn = Cc; bx -= 96; }
    const int R = Cc;   // 1024 rows for both
    int tx = threadIdx.x, ty = threadIdx.y;
    int c = bx * 32 + tx;
    int rbase = blockIdx.y * 32;
    #pragma unroll
    for (int rr = 0; rr < 4; ++rr)
        tile[ty + rr * 8][tx] = in[(size_t)(rbase + ty + rr * 8) * Cn + c];
    __syncthreads();
    int ro = bx * 32 + ty;
    #pragma unroll
    for (int rr = 0; rr < 4; ++rr)
        out[(size_t)(ro + rr * 8) * R + rbase + tx] = f2b(tile[tx][ty + rr * 8]);
}

// --- batched bf16 transpose + zinv row-scale: v (bh,L,D) -> vt (bh,D,L)*zinv[l] ---
__global__ void k_transpose_scale_bf16(const u16* __restrict__ in, const float* __restrict__ zinv,
                                       u16* __restrict__ out, int R, int Cn) {
    __shared__ u16 tile[32][33];
    int bh = blockIdx.z;
    size_t base = (size_t)bh * R * Cn;
    int tx = threadIdx.x, ty = threadIdx.y;
    int c = blockIdx.x * 32 + tx;
    int rbase = blockIdx.y * 32;
    #pragma unroll
    for (int rr = 0; rr < 4; ++rr)
        tile[ty + rr * 8][tx] = in[base + (size_t)(rbase + ty + rr * 8) * Cn + c];
    __syncthreads();
    float zv = zinv[(size_t)bh * R + rbase + tx];   // L index is rbase+tx for all rr
    int ro = blockIdx.x * 32 + ty;
    #pragma unroll
    for (int rr = 0; rr < 4; ++rr)
        out[base + (size_t)(ro + rr * 8) * R + rbase + tx] = f2b(b2f(tile[tx][ty + rr * 8]) * zv);
}

// ======== QKV GEMM v3: 32x32x16 MFMA, 128^2 tile, BK=64, dbuf, 2 blocks/CU ========
// R10-proven (took QKV out of the top-5). DO NOT PERTURB.
__global__ __launch_bounds__(256, 2)
void k_gemm_qkv32(const u16* __restrict__ A, const u16* __restrict__ Bt,
                  const float* __restrict__ bias,
                  u16* __restrict__ qo, u16* __restrict__ ko, u16* __restrict__ vo)
{
    const int K = Cc;            // 1024
    const int NT = K / 64;       // 16 K-tiles
    __shared__ u16 As[2][128 * 64];
    __shared__ u16 Bs[2][128 * 64];
    const int tid = threadIdx.x;
    const int wid = tid >> 6, lane = tid & 63;
    const int l31 = lane & 31, lhi = lane >> 5, l7 = lane & 7;
    const int wr = wid >> 1, wc = wid & 1;       // 2x2 waves, 64x64 each
    const int nwg = gridDim.x * gridDim.y;       // 1536, %8==0
    const int flat = blockIdx.y * gridDim.x + blockIdx.x;
    const int swz = (flat & 7) * (nwg >> 3) + (flat >> 3);
    const int bx = swz % gridDim.x, by = swz / gridDim.x;
    const int row0 = by * 128, col0 = bx * 128;

    const int srow = tid >> 3;
    const int schunk = (tid & 7) ^ (srow & 7);
    const u16* gA = A  + (size_t)(row0 + srow) * K + schunk * 8;
    const u16* gB = Bt + (size_t)(col0 + srow) * K + schunk * 8;

#define STG(buf, t) do { \
    const u16* ga_ = gA + (size_t)(t) * 64; \
    const u16* gb_ = gB + (size_t)(t) * 64; \
    u16* la_ = &As[buf][wid * 512]; \
    u16* lb_ = &Bs[buf][wid * 512]; \
    gload16(ga_,                  la_); \
    gload16(ga_ + (size_t)32 * K, la_ + 2048); \
    gload16(ga_ + (size_t)64 * K, la_ + 4096); \
    gload16(ga_ + (size_t)96 * K, la_ + 6144); \
    gload16(gb_,                  lb_); \
    gload16(gb_ + (size_t)32 * K, lb_ + 2048); \
    gload16(gb_ + (size_t)64 * K, lb_ + 4096); \
    gload16(gb_ + (size_t)96 * K, lb_ + 6144); \
} while (0)

    const int coff0 = (((0 + lhi) ^ l7) << 3);
    const int coff1 = (((2 + lhi) ^ l7) << 3);
    const int coff2 = (((4 + lhi) ^ l7) << 3);
    const int coff3 = (((6 + lhi) ^ l7) << 3);
    const int coff[4] = { coff0, coff1, coff2, coff3 };

    f32x16 acc[2][2] = {};

    STG(0, 0);
    STG(1, 1);
    asm volatile("s_waitcnt vmcnt(8)" ::: "memory");   // tile0's 8 loads landed
    __builtin_amdgcn_s_barrier();
    __builtin_amdgcn_sched_barrier(0);

    for (int t = 0; t < NT; ++t) {
        const u16* cA = &As[t & 1][0];
        const u16* cB = &Bs[t & 1][0];
        // ---- phase 0: A frags (held) + B tn=0, 8 MFMA ----
        bf16x8 af[2][4], bf0[4];
        #pragma unroll
        for (int tm = 0; tm < 2; ++tm)
            #pragma unroll
            for (int kc = 0; kc < 4; ++kc)
                af[tm][kc] = *(const bf16x8*)&cA[(wr * 64 + tm * 32 + l31) * 64 + coff[kc]];
        #pragma unroll
        for (int kc = 0; kc < 4; ++kc)
            bf0[kc] = *(const bf16x8*)&cB[(wc * 64 + l31) * 64 + coff[kc]];
        __builtin_amdgcn_s_setprio(1);
        #pragma unroll
        for (int tm = 0; tm < 2; ++tm)
            #pragma unroll
            for (int kc = 0; kc < 4; ++kc)
                acc[tm][0] = __builtin_amdgcn_mfma_f32_32x32x16_bf16(
                    af[tm][kc], bf0[kc], acc[tm][0], 0, 0, 0);
        __builtin_amdgcn_s_setprio(0);
        __builtin_amdgcn_s_barrier();
        // ---- phase 1: B tn=1, 8 MFMA ----
        bf16x8 bf1[4];
        #pragma unroll
        for (int kc = 0; kc < 4; ++kc)
            bf1[kc] = *(const bf16x8*)&cB[(wc * 64 + 32 + l31) * 64 + coff[kc]];
        __builtin_amdgcn_s_setprio(1);
        #pragma unroll
        for (int tm = 0; tm < 2; ++tm)
            #pragma unroll
            for (int kc = 0; kc < 4; ++kc)
                acc[tm][1] = __builtin_amdgcn_mfma_f32_32x32x16_bf16(
                    af[tm][kc], bf1[kc], acc[tm][1], 0, 0, 0);
        __builtin_amdgcn_s_setprio(0);
        __builtin_amdgcn_s_barrier();          // all waves done reading buf[t&1]
        __builtin_amdgcn_sched_barrier(0);
        if (t + 2 < NT) STG(t & 1, t + 2);
        if (t + 1 < NT) {
            if (t + 2 < NT) { asm volatile("s_waitcnt vmcnt(8)" ::: "memory"); }
            else            { asm volatile("s_waitcnt vmcnt(0)" ::: "memory"); }
            __builtin_amdgcn_s_barrier();      // all waves' t+1 landed
            __builtin_amdgcn_sched_barrier(0);
        }
    }
#undef STG

    // epilogue: q/k/v scatter to (B,H,L,D); 32x32 C/D layout
    #pragma unroll
    for (int tm = 0; tm < 2; ++tm) {
        #pragma unroll
        for (int tn = 0; tn < 2; ++tn) {
            int cg = col0 + wc * 64 + tn * 32 + l31;
            float bv = bias[cg];
            int which = cg >> 10;         // 0=q 1=k 2=v
            float sc = (which == 0) ? QSCALE : 1.0f;
            int cc2 = cg & 1023;
            int h = cc2 >> 6, dd = cc2 & 63;
            int rbase = row0 + wr * 64 + tm * 32 + 4 * lhi;
            #pragma unroll
            for (int g = 0; g < 4; ++g) {
                #pragma unroll
                for (int r = 0; r < 4; ++r) {
                    int rg = rbase + 8 * g + r;
                    int bidx = rg >> 10, ll2 = rg & 1023;
                    size_t o = ((size_t)(bidx * Hh + h) * Ll + ll2) * Dd + dd;
                    u16 val = f2b((acc[tm][tn][g * 4 + r] + bv) * sc);
                    if (which == 0) qo[o] = val;
                    else if (which == 1) ko[o] = val;
                    else vo[o] = val;
                }
            }
        }
    }
}

// ---- proj GEMM: 2-phase dbuf + global_load_lds + source-side XOR swizzle ----
__global__ __launch_bounds__(256)
void k_gemm_proj(const u16* __restrict__ A, const u16* __restrict__ Bt,
                 const float* __restrict__ bias, float* __restrict__ outf)
{
    const int N = Cc, K = Cc;
    __shared__ u16 As[2][128 * 32];
    __shared__ u16 Bs[2][128 * 32];
    const int tid = threadIdx.x;
    const int wid = tid >> 6, lane = tid & 63;
    const int lr = lane & 15, lg = lane >> 4;
    const int wr = wid >> 1, wc = wid & 1;
    const int nwg = gridDim.x * gridDim.y;
    const int flat = blockIdx.y * gridDim.x + blockIdx.x;
    const int swz = (flat & 7) * (nwg >> 3) + (flat >> 3);
    const int bx = swz % gridDim.x, by = swz / gridDim.x;
    const int row0 = by * 128, col0 = bx * 128;

    const int srow = wid * 32 + (lane >> 2);
    const int schk = (lane & 3) ^ (srow & 3);
    const u16* aP = A  + (size_t)(row0 + srow) * K + schk * 8;
    const u16* bP = Bt + (size_t)(col0 + srow) * K + schk * 8;
    const size_t r16 = (size_t)16 * K;
    u16* aL0 = &As[0][wid * 32 * 32]; u16* aL0b = aL0 + 16 * 32;
    u16* bL0 = &Bs[0][wid * 32 * 32]; u16* bL0b = bL0 + 16 * 32;
    u16* aL1 = &As[1][wid * 32 * 32]; u16* aL1b = aL1 + 16 * 32;
    u16* bL1 = &Bs[1][wid * 32 * 32]; u16* bL1b = bL1 + 16 * 32;

    f32x4 acc[4][4] = {};

#define STAGE0(kk) { gload16(aP + (kk), aL0); gload16(aP + r16 + (kk), aL0b); \
                     gload16(bP + (kk), bL0); gload16(bP + r16 + (kk), bL0b); }
#define STAGE1(kk) { gload16(aP + (kk), aL1); gload16(aP + r16 + (kk), aL1b); \
                     gload16(bP + (kk), bL1); gload16(bP + r16 + (kk), bL1b); }
#define COMPUTE(bufi) { \
        bf16x8 af[4], bfv[4]; \
        _Pragma("unroll") \
        for (int m = 0; m < 4; ++m) { int rw = wr * 64 + m * 16 + lr; \
            af[m] = *(const bf16x8*)&As[bufi][rw * 32 + ((lg ^ (rw & 3)) * 8)]; } \
        _Pragma("unroll") \
        for (int n = 0; n < 4; ++n) { int rw = wc * 64 + n * 16 + lr; \
            bfv[n] = *(const bf16x8*)&Bs[bufi][rw * 32 + ((lg ^ (rw & 3)) * 8)]; } \
        _Pragma("unroll") \
        for (int m = 0; m < 4; ++m) \
            _Pragma("unroll") \
            for (int n = 0; n < 4; ++n) \
                acc[m][n] = __builtin_amdgcn_mfma_f32_16x16x32_bf16(af[m], bfv[n], acc[m][n], 0, 0, 0); }

    STAGE0(0);
    __syncthreads();
    for (int k0 = 0; k0 < K; k0 += 64) {
        if (k0 + 32 < K) STAGE1(k0 + 32);
        COMPUTE(0);
        __syncthreads();
        if (k0 + 64 < K) STAGE0(k0 + 64);
        COMPUTE(1);
        __syncthreads();
    }
#undef STAGE0
#undef STAGE1
#undef COMPUTE

    #pragma unroll
    for (int m = 0; m < 4; ++m) {
        int rb2 = row0 + wr * 64 + m * 16 + lg * 4;
        #pragma unroll
        for (int n = 0; n < 4; ++n) {
            int cg = col0 + wc * 64 + n * 16 + lr;
            float bv = bias[cg];
            #pragma unroll
            for (int r = 0; r < 4; ++r)
                outf[(size_t)(rb2 + r) * N + cg] = acc[m][n][r] + bv;
        }
    }
}

// ---------------- attention pass 1: column sums ----------------
__global__ __launch_bounds__(256)
void k_attn_colsum(const u16* __restrict__ Q, const u16* __restrict__ Kb,
                   float* __restrict__ zinv)
{
    const int tid = threadIdx.x;
    const int wid = tid >> 6, lane = tid & 63;
    const int lr = lane & 15, lg = lane >> 4;
    const int fid = blockIdx.x;
    const int xcd = fid & 7, n = fid >> 3;
    const int pr = n & 3;
    const int bh = (xcd << 4) | (n >> 2);
    const u16* Qp = Q  + (size_t)bh * Ll * Dd;
    const u16* Kp = Kb + (size_t)bh * Ll * Dd;
    const bool dmask[4] = { lg * 4 + 0 >= lr, lg * 4 + 1 >= lr,
                            lg * 4 + 2 >= lr, lg * 4 + 3 >= lr };

    #pragma unroll
    for (int t = 0; t < 2; ++t) {
        const int xt = t ? (7 - pr) : pr;
        const int jw = xt * 128 + wid * 32;
        bf16x8 kb[2][2];
        #pragma unroll
        for (int g = 0; g < 2; ++g) {
            kb[g][0] = *(const bf16x8*)&Kp[(jw + g * 16 + lr) * Dd + lg * 8];
            kb[g][1] = *(const bf16x8*)&Kp[(jw + g * 16 + lr) * Dd + 32 + lg * 8];
        }
        float z0 = 0.f, z1 = 0.f;
        {   // ib = jw: g0 diag-masked; g1 entirely above diagonal (skip)
            bf16x8 qa0 = *(const bf16x8*)&Qp[(jw + lr) * Dd + lg * 8];
            bf16x8 qa1 = *(const bf16x8*)&Qp[(jw + lr) * Dd + 32 + lg * 8];
            f32x4 s = {0.f, 0.f, 0.f, 0.f};
            s = __builtin_amdgcn_mfma_f32_16x16x32_bf16(qa0, kb[0][0], s, 0, 0, 0);
            s = __builtin_amdgcn_mfma_f32_16x16x32_bf16(qa1, kb[0][1], s, 0, 0, 0);
            #pragma unroll
            for (int r = 0; r < 4; ++r) z0 += dmask[r] ? exp2f(s[r]) : 0.f;
        }
        {   // ib = jw+16: g0 unmasked, g1 diag-masked
            bf16x8 qa0 = *(const bf16x8*)&Qp[(jw + 16 + lr) * Dd + lg * 8];
            bf16x8 qa1 = *(const bf16x8*)&Qp[(jw + 16 + lr) * Dd + 32 + lg * 8];
            f32x4 s0 = {0.f, 0.f, 0.f, 0.f}, s1 = {0.f, 0.f, 0.f, 0.f};
            s0 = __builtin_amdgcn_mfma_f32_16x16x32_bf16(qa0, kb[0][0], s0, 0, 0, 0);
            s0 = __builtin_amdgcn_mfma_f32_16x16x32_bf16(qa1, kb[0][1], s0, 0, 0, 0);
            s1 = __builtin_amdgcn_mfma_f32_16x16x32_bf16(qa0, kb[1][0], s1, 0, 0, 0);
            s1 = __builtin_amdgcn_mfma_f32_16x16x32_bf16(qa1, kb[1][1], s1, 0, 0, 0);
            #pragma unroll
            for (int r = 0; r < 4; ++r) {
                z0 += exp2f(s0[r]);
                z1 += dmask[r] ? exp2f(s1[r]) : 0.f;
            }
        }
        for (int ib = jw + 32; ib < Ll; ib += 16) {
            bf16x8 qa0 = *(const bf16x8*)&Qp[(ib + lr) * Dd + lg * 8];
            bf16x8 qa1 = *(const bf16x8*)&Qp[(ib + lr) * Dd + 32 + lg * 8];
            f32x4 s0 = {0.f, 0.f, 0.f, 0.f}, s1 = {0.f, 0.f, 0.f, 0.f};
            s0 = __builtin_amdgcn_mfma_f32_16x16x32_bf16(qa0, kb[0][0], s0, 0, 0, 0);
            s0 = __builtin_amdgcn_mfma_f32_16x16x32_bf16(qa1, kb[0][1], s0, 0, 0, 0);
            s1 = __builtin_amdgcn_mfma_f32_16x16x32_bf16(qa0, kb[1][0], s1, 0, 0, 0);
            s1 = __builtin_amdgcn_mfma_f32_16x16x32_bf16(qa1, kb[1][1], s1, 0, 0, 0);
            #pragma unroll
            for (int r = 0; r < 4; ++r) { z0 += exp2f(s0[r]); z1 += exp2f(s1[r]); }
        }
        z0 += __shfl_xor(z0, 16); z0 += __shfl_xor(z0, 32);
        z1 += __shfl_xor(z1, 16); z1 += __shfl_xor(z1, 32);
        if (lg == 0) {
            zinv[(size_t)bh * Ll + jw + lr]      = 1.f / z0;
            zinv[(size_t)bh * Ll + jw + 16 + lr] = 1.f / z1;
        }
    }
}

// ---------------- attention pass 2: Y = exp(S') @ V'  (shuffle P, no LDS) ----------------
// R13 post-mortem: the ds_write->lgkmcnt(0)->ds_read bounce is the serial chain
// AND the TU-fragile scheduling point. Replaced with in-register redistribution:
// producer lane (lr,lg) holds P[j=j0+16cs+4lg+r][i=lr] packed in uint2 w_cs;
// PV A-frag needs lane (lr,lg) = P[i=lr][j=j0+8lg+e]. i matches; j moves across
// lane-groups only: pa0 u32s = {w[cs].x,.y from lane lr+32(lg&1), same +16},
// cs=lg>>1 (pa1: cs=2+(lg>>1)). Register index can't be lane-dependent (rule
// #20), so shuffle both candidates (16 shfl) and cndmask-select by lg&2.
__global__ __launch_bounds__(256)
void k_attn_pv(const u16* __restrict__ Q, const u16* __restrict__ Kb,
               const u16* __restrict__ Vt, u16* __restrict__ Y)
{
    const int tid = threadIdx.x;
    const int wid = tid >> 6, lane = tid & 63;
    const int lr = lane & 15, lg = lane >> 4;
    const int fid = blockIdx.x;
    const int xcd = fid & 7, n = fid >> 3;
    const int xtile = n & 7;
    const int bh = (xcd << 4) | (n >> 3);
    const int bidx = bh >> 4, h = bh & 15;
    const u16* Qp = Q  + (size_t)bh * Ll * Dd;
    const u16* Kp = Kb + (size_t)bh * Ll * Dd;
    const u16* Vp = Vt + (size_t)bh * Ll * Dd;     // (Dd, Ll) layout, zinv-scaled
    const int src0 = lr + 32 * (lg & 1);           // producer lane lg'=2(lg&1)
    const int src1 = src0 + 16;                    // producer lane lg'=2(lg&1)+1
    const bool selHi = (lg & 2) != 0;              // cs select: w1/w3 vs w0/w2

    #pragma unroll
    for (int t = 0; t < 2; ++t) {
        const int xt = t ? (15 - xtile) : xtile;
        const int iw = xt * 64 + wid * 16;
        // Q is the B-operand: lane (lr,lg) needs Q[i=iw+lr][d=8lg+e]
        bf16x8 qa0 = *(const bf16x8*)&Qp[(iw + lr) * Dd + lg * 8];
        bf16x8 qa1 = *(const bf16x8*)&Qp[(iw + lr) * Dd + 32 + lg * 8];
        f32x4 yacc[4] = {};

        for (int j0 = 0; j0 <= iw + 15; j0 += 64) {
            // V loads first (consumed last -> latency hides under S phase)
            bf16x8 vb[4][2];
            #pragma unroll
            for (int ns = 0; ns < 4; ++ns) {
                vb[ns][0] = *(const bf16x8*)&Vp[(size_t)(ns * 16 + lr) * Ll + j0 + lg * 8];
                vb[ns][1] = *(const bf16x8*)&Vp[(size_t)(ns * 16 + lr) * Ll + j0 + 32 + lg * 8];
            }
            // ---- S phase: 4 cs blocks, results kept in named uint2 regs ----
            uint2 w0, w1, w2, w3;
            #pragma unroll
            for (int cs = 0; cs < 4; ++cs) {
                int jb = j0 + cs * 16;
                bf16x8 kb0 = *(const bf16x8*)&Kp[(jb + lr) * Dd + lg * 8];
                bf16x8 kb1 = *(const bf16x8*)&Kp[(jb + lr) * Dd + 32 + lg * 8];
                f32x4 s = {0.f, 0.f, 0.f, 0.f};
                s = __builtin_amdgcn_mfma_f32_16x16x32_bf16(kb0, qa0, s, 0, 0, 0);
                s = __builtin_amdgcn_mfma_f32_16x16x32_bf16(kb1, qa1, s, 0, 0, 0);
                // lane holds S^T[j=jb+4lg+r][i=iw+lr]
                float p[4];
                if (jb + 15 <= iw) {          // fully unmasked sub-tile
                    #pragma unroll
                    for (int r = 0; r < 4; ++r) p[r] = exp2f(s[r]);
                } else {
                    int ig = iw + lr;
                    #pragma unroll
                    for (int r = 0; r < 4; ++r)
                        p[r] = (jb + 4 * lg + r <= ig) ? exp2f(s[r]) : 0.f;
                }
                uint2 w;
                w.x = pack2bf(p[0], p[1]);
                w.y = pack2bf(p[2], p[3]);
                if (cs == 0) w0 = w; else if (cs == 1) w1 = w;
                else if (cs == 2) w2 = w; else w3 = w;
            }
            // ---- redistribute P across lane-groups: 16 shfl + 8 selects ----
            u32 a00 = (u32)__shfl((int)w0.x, src0), a01 = (u32)__shfl((int)w0.y, src0);
            u32 a02 = (u32)__shfl((int)w0.x, src1), a03 = (u32)__shfl((int)w0.y, src1);
            u32 a10 = (u32)__shfl((int)w1.x, src0), a11 = (u32)__shfl((int)w1.y, src0);
            u32 a12 = (u32)__shfl((int)w1.x, src1), a13 = (u32)__shfl((int)w1.y, src1);
            u32 a20 = (u32)__shfl((int)w2.x, src0), a21 = (u32)__shfl((int)w2.y, src0);
            u32 a22 = (u32)__shfl((int)w2.x, src1), a23 = (u32)__shfl((int)w2.y, src1);
            u32 a30 = (u32)__shfl((int)w3.x, src0), a31 = (u32)__shfl((int)w3.y, src0);
            u32 a32 = (u32)__shfl((int)w3.x, src1), a33 = (u32)__shfl((int)w3.y, src1);
            u32x4 pa0u, pa1u;
            pa0u[0] = selHi ? a10 : a00;  pa0u[1] = selHi ? a11 : a01;
            pa0u[2] = selHi ? a12 : a02;  pa0u[3] = selHi ? a13 : a03;
            pa1u[0] = selHi ? a30 : a20;  pa1u[1] = selHi ? a31 : a21;
            pa1u[2] = selHi ? a32 : a22;  pa1u[3] = selHi ? a33 : a23;
            bf16x8 pa0 = __builtin_bit_cast(bf16x8, pa0u);   // k = j0..j0+31
            bf16x8 pa1 = __builtin_bit_cast(bf16x8, pa1u);   // k = j0+32..+63
            // ---- PV phase: V already in registers ----
            #pragma unroll
            for (int ns = 0; ns < 4; ++ns) {
                yacc[ns] = __builtin_amdgcn_mfma_f32_16x16x32_bf16(pa0, vb[ns][0], yacc[ns], 0, 0, 0);
                yacc[ns] = __builtin_amdgcn_mfma_f32_16x16x32_bf16(pa1, vb[ns][1], yacc[ns], 0, 0, 0);
            }
        }
        #pragma unroll
        for (int ns = 0; ns < 4; ++ns)
            #pragma unroll
            for (int r = 0; r < 4; ++r) {
                int l2 = iw + lg * 4 + r;
                Y[((size_t)bidx * Ll + l2) * Cc + h * Dd + ns * 16 + lr] = f2b(yacc[ns][r]);
            }
    }
}

extern "C" void kernel_launch(void* const* d_in, const int* in_sizes, int n_in,
                              void* d_out, int out_size, void* d_ws, size_t ws_size,
                              hipStream_t stream)
{
    const float* x     = (const float*)d_in[0];
    const float* Wqkv  = (const float*)d_in[1];
    const float* bqkv  = (const float*)d_in[2];
    const float* Wproj = (const float*)d_in[3];
    const float* bproj = (const float*)d_in[4];
    float* out = (float*)d_out;

    char* ws = (char*)d_ws;
    u16* xb     = (u16*)(ws + 0);            // x as bf16, 8192x1024         (16 MB)
    u16* WqkvT  = (u16*)(ws + 16777216);     // W_qkv^T bf16, 3072x1024      (6 MB)
    u16* WprojT = (u16*)(ws + 23068672);     // W_proj^T bf16, 1024x1024     (2 MB)
    u16* q      = (u16*)(ws + 25165824);     // (B,H,L,D) bf16, pre-scaled   (16 MB)
    u16* k      = (u16*)(ws + 41943040);     // (B,H,L,D) bf16               (16 MB)
    u16* v      = (u16*)(ws + 58720256);     // (B,H,L,D) bf16; reused as Y  (16 MB)
    u16* vt     = (u16*)(ws + 75497472);     // (B,H,D,L) bf16, zinv-scaled  (16 MB)
    float* zinv = (float*)(ws + 92274688);   // (B*H*L) fp32                 (0.5 MB)

    k_f32_to_bf16<<<dim3(2048), dim3(256), 0, stream>>>(x, xb, Mrows * Cc / 16);
    k_transpose_w<<<dim3(128, 32), dim3(32, 8), 0, stream>>>(Wqkv, WqkvT, Wproj, WprojT);
    k_gemm_qkv32<<<dim3(N3 / 128, Mrows / 128), dim3(256), 0, stream>>>(
        xb, WqkvT, bqkv, q, k, v);
    k_attn_colsum<<<dim3(512), dim3(256), 0, stream>>>(q, k, zinv);
    k_transpose_scale_bf16<<<dim3(2, 32, Bb * Hh), dim3(32, 8), 0, stream>>>(v, zinv, vt, Ll, Dd);
    k_attn_pv<<<dim3(1024), dim3(256), 0, stream>>>(q, k, vt, v);
    k_gemm_proj<<<dim3(Cc / 128, Mrows / 128), dim3(256), 0, stream>>>(
        v, WprojT, bproj, out);
}

// Round 15
// 274.868 us; speedup vs baseline: 1.0019x; 1.0019x over previous
//
#include <hip/hip_runtime.h>

typedef unsigned short u16;
typedef unsigned int   u32;
using bf16x8 = __attribute__((ext_vector_type(8))) short;
using f32x4  = __attribute__((ext_vector_type(4))) float;
using f32x16 = __attribute__((ext_vector_type(16))) float;
using u32x4  = __attribute__((ext_vector_type(4))) u32;

static constexpr int Bb = 8, Ll = 1024, Cc = 1024, Hh = 16, Dd = 64;
static constexpr int Mrows = Bb * Ll;   // 8192
static constexpr int N3    = 3 * Cc;    // 3072
// exp(S/8) = 2^(S * 0.125*log2(e)); fold into q at the QKV epilogue
static constexpr float QSCALE = 0.125f * 1.44269504088896f;

__device__ __forceinline__ u16 f2b(float f) {  // fp32 -> bf16 RNE
    u32 u = __builtin_bit_cast(u32, f);
    u += 0x7FFFu + ((u >> 16) & 1u);
    return (u16)(u >> 16);
}
__device__ __forceinline__ float b2f(u16 u) {
    return __builtin_bit_cast(float, (u32)u << 16);
}
__device__ __forceinline__ u32 pack2bf(float a, float b) {
    return (u32)f2b(a) | ((u32)f2b(b) << 16);
}
// async global->LDS, 16B/lane; LDS dest is wave-uniform base (lane*16 HW-added)
__device__ __forceinline__ void gload16(const u16* g, u16* l) {
    __builtin_amdgcn_global_load_lds(
        (const __attribute__((address_space(1))) void*)g,
        (__attribute__((address_space(3))) void*)l, 16, 0, 0);
}

// ---------------- fp32 -> bf16 convert, 16 elems/thread ----------------
__global__ void k_f32_to_bf16(const float* __restrict__ in, u16* __restrict__ out, int n16) {
    int idx = blockIdx.x * blockDim.x + threadIdx.x;
    if (idx >= n16) return;
    #pragma unroll
    for (int h = 0; h < 2; ++h) {
        f32x4 v0 = *((const f32x4*)in + idx * 4 + h * 2);
        f32x4 v1 = *((const f32x4*)in + idx * 4 + h * 2 + 1);
        u32x4 o;
        o[0] = pack2bf(v0[0], v0[1]);
        o[1] = pack2bf(v0[2], v0[3]);
        o[2] = pack2bf(v1[0], v1[1]);
        o[3] = pack2bf(v1[2], v1[3]);
        *((u32x4*)out + idx * 2 + h) = o;
    }
}

// ---- fused weight transpose+convert: W_qkv (1024x3072) and W_proj (1024x1024) ----
__global__ void k_transpose_w(const float* __restrict__ Wqkv, u16* __restrict__ WqkvT,
                              const float* __restrict__ Wproj, u16* __restrict__ WprojT) {
    __shared__ float tile[32][33];
    int bx = blockIdx.x;
    const float* in; u16* out; int Cn;
    if (bx < 96) { in = Wqkv;  out = WqkvT;  Cn = N3; }
    else         { in = Wproj; out = WprojT; Cn = Cc; bx -= 96; }
    const int R = Cc;   // 1024 rows for both
    int tx = threadIdx.x, ty = threadIdx.y;
    int c = bx * 32 + tx;
    int rbase = blockIdx.y * 32;
    #pragma unroll
    for (int rr = 0; rr < 4; ++rr)
        tile[ty + rr * 8][tx] = in[(size_t)(rbase + ty + rr * 8) * Cn + c];
    __syncthreads();
    int ro = bx * 32 + ty;
    #pragma unroll
    for (int rr = 0; rr < 4; ++rr)
        out[(size_t)(ro + rr * 8) * R + rbase + tx] = f2b(tile[tx][ty + rr * 8]);
}

// --- batched bf16 transpose + zinv row-scale: v (bh,L,D) -> vt (bh,D,L)*zinv[l] ---
__global__ void k_transpose_scale_bf16(const u16* __restrict__ in, const float* __restrict__ zinv,
                                       u16* __restrict__ out, int R, int Cn) {
    __shared__ u16 tile[32][33];
    int bh = blockIdx.z;
    size_t base = (size_t)bh * R * Cn;
    int tx = threadIdx.x, ty = threadIdx.y;
    int c = blockIdx.x * 32 + tx;
    int rbase = blockIdx.y * 32;
    #pragma unroll
    for (int rr = 0; rr < 4; ++rr)
        tile[ty + rr * 8][tx] = in[base + (size_t)(rbase + ty + rr * 8) * Cn + c];
    __syncthreads();
    float zv = zinv[(size_t)bh * R + rbase + tx];   // L index is rbase+tx for all rr
    int ro = blockIdx.x * 32 + ty;
    #pragma unroll
    for (int rr = 0; rr < 4; ++rr)
        out[base + (size_t)(ro + rr * 8) * R + rbase + tx] = f2b(b2f(tile[tx][ty + rr * 8]) * zv);
}

// ======== QKV GEMM v3: 32x32x16 MFMA, 128^2 tile, BK=64, dbuf, 2 blocks/CU ========
// R10-proven (took QKV out of the top-5). DO NOT PERTURB.
__global__ __launch_bounds__(256, 2)
void k_gemm_qkv32(const u16* __restrict__ A, const u16* __restrict__ Bt,
                  const float* __restrict__ bias,
                  u16* __restrict__ qo, u16* __restrict__ ko, u16* __restrict__ vo)
{
    const int K = Cc;            // 1024
    const int NT = K / 64;       // 16 K-tiles
    __shared__ u16 As[2][128 * 64];
    __shared__ u16 Bs[2][128 * 64];
    const int tid = threadIdx.x;
    const int wid = tid >> 6, lane = tid & 63;
    const int l31 = lane & 31, lhi = lane >> 5, l7 = lane & 7;
    const int wr = wid >> 1, wc = wid & 1;       // 2x2 waves, 64x64 each
    const int nwg = gridDim.x * gridDim.y;       // 1536, %8==0
    const int flat = blockIdx.y * gridDim.x + blockIdx.x;
    const int swz = (flat & 7) * (nwg >> 3) + (flat >> 3);
    const int bx = swz % gridDim.x, by = swz / gridDim.x;
    const int row0 = by * 128, col0 = bx * 128;

    const int srow = tid >> 3;
    const int schunk = (tid & 7) ^ (srow & 7);
    const u16* gA = A  + (size_t)(row0 + srow) * K + schunk * 8;
    const u16* gB = Bt + (size_t)(col0 + srow) * K + schunk * 8;

#define STG(buf, t) do { \
    const u16* ga_ = gA + (size_t)(t) * 64; \
    const u16* gb_ = gB + (size_t)(t) * 64; \
    u16* la_ = &As[buf][wid * 512]; \
    u16* lb_ = &Bs[buf][wid * 512]; \
    gload16(ga_,                  la_); \
    gload16(ga_ + (size_t)32 * K, la_ + 2048); \
    gload16(ga_ + (size_t)64 * K, la_ + 4096); \
    gload16(ga_ + (size_t)96 * K, la_ + 6144); \
    gload16(gb_,                  lb_); \
    gload16(gb_ + (size_t)32 * K, lb_ + 2048); \
    gload16(gb_ + (size_t)64 * K, lb_ + 4096); \
    gload16(gb_ + (size_t)96 * K, lb_ + 6144); \
} while (0)

    const int coff0 = (((0 + lhi) ^ l7) << 3);
    const int coff1 = (((2 + lhi) ^ l7) << 3);
    const int coff2 = (((4 + lhi) ^ l7) << 3);
    const int coff3 = (((6 + lhi) ^ l7) << 3);
    const int coff[4] = { coff0, coff1, coff2, coff3 };

    f32x16 acc[2][2] = {};

    STG(0, 0);
    STG(1, 1);
    asm volatile("s_waitcnt vmcnt(8)" ::: "memory");   // tile0's 8 loads landed
    __builtin_amdgcn_s_barrier();
    __builtin_amdgcn_sched_barrier(0);

    for (int t = 0; t < NT; ++t) {
        const u16* cA = &As[t & 1][0];
        const u16* cB = &Bs[t & 1][0];
        // ---- phase 0: A frags (held) + B tn=0, 8 MFMA ----
        bf16x8 af[2][4], bf0[4];
        #pragma unroll
        for (int tm = 0; tm < 2; ++tm)
            #pragma unroll
            for (int kc = 0; kc < 4; ++kc)
                af[tm][kc] = *(const bf16x8*)&cA[(wr * 64 + tm * 32 + l31) * 64 + coff[kc]];
        #pragma unroll
        for (int kc = 0; kc < 4; ++kc)
            bf0[kc] = *(const bf16x8*)&cB[(wc * 64 + l31) * 64 + coff[kc]];
        __builtin_amdgcn_s_setprio(1);
        #pragma unroll
        for (int tm = 0; tm < 2; ++tm)
            #pragma unroll
            for (int kc = 0; kc < 4; ++kc)
                acc[tm][0] = __builtin_amdgcn_mfma_f32_32x32x16_bf16(
                    af[tm][kc], bf0[kc], acc[tm][0], 0, 0, 0);
        __builtin_amdgcn_s_setprio(0);
        __builtin_amdgcn_s_barrier();
        // ---- phase 1: B tn=1, 8 MFMA ----
        bf16x8 bf1[4];
        #pragma unroll
        for (int kc = 0; kc < 4; ++kc)
            bf1[kc] = *(const bf16x8*)&cB[(wc * 64 + 32 + l31) * 64 + coff[kc]];
        __builtin_amdgcn_s_setprio(1);
        #pragma unroll
        for (int tm = 0; tm < 2; ++tm)
            #pragma unroll
            for (int kc = 0; kc < 4; ++kc)
                acc[tm][1] = __builtin_amdgcn_mfma_f32_32x32x16_bf16(
                    af[tm][kc], bf1[kc], acc[tm][1], 0, 0, 0);
        __builtin_amdgcn_s_setprio(0);
        __builtin_amdgcn_s_barrier();          // all waves done reading buf[t&1]
        __builtin_amdgcn_sched_barrier(0);
        if (t + 2 < NT) STG(t & 1, t + 2);
        if (t + 1 < NT) {
            if (t + 2 < NT) { asm volatile("s_waitcnt vmcnt(8)" ::: "memory"); }
            else            { asm volatile("s_waitcnt vmcnt(0)" ::: "memory"); }
            __builtin_amdgcn_s_barrier();      // all waves' t+1 landed
            __builtin_amdgcn_sched_barrier(0);
        }
    }
#undef STG

    // epilogue: q/k/v scatter to (B,H,L,D); 32x32 C/D layout
    #pragma unroll
    for (int tm = 0; tm < 2; ++tm) {
        #pragma unroll
        for (int tn = 0; tn < 2; ++tn) {
            int cg = col0 + wc * 64 + tn * 32 + l31;
            float bv = bias[cg];
            int which = cg >> 10;         // 0=q 1=k 2=v
            float sc = (which == 0) ? QSCALE : 1.0f;
            int cc2 = cg & 1023;
            int h = cc2 >> 6, dd = cc2 & 63;
            int rbase = row0 + wr * 64 + tm * 32 + 4 * lhi;
            #pragma unroll
            for (int g = 0; g < 4; ++g) {
                #pragma unroll
                for (int r = 0; r < 4; ++r) {
                    int rg = rbase + 8 * g + r;
                    int bidx = rg >> 10, ll2 = rg & 1023;
                    size_t o = ((size_t)(bidx * Hh + h) * Ll + ll2) * Dd + dd;
                    u16 val = f2b((acc[tm][tn][g * 4 + r] + bv) * sc);
                    if (which == 0) qo[o] = val;
                    else if (which == 1) ko[o] = val;
                    else vo[o] = val;
                }
            }
        }
    }
}

// ---- proj GEMM: 2-phase dbuf + global_load_lds + source-side XOR swizzle ----
__global__ __launch_bounds__(256)
void k_gemm_proj(const u16* __restrict__ A, const u16* __restrict__ Bt,
                 const float* __restrict__ bias, float* __restrict__ outf)
{
    const int N = Cc, K = Cc;
    __shared__ u16 As[2][128 * 32];
    __shared__ u16 Bs[2][128 * 32];
    const int tid = threadIdx.x;
    const int wid = tid >> 6, lane = tid & 63;
    const int lr = lane & 15, lg = lane >> 4;
    const int wr = wid >> 1, wc = wid & 1;
    const int nwg = gridDim.x * gridDim.y;
    const int flat = blockIdx.y * gridDim.x + blockIdx.x;
    const int swz = (flat & 7) * (nwg >> 3) + (flat >> 3);
    const int bx = swz % gridDim.x, by = swz / gridDim.x;
    const int row0 = by * 128, col0 = bx * 128;

    const int srow = wid * 32 + (lane >> 2);
    const int schk = (lane & 3) ^ (srow & 3);
    const u16* aP = A  + (size_t)(row0 + srow) * K + schk * 8;
    const u16* bP = Bt + (size_t)(col0 + srow) * K + schk * 8;
    const size_t r16 = (size_t)16 * K;
    u16* aL0 = &As[0][wid * 32 * 32]; u16* aL0b = aL0 + 16 * 32;
    u16* bL0 = &Bs[0][wid * 32 * 32]; u16* bL0b = bL0 + 16 * 32;
    u16* aL1 = &As[1][wid * 32 * 32]; u16* aL1b = aL1 + 16 * 32;
    u16* bL1 = &Bs[1][wid * 32 * 32]; u16* bL1b = bL1 + 16 * 32;

    f32x4 acc[4][4] = {};

#define STAGE0(kk) { gload16(aP + (kk), aL0); gload16(aP + r16 + (kk), aL0b); \
                     gload16(bP + (kk), bL0); gload16(bP + r16 + (kk), bL0b); }
#define STAGE1(kk) { gload16(aP + (kk), aL1); gload16(aP + r16 + (kk), aL1b); \
                     gload16(bP + (kk), bL1); gload16(bP + r16 + (kk), bL1b); }
#define COMPUTE(bufi) { \
        bf16x8 af[4], bfv[4]; \
        _Pragma("unroll") \
        for (int m = 0; m < 4; ++m) { int rw = wr * 64 + m * 16 + lr; \
            af[m] = *(const bf16x8*)&As[bufi][rw * 32 + ((lg ^ (rw & 3)) * 8)]; } \
        _Pragma("unroll") \
        for (int n = 0; n < 4; ++n) { int rw = wc * 64 + n * 16 + lr; \
            bfv[n] = *(const bf16x8*)&Bs[bufi][rw * 32 + ((lg ^ (rw & 3)) * 8)]; } \
        _Pragma("unroll") \
        for (int m = 0; m < 4; ++m) \
            _Pragma("unroll") \
            for (int n = 0; n < 4; ++n) \
                acc[m][n] = __builtin_amdgcn_mfma_f32_16x16x32_bf16(af[m], bfv[n], acc[m][n], 0, 0, 0); }

    STAGE0(0);
    __syncthreads();
    for (int k0 = 0; k0 < K; k0 += 64) {
        if (k0 + 32 < K) STAGE1(k0 + 32);
        COMPUTE(0);
        __syncthreads();
        if (k0 + 64 < K) STAGE0(k0 + 64);
        COMPUTE(1);
        __syncthreads();
    }
#undef STAGE0
#undef STAGE1
#undef COMPUTE

    #pragma unroll
    for (int m = 0; m < 4; ++m) {
        int rb2 = row0 + wr * 64 + m * 16 + lg * 4;
        #pragma unroll
        for (int n = 0; n < 4; ++n) {
            int cg = col0 + wc * 64 + n * 16 + lr;
            float bv = bias[cg];
            #pragma unroll
            for (int r = 0; r < 4; ++r)
                outf[(size_t)(rb2 + r) * N + cg] = acc[m][n][r] + bv;
        }
    }
}

// ---------------- attention pass 1: column sums ----------------
__global__ __launch_bounds__(256)
void k_attn_colsum(const u16* __restrict__ Q, const u16* __restrict__ Kb,
                   float* __restrict__ zinv)
{
    const int tid = threadIdx.x;
    const int wid = tid >> 6, lane = tid & 63;
    const int lr = lane & 15, lg = lane >> 4;
    const int fid = blockIdx.x;
    const int xcd = fid & 7, n = fid >> 3;
    const int pr = n & 3;
    const int bh = (xcd << 4) | (n >> 2);
    const u16* Qp = Q  + (size_t)bh * Ll * Dd;
    const u16* Kp = Kb + (size_t)bh * Ll * Dd;
    const bool dmask[4] = { lg * 4 + 0 >= lr, lg * 4 + 1 >= lr,
                            lg * 4 + 2 >= lr, lg * 4 + 3 >= lr };

    #pragma unroll
    for (int t = 0; t < 2; ++t) {
        const int xt = t ? (7 - pr) : pr;
        const int jw = xt * 128 + wid * 32;
        bf16x8 kb[2][2];
        #pragma unroll
        for (int g = 0; g < 2; ++g) {
            kb[g][0] = *(const bf16x8*)&Kp[(jw + g * 16 + lr) * Dd + lg * 8];
            kb[g][1] = *(const bf16x8*)&Kp[(jw + g * 16 + lr) * Dd + 32 + lg * 8];
        }
        float z0 = 0.f, z1 = 0.f;
        {   // ib = jw: g0 diag-masked; g1 entirely above diagonal (skip)
            bf16x8 qa0 = *(const bf16x8*)&Qp[(jw + lr) * Dd + lg * 8];
            bf16x8 qa1 = *(const bf16x8*)&Qp[(jw + lr) * Dd + 32 + lg * 8];
            f32x4 s = {0.f, 0.f, 0.f, 0.f};
            s = __builtin_amdgcn_mfma_f32_16x16x32_bf16(qa0, kb[0][0], s, 0, 0, 0);
            s = __builtin_amdgcn_mfma_f32_16x16x32_bf16(qa1, kb[0][1], s, 0, 0, 0);
            #pragma unroll
            for (int r = 0; r < 4; ++r) z0 += dmask[r] ? exp2f(s[r]) : 0.f;
        }
        {   // ib = jw+16: g0 unmasked, g1 diag-masked
            bf16x8 qa0 = *(const bf16x8*)&Qp[(jw + 16 + lr) * Dd + lg * 8];
            bf16x8 qa1 = *(const bf16x8*)&Qp[(jw + 16 + lr) * Dd + 32 + lg * 8];
            f32x4 s0 = {0.f, 0.f, 0.f, 0.f}, s1 = {0.f, 0.f, 0.f, 0.f};
            s0 = __builtin_amdgcn_mfma_f32_16x16x32_bf16(qa0, kb[0][0], s0, 0, 0, 0);
            s0 = __builtin_amdgcn_mfma_f32_16x16x32_bf16(qa1, kb[0][1], s0, 0, 0, 0);
            s1 = __builtin_amdgcn_mfma_f32_16x16x32_bf16(qa0, kb[1][0], s1, 0, 0, 0);
            s1 = __builtin_amdgcn_mfma_f32_16x16x32_bf16(qa1, kb[1][1], s1, 0, 0, 0);
            #pragma unroll
            for (int r = 0; r < 4; ++r) {
                z0 += exp2f(s0[r]);
                z1 += dmask[r] ? exp2f(s1[r]) : 0.f;
            }
        }
        for (int ib = jw + 32; ib < Ll; ib += 16) {
            bf16x8 qa0 = *(const bf16x8*)&Qp[(ib + lr) * Dd + lg * 8];
            bf16x8 qa1 = *(const bf16x8*)&Qp[(ib + lr) * Dd + 32 + lg * 8];
            f32x4 s0 = {0.f, 0.f, 0.f, 0.f}, s1 = {0.f, 0.f, 0.f, 0.f};
            s0 = __builtin_amdgcn_mfma_f32_16x16x32_bf16(qa0, kb[0][0], s0, 0, 0, 0);
            s0 = __builtin_amdgcn_mfma_f32_16x16x32_bf16(qa1, kb[0][1], s0, 0, 0, 0);
            s1 = __builtin_amdgcn_mfma_f32_16x16x32_bf16(qa0, kb[1][0], s1, 0, 0, 0);
            s1 = __builtin_amdgcn_mfma_f32_16x16x32_bf16(qa1, kb[1][1], s1, 0, 0, 0);
            #pragma unroll
            for (int r = 0; r < 4; ++r) { z0 += exp2f(s0[r]); z1 += exp2f(s1[r]); }
        }
        z0 += __shfl_xor(z0, 16); z0 += __shfl_xor(z0, 32);
        z1 += __shfl_xor(z1, 16); z1 += __shfl_xor(z1, 32);
        if (lg == 0) {
            zinv[(size_t)bh * Ll + jw + lr]      = 1.f / z0;
            zinv[(size_t)bh * Ll + jw + 16 + lr] = 1.f / z1;
        }
    }
}

// ---------------- attention pass 2: Y = exp(S') @ V'  (shuffle P, pinned loads) ----------------
// R14 post-mortem: LDS-bounce removal was null; the invariant bottleneck is the
// compiler's low-register schedule (VGPR 52-60) issuing the 16 loads per j0
// serially. Fix: issue ALL 8 K-frag + 8 V-frag loads, then sched_barrier(0) —
// the fence forces all 16 results live simultaneously (allocator must give
// ~110 VGPR) and loads go out back-to-back. Falsifiable: if VGPR stays ~60,
// this theory is dead.
__global__ __launch_bounds__(256, 4)
void k_attn_pv(const u16* __restrict__ Q, const u16* __restrict__ Kb,
               const u16* __restrict__ Vt, u16* __restrict__ Y)
{
    const int tid = threadIdx.x;
    const int wid = tid >> 6, lane = tid & 63;
    const int lr = lane & 15, lg = lane >> 4;
    const int fid = blockIdx.x;
    const int xcd = fid & 7, n = fid >> 3;
    const int xtile = n & 7;
    const int bh = (xcd << 4) | (n >> 3);
    const int bidx = bh >> 4, h = bh & 15;
    const u16* Qp = Q  + (size_t)bh * Ll * Dd;
    const u16* Kp = Kb + (size_t)bh * Ll * Dd;
    const u16* Vp = Vt + (size_t)bh * Ll * Dd;     // (Dd, Ll) layout, zinv-scaled
    const int src0 = lr + 32 * (lg & 1);           // producer lane lg'=2(lg&1)
    const int src1 = src0 + 16;                    // producer lane lg'=2(lg&1)+1
    const bool selHi = (lg & 2) != 0;              // cs select: w1/w3 vs w0/w2

    #pragma unroll
    for (int t = 0; t < 2; ++t) {
        const int xt = t ? (15 - xtile) : xtile;
        const int iw = xt * 64 + wid * 16;
        // Q is the B-operand: lane (lr,lg) needs Q[i=iw+lr][d=8lg+e]
        bf16x8 qa0 = *(const bf16x8*)&Qp[(iw + lr) * Dd + lg * 8];
        bf16x8 qa1 = *(const bf16x8*)&Qp[(iw + lr) * Dd + 32 + lg * 8];
        f32x4 yacc[4] = {};

        for (int j0 = 0; j0 <= iw + 15; j0 += 64) {
            // ---- issue ALL 16 loads back-to-back, then FENCE ----
            bf16x8 kb[4][2], vb[4][2];
            #pragma unroll
            for (int cs = 0; cs < 4; ++cs) {
                kb[cs][0] = *(const bf16x8*)&Kp[(j0 + cs * 16 + lr) * Dd + lg * 8];
                kb[cs][1] = *(const bf16x8*)&Kp[(j0 + cs * 16 + lr) * Dd + 32 + lg * 8];
            }
            #pragma unroll
            for (int ns = 0; ns < 4; ++ns) {
                vb[ns][0] = *(const bf16x8*)&Vp[(size_t)(ns * 16 + lr) * Ll + j0 + lg * 8];
                vb[ns][1] = *(const bf16x8*)&Vp[(size_t)(ns * 16 + lr) * Ll + j0 + 32 + lg * 8];
            }
            __builtin_amdgcn_sched_barrier(0);   // loads may NOT sink below this
            // ---- S phase: 4 cs blocks, results kept in named uint2 regs ----
            uint2 w0, w1, w2, w3;
            #pragma unroll
            for (int cs = 0; cs < 4; ++cs) {
                int jb = j0 + cs * 16;
                f32x4 s = {0.f, 0.f, 0.f, 0.f};
                s = __builtin_amdgcn_mfma_f32_16x16x32_bf16(kb[cs][0], qa0, s, 0, 0, 0);
                s = __builtin_amdgcn_mfma_f32_16x16x32_bf16(kb[cs][1], qa1, s, 0, 0, 0);
                // lane holds S^T[j=jb+4lg+r][i=iw+lr]
                float p[4];
                if (jb + 15 <= iw) {          // fully unmasked sub-tile
                    #pragma unroll
                    for (int r = 0; r < 4; ++r) p[r] = exp2f(s[r]);
                } else {
                    int ig = iw + lr;
                    #pragma unroll
                    for (int r = 0; r < 4; ++r)
                        p[r] = (jb + 4 * lg + r <= ig) ? exp2f(s[r]) : 0.f;
                }
                uint2 w;
                w.x = pack2bf(p[0], p[1]);
                w.y = pack2bf(p[2], p[3]);
                if (cs == 0) w0 = w; else if (cs == 1) w1 = w;
                else if (cs == 2) w2 = w; else w3 = w;
            }
            // ---- redistribute P across lane-groups: 16 shfl + 8 selects ----
            u32 a00 = (u32)__shfl((int)w0.x, src0), a01 = (u32)__shfl((int)w0.y, src0);
            u32 a02 = (u32)__shfl((int)w0.x, src1), a03 = (u32)__shfl((int)w0.y, src1);
            u32 a10 = (u32)__shfl((int)w1.x, src0), a11 = (u32)__shfl((int)w1.y, src0);
            u32 a12 = (u32)__shfl((int)w1.x, src1), a13 = (u32)__shfl((int)w1.y, src1);
            u32 a20 = (u32)__shfl((int)w2.x, src0), a21 = (u32)__shfl((int)w2.y, src0);
            u32 a22 = (u32)__shfl((int)w2.x, src1), a23 = (u32)__shfl((int)w2.y, src1);
            u32 a30 = (u32)__shfl((int)w3.x, src0), a31 = (u32)__shfl((int)w3.y, src0);
            u32 a32 = (u32)__shfl((int)w3.x, src1), a33 = (u32)__shfl((int)w3.y, src1);
            u32x4 pa0u, pa1u;
            pa0u[0] = selHi ? a10 : a00;  pa0u[1] = selHi ? a11 : a01;
            pa0u[2] = selHi ? a12 : a02;  pa0u[3] = selHi ? a13 : a03;
            pa1u[0] = selHi ? a30 : a20;  pa1u[1] = selHi ? a31 : a21;
            pa1u[2] = selHi ? a32 : a22;  pa1u[3] = selHi ? a33 : a23;
            bf16x8 pa0 = __builtin_bit_cast(bf16x8, pa0u);   // k = j0..j0+31
            bf16x8 pa1 = __builtin_bit_cast(bf16x8, pa1u);   // k = j0+32..+63
            // ---- PV phase: V already in registers ----
            #pragma unroll
            for (int ns = 0; ns < 4; ++ns) {
                yacc[ns] = __builtin_amdgcn_mfma_f32_16x16x32_bf16(pa0, vb[ns][0], yacc[ns], 0, 0, 0);
                yacc[ns] = __builtin_amdgcn_mfma_f32_16x16x32_bf16(pa1, vb[ns][1], yacc[ns], 0, 0, 0);
            }
        }
        #pragma unroll
        for (int ns = 0; ns < 4; ++ns)
            #pragma unroll
            for (int r = 0; r < 4; ++r) {
                int l2 = iw + lg * 4 + r;
                Y[((size_t)bidx * Ll + l2) * Cc + h * Dd + ns * 16 + lr] = f2b(yacc[ns][r]);
            }
    }
}

extern "C" void kernel_launch(void* const* d_in, const int* in_sizes, int n_in,
                              void* d_out, int out_size, void* d_ws, size_t ws_size,
                              hipStream_t stream)
{
    const float* x     = (const float*)d_in[0];
    const float* Wqkv  = (const float*)d_in[1];
    const float* bqkv  = (const float*)d_in[2];
    const float* Wproj = (const float*)d_in[3];
    const float* bproj = (const float*)d_in[4];
    float* out = (float*)d_out;

    char* ws = (char*)d_ws;
    u16* xb     = (u16*)(ws + 0);            // x as bf16, 8192x1024         (16 MB)
    u16* WqkvT  = (u16*)(ws + 16777216);     // W_qkv^T bf16, 3072x1024      (6 MB)
    u16* WprojT = (u16*)(ws + 23068672);     // W_proj^T bf16, 1024x1024     (2 MB)
    u16* q      = (u16*)(ws + 25165824);     // (B,H,L,D) bf16, pre-scaled   (16 MB)
    u16* k      = (u16*)(ws + 41943040);     // (B,H,L,D) bf16               (16 MB)
    u16* v      = (u16*)(ws + 58720256);     // (B,H,L,D) bf16; reused as Y  (16 MB)
    u16* vt     = (u16*)(ws + 75497472);     // (B,H,D,L) bf16, zinv-scaled  (16 MB)
    float* zinv = (float*)(ws + 92274688);   // (B*H*L) fp32                 (0.5 MB)

    k_f32_to_bf16<<<dim3(2048), dim3(256), 0, stream>>>(x, xb, Mrows * Cc / 16);
    k_transpose_w<<<dim3(128, 32), dim3(32, 8), 0, stream>>>(Wqkv, WqkvT, Wproj, WprojT);
    k_gemm_qkv32<<<dim3(N3 / 128, Mrows / 128), dim3(256), 0, stream>>>(
        xb, WqkvT, bqkv, q, k, v);
    k_attn_colsum<<<dim3(512), dim3(256), 0, stream>>>(q, k, zinv);
    k_transpose_scale_bf16<<<dim3(2, 32, Bb * Hh), dim3(32, 8), 0, stream>>>(v, zinv, vt, Ll, Dd);
    k_attn_pv<<<dim3(1024), dim3(256), 0, stream>>>(q, k, vt, v);
    k_gemm_proj<<<dim3(Cc / 128, Mrows / 128), dim3(256), 0, stream>>>(
        v, WprojT, bproj, out);
}

// Round 16
// 198.278 us; speedup vs baseline: 1.3889x; 1.3863x over previous
//
#include <hip/hip_runtime.h>

typedef unsigned short u16;
typedef unsigned int   u32;
using bf16x8 = __attribute__((ext_vector_type(8))) short;
using f32x4  = __attribute__((ext_vector_type(4))) float;
using f32x16 = __attribute__((ext_vector_type(16))) float;
using u32x4  = __attribute__((ext_vector_type(4))) u32;

static constexpr int Bb = 8, Ll = 1024, Cc = 1024, Hh = 16, Dd = 64;
static constexpr int Mrows = Bb * Ll;   // 8192
static constexpr int N3    = 3 * Cc;    // 3072
// exp(S/8) = 2^(S * 0.125*log2(e)); fold into q at the QKV epilogue
static constexpr float QSCALE = 0.125f * 1.44269504088896f;

__device__ __forceinline__ u16 f2b(float f) {  // fp32 -> bf16 RNE
    u32 u = __builtin_bit_cast(u32, f);
    u += 0x7FFFu + ((u >> 16) & 1u);
    return (u16)(u >> 16);
}
__device__ __forceinline__ float b2f(u16 u) {
    return __builtin_bit_cast(float, (u32)u << 16);
}
__device__ __forceinline__ u32 pack2bf(float a, float b) {
    return (u32)f2b(a) | ((u32)f2b(b) << 16);
}
// async global->LDS, 16B/lane; LDS dest is wave-uniform base (lane*16 HW-added)
__device__ __forceinline__ void gload16(const u16* g, u16* l) {
    __builtin_amdgcn_global_load_lds(
        (const __attribute__((address_space(1))) void*)g,
        (__attribute__((address_space(3))) void*)l, 16, 0, 0);
}

// ---------------- fp32 -> bf16 convert, 16 elems/thread ----------------
__global__ void k_f32_to_bf16(const float* __restrict__ in, u16* __restrict__ out, int n16) {
    int idx = blockIdx.x * blockDim.x + threadIdx.x;
    if (idx >= n16) return;
    #pragma unroll
    for (int h = 0; h < 2; ++h) {
        f32x4 v0 = *((const f32x4*)in + idx * 4 + h * 2);
        f32x4 v1 = *((const f32x4*)in + idx * 4 + h * 2 + 1);
        u32x4 o;
        o[0] = pack2bf(v0[0], v0[1]);
        o[1] = pack2bf(v0[2], v0[3]);
        o[2] = pack2bf(v1[0], v1[1]);
        o[3] = pack2bf(v1[2], v1[3]);
        *((u32x4*)out + idx * 2 + h) = o;
    }
}

// ---- fused weight transpose+convert: W_qkv (1024x3072) and W_proj (1024x1024) ----
__global__ void k_transpose_w(const float* __restrict__ Wqkv, u16* __restrict__ WqkvT,
                              const float* __restrict__ Wproj, u16* __restrict__ WprojT) {
    __shared__ float tile[32][33];
    int bx = blockIdx.x;
    const float* in; u16* out; int Cn;
    if (bx < 96) { in = Wqkv;  out = WqkvT;  Cn = N3; }
    else         { in = Wproj; out = WprojT; Cn = Cc; bx -= 96; }
    const int R = Cc;   // 1024 rows for both
    int tx = threadIdx.x, ty = threadIdx.y;
    int c = bx * 32 + tx;
    int rbase = blockIdx.y * 32;
    #pragma unroll
    for (int rr = 0; rr < 4; ++rr)
        tile[ty + rr * 8][tx] = in[(size_t)(rbase + ty + rr * 8) * Cn + c];
    __syncthreads();
    int ro = bx * 32 + ty;
    #pragma unroll
    for (int rr = 0; rr < 4; ++rr)
        out[(size_t)(ro + rr * 8) * R + rbase + tx] = f2b(tile[tx][ty + rr * 8]);
}

// --- batched bf16 transpose + zinv row-scale: v (bh,L,D) -> vt (bh,D,L)*zinv[l] ---
__global__ void k_transpose_scale_bf16(const u16* __restrict__ in, const float* __restrict__ zinv,
                                       u16* __restrict__ out, int R, int Cn) {
    __shared__ u16 tile[32][33];
    int bh = blockIdx.z;
    size_t base = (size_t)bh * R * Cn;
    int tx = threadIdx.x, ty = threadIdx.y;
    int c = blockIdx.x * 32 + tx;
    int rbase = blockIdx.y * 32;
    #pragma unroll
    for (int rr = 0; rr < 4; ++rr)
        tile[ty + rr * 8][tx] = in[base + (size_t)(rbase + ty + rr * 8) * Cn + c];
    __syncthreads();
    float zv = zinv[(size_t)bh * R + rbase + tx];   // L index is rbase+tx for all rr
    int ro = blockIdx.x * 32 + ty;
    #pragma unroll
    for (int rr = 0; rr < 4; ++rr)
        out[base + (size_t)(ro + rr * 8) * R + rbase + tx] = f2b(b2f(tile[tx][ty + rr * 8]) * zv);
}

// ======== QKV GEMM v3: 32x32x16 MFMA, 128^2 tile, BK=64, dbuf, 2 blocks/CU ========
// R10-proven (took QKV out of the top-5). DO NOT PERTURB.
__global__ __launch_bounds__(256, 2)
void k_gemm_qkv32(const u16* __restrict__ A, const u16* __restrict__ Bt,
                  const float* __restrict__ bias,
                  u16* __restrict__ qo, u16* __restrict__ ko, u16* __restrict__ vo)
{
    const int K = Cc;            // 1024
    const int NT = K / 64;       // 16 K-tiles
    __shared__ u16 As[2][128 * 64];
    __shared__ u16 Bs[2][128 * 64];
    const int tid = threadIdx.x;
    const int wid = tid >> 6, lane = tid & 63;
    const int l31 = lane & 31, lhi = lane >> 5, l7 = lane & 7;
    const int wr = wid >> 1, wc = wid & 1;       // 2x2 waves, 64x64 each
    const int nwg = gridDim.x * gridDim.y;       // 1536, %8==0
    const int flat = blockIdx.y * gridDim.x + blockIdx.x;
    const int swz = (flat & 7) * (nwg >> 3) + (flat >> 3);
    const int bx = swz % gridDim.x, by = swz / gridDim.x;
    const int row0 = by * 128, col0 = bx * 128;

    const int srow = tid >> 3;
    const int schunk = (tid & 7) ^ (srow & 7);
    const u16* gA = A  + (size_t)(row0 + srow) * K + schunk * 8;
    const u16* gB = Bt + (size_t)(col0 + srow) * K + schunk * 8;

#define STG(buf, t) do { \
    const u16* ga_ = gA + (size_t)(t) * 64; \
    const u16* gb_ = gB + (size_t)(t) * 64; \
    u16* la_ = &As[buf][wid * 512]; \
    u16* lb_ = &Bs[buf][wid * 512]; \
    gload16(ga_,                  la_); \
    gload16(ga_ + (size_t)32 * K, la_ + 2048); \
    gload16(ga_ + (size_t)64 * K, la_ + 4096); \
    gload16(ga_ + (size_t)96 * K, la_ + 6144); \
    gload16(gb_,                  lb_); \
    gload16(gb_ + (size_t)32 * K, lb_ + 2048); \
    gload16(gb_ + (size_t)64 * K, lb_ + 4096); \
    gload16(gb_ + (size_t)96 * K, lb_ + 6144); \
} while (0)

    const int coff0 = (((0 + lhi) ^ l7) << 3);
    const int coff1 = (((2 + lhi) ^ l7) << 3);
    const int coff2 = (((4 + lhi) ^ l7) << 3);
    const int coff3 = (((6 + lhi) ^ l7) << 3);
    const int coff[4] = { coff0, coff1, coff2, coff3 };

    f32x16 acc[2][2] = {};

    STG(0, 0);
    STG(1, 1);
    asm volatile("s_waitcnt vmcnt(8)" ::: "memory");   // tile0's 8 loads landed
    __builtin_amdgcn_s_barrier();
    __builtin_amdgcn_sched_barrier(0);

    for (int t = 0; t < NT; ++t) {
        const u16* cA = &As[t & 1][0];
        const u16* cB = &Bs[t & 1][0];
        // ---- phase 0: A frags (held) + B tn=0, 8 MFMA ----
        bf16x8 af[2][4], bf0[4];
        #pragma unroll
        for (int tm = 0; tm < 2; ++tm)
            #pragma unroll
            for (int kc = 0; kc < 4; ++kc)
                af[tm][kc] = *(const bf16x8*)&cA[(wr * 64 + tm * 32 + l31) * 64 + coff[kc]];
        #pragma unroll
        for (int kc = 0; kc < 4; ++kc)
            bf0[kc] = *(const bf16x8*)&cB[(wc * 64 + l31) * 64 + coff[kc]];
        __builtin_amdgcn_s_setprio(1);
        #pragma unroll
        for (int tm = 0; tm < 2; ++tm)
            #pragma unroll
            for (int kc = 0; kc < 4; ++kc)
                acc[tm][0] = __builtin_amdgcn_mfma_f32_32x32x16_bf16(
                    af[tm][kc], bf0[kc], acc[tm][0], 0, 0, 0);
        __builtin_amdgcn_s_setprio(0);
        __builtin_amdgcn_s_barrier();
        // ---- phase 1: B tn=1, 8 MFMA ----
        bf16x8 bf1[4];
        #pragma unroll
        for (int kc = 0; kc < 4; ++kc)
            bf1[kc] = *(const bf16x8*)&cB[(wc * 64 + 32 + l31) * 64 + coff[kc]];
        __builtin_amdgcn_s_setprio(1);
        #pragma unroll
        for (int tm = 0; tm < 2; ++tm)
            #pragma unroll
            for (int kc = 0; kc < 4; ++kc)
                acc[tm][1] = __builtin_amdgcn_mfma_f32_32x32x16_bf16(
                    af[tm][kc], bf1[kc], acc[tm][1], 0, 0, 0);
        __builtin_amdgcn_s_setprio(0);
        __builtin_amdgcn_s_barrier();          // all waves done reading buf[t&1]
        __builtin_amdgcn_sched_barrier(0);
        if (t + 2 < NT) STG(t & 1, t + 2);
        if (t + 1 < NT) {
            if (t + 2 < NT) { asm volatile("s_waitcnt vmcnt(8)" ::: "memory"); }
            else            { asm volatile("s_waitcnt vmcnt(0)" ::: "memory"); }
            __builtin_amdgcn_s_barrier();      // all waves' t+1 landed
            __builtin_amdgcn_sched_barrier(0);
        }
    }
#undef STG

    // epilogue: q/k/v scatter to (B,H,L,D); 32x32 C/D layout
    #pragma unroll
    for (int tm = 0; tm < 2; ++tm) {
        #pragma unroll
        for (int tn = 0; tn < 2; ++tn) {
            int cg = col0 + wc * 64 + tn * 32 + l31;
            float bv = bias[cg];
            int which = cg >> 10;         // 0=q 1=k 2=v
            float sc = (which == 0) ? QSCALE : 1.0f;
            int cc2 = cg & 1023;
            int h = cc2 >> 6, dd = cc2 & 63;
            int rbase = row0 + wr * 64 + tm * 32 + 4 * lhi;
            #pragma unroll
            for (int g = 0; g < 4; ++g) {
                #pragma unroll
                for (int r = 0; r < 4; ++r) {
                    int rg = rbase + 8 * g + r;
                    int bidx = rg >> 10, ll2 = rg & 1023;
                    size_t o = ((size_t)(bidx * Hh + h) * Ll + ll2) * Dd + dd;
                    u16 val = f2b((acc[tm][tn][g * 4 + r] + bv) * sc);
                    if (which == 0) qo[o] = val;
                    else if (which == 1) ko[o] = val;
                    else vo[o] = val;
                }
            }
        }
    }
}

// ---- proj GEMM: 2-phase dbuf + global_load_lds + source-side XOR swizzle ----
__global__ __launch_bounds__(256)
void k_gemm_proj(const u16* __restrict__ A, const u16* __restrict__ Bt,
                 const float* __restrict__ bias, float* __restrict__ outf)
{
    const int N = Cc, K = Cc;
    __shared__ u16 As[2][128 * 32];
    __shared__ u16 Bs[2][128 * 32];
    const int tid = threadIdx.x;
    const int wid = tid >> 6, lane = tid & 63;
    const int lr = lane & 15, lg = lane >> 4;
    const int wr = wid >> 1, wc = wid & 1;
    const int nwg = gridDim.x * gridDim.y;
    const int flat = blockIdx.y * gridDim.x + blockIdx.x;
    const int swz = (flat & 7) * (nwg >> 3) + (flat >> 3);
    const int bx = swz % gridDim.x, by = swz / gridDim.x;
    const int row0 = by * 128, col0 = bx * 128;

    const int srow = wid * 32 + (lane >> 2);
    const int schk = (lane & 3) ^ (srow & 3);
    const u16* aP = A  + (size_t)(row0 + srow) * K + schk * 8;
    const u16* bP = Bt + (size_t)(col0 + srow) * K + schk * 8;
    const size_t r16 = (size_t)16 * K;
    u16* aL0 = &As[0][wid * 32 * 32]; u16* aL0b = aL0 + 16 * 32;
    u16* bL0 = &Bs[0][wid * 32 * 32]; u16* bL0b = bL0 + 16 * 32;
    u16* aL1 = &As[1][wid * 32 * 32]; u16* aL1b = aL1 + 16 * 32;
    u16* bL1 = &Bs[1][wid * 32 * 32]; u16* bL1b = bL1 + 16 * 32;

    f32x4 acc[4][4] = {};

#define STAGE0(kk) { gload16(aP + (kk), aL0); gload16(aP + r16 + (kk), aL0b); \
                     gload16(bP + (kk), bL0); gload16(bP + r16 + (kk), bL0b); }
#define STAGE1(kk) { gload16(aP + (kk), aL1); gload16(aP + r16 + (kk), aL1b); \
                     gload16(bP + (kk), bL1); gload16(bP + r16 + (kk), bL1b); }
#define COMPUTE(bufi) { \
        bf16x8 af[4], bfv[4]; \
        _Pragma("unroll") \
        for (int m = 0; m < 4; ++m) { int rw = wr * 64 + m * 16 + lr; \
            af[m] = *(const bf16x8*)&As[bufi][rw * 32 + ((lg ^ (rw & 3)) * 8)]; } \
        _Pragma("unroll") \
        for (int n = 0; n < 4; ++n) { int rw = wc * 64 + n * 16 + lr; \
            bfv[n] = *(const bf16x8*)&Bs[bufi][rw * 32 + ((lg ^ (rw & 3)) * 8)]; } \
        _Pragma("unroll") \
        for (int m = 0; m < 4; ++m) \
            _Pragma("unroll") \
            for (int n = 0; n < 4; ++n) \
                acc[m][n] = __builtin_amdgcn_mfma_f32_16x16x32_bf16(af[m], bfv[n], acc[m][n], 0, 0, 0); }

    STAGE0(0);
    __syncthreads();
    for (int k0 = 0; k0 < K; k0 += 64) {
        if (k0 + 32 < K) STAGE1(k0 + 32);
        COMPUTE(0);
        __syncthreads();
        if (k0 + 64 < K) STAGE0(k0 + 64);
        COMPUTE(1);
        __syncthreads();
    }
#undef STAGE0
#undef STAGE1
#undef COMPUTE

    #pragma unroll
    for (int m = 0; m < 4; ++m) {
        int rb2 = row0 + wr * 64 + m * 16 + lg * 4;
        #pragma unroll
        for (int n = 0; n < 4; ++n) {
            int cg = col0 + wc * 64 + n * 16 + lr;
            float bv = bias[cg];
            #pragma unroll
            for (int r = 0; r < 4; ++r)
                outf[(size_t)(rb2 + r) * N + cg] = acc[m][n][r] + bv;
        }
    }
}

// ---------------- attention pass 1: column sums ----------------
__global__ __launch_bounds__(256)
void k_attn_colsum(const u16* __restrict__ Q, const u16* __restrict__ Kb,
                   float* __restrict__ zinv)
{
    const int tid = threadIdx.x;
    const int wid = tid >> 6, lane = tid & 63;
    const int lr = lane & 15, lg = lane >> 4;
    const int fid = blockIdx.x;
    const int xcd = fid & 7, n = fid >> 3;
    const int pr = n & 3;
    const int bh = (xcd << 4) | (n >> 2);
    const u16* Qp = Q  + (size_t)bh * Ll * Dd;
    const u16* Kp = Kb + (size_t)bh * Ll * Dd;
    const bool dmask[4] = { lg * 4 + 0 >= lr, lg * 4 + 1 >= lr,
                            lg * 4 + 2 >= lr, lg * 4 + 3 >= lr };

    #pragma unroll
    for (int t = 0; t < 2; ++t) {
        const int xt = t ? (7 - pr) : pr;
        const int jw = xt * 128 + wid * 32;
        bf16x8 kb[2][2];
        #pragma unroll
        for (int g = 0; g < 2; ++g) {
            kb[g][0] = *(const bf16x8*)&Kp[(jw + g * 16 + lr) * Dd + lg * 8];
            kb[g][1] = *(const bf16x8*)&Kp[(jw + g * 16 + lr) * Dd + 32 + lg * 8];
        }
        float z0 = 0.f, z1 = 0.f;
        {   // ib = jw: g0 diag-masked; g1 entirely above diagonal (skip)
            bf16x8 qa0 = *(const bf16x8*)&Qp[(jw + lr) * Dd + lg * 8];
            bf16x8 qa1 = *(const bf16x8*)&Qp[(jw + lr) * Dd + 32 + lg * 8];
            f32x4 s = {0.f, 0.f, 0.f, 0.f};
            s = __builtin_amdgcn_mfma_f32_16x16x32_bf16(qa0, kb[0][0], s, 0, 0, 0);
            s = __builtin_amdgcn_mfma_f32_16x16x32_bf16(qa1, kb[0][1], s, 0, 0, 0);
            #pragma unroll
            for (int r = 0; r < 4; ++r) z0 += dmask[r] ? exp2f(s[r]) : 0.f;
        }
        {   // ib = jw+16: g0 unmasked, g1 diag-masked
            bf16x8 qa0 = *(const bf16x8*)&Qp[(jw + 16 + lr) * Dd + lg * 8];
            bf16x8 qa1 = *(const bf16x8*)&Qp[(jw + 16 + lr) * Dd + 32 + lg * 8];
            f32x4 s0 = {0.f, 0.f, 0.f, 0.f}, s1 = {0.f, 0.f, 0.f, 0.f};
            s0 = __builtin_amdgcn_mfma_f32_16x16x32_bf16(qa0, kb[0][0], s0, 0, 0, 0);
            s0 = __builtin_amdgcn_mfma_f32_16x16x32_bf16(qa1, kb[0][1], s0, 0, 0, 0);
            s1 = __builtin_amdgcn_mfma_f32_16x16x32_bf16(qa0, kb[1][0], s1, 0, 0, 0);
            s1 = __builtin_amdgcn_mfma_f32_16x16x32_bf16(qa1, kb[1][1], s1, 0, 0, 0);
            #pragma unroll
            for (int r = 0; r < 4; ++r) {
                z0 += exp2f(s0[r]);
                z1 += dmask[r] ? exp2f(s1[r]) : 0.f;
            }
        }
        for (int ib = jw + 32; ib < Ll; ib += 16) {
            bf16x8 qa0 = *(const bf16x8*)&Qp[(ib + lr) * Dd + lg * 8];
            bf16x8 qa1 = *(const bf16x8*)&Qp[(ib + lr) * Dd + 32 + lg * 8];
            f32x4 s0 = {0.f, 0.f, 0.f, 0.f}, s1 = {0.f, 0.f, 0.f, 0.f};
            s0 = __builtin_amdgcn_mfma_f32_16x16x32_bf16(qa0, kb[0][0], s0, 0, 0, 0);
            s0 = __builtin_amdgcn_mfma_f32_16x16x32_bf16(qa1, kb[0][1], s0, 0, 0, 0);
            s1 = __builtin_amdgcn_mfma_f32_16x16x32_bf16(qa0, kb[1][0], s1, 0, 0, 0);
            s1 = __builtin_amdgcn_mfma_f32_16x16x32_bf16(qa1, kb[1][1], s1, 0, 0, 0);
            #pragma unroll
            for (int r = 0; r < 4; ++r) { z0 += exp2f(s0[r]); z1 += exp2f(s1[r]); }
        }
        z0 += __shfl_xor(z0, 16); z0 += __shfl_xor(z0, 32);
        z1 += __shfl_xor(z1, 16); z1 += __shfl_xor(z1, 32);
        if (lg == 0) {
            zinv[(size_t)bh * Ll + jw + lr]      = 1.f / z0;
            zinv[(size_t)bh * Ll + jw + 16 + lr] = 1.f / z1;
        }
    }
}

// ---------------- attention pass 2: Y = exp(S') @ V'  (LDS-staged K/V pipeline) ----------------
// R15 post-mortem: flat-load pv is stuck at VGPR~56 / serialized loads in every
// source variant. This version transplants the PROVEN qkv32 async skeleton:
// per j0-step, stage K-tile(64jx64d) + V-tile(64dx64j) into double-buffered LDS
// via global_load_lds (shared by all 4 waves: 4x less L2 traffic), counted
// vmcnt(4) at step boundaries, raw-barrier phases, both-sides XOR swizzle.
// Paired i-tiles fused into ONE uniform 17-step pipeline (steps 0..xt = tileA,
// rest = tileB); grid 1024 = exactly 4 blocks/CU, no tail. P stays in regs via
// the R14-verified shuffle redistribution.
__global__ __launch_bounds__(256, 4)
void k_attn_pv(const u16* __restrict__ Q, const u16* __restrict__ Kb,
               const u16* __restrict__ Vt, u16* __restrict__ Y)
{
    __shared__ u16 Ks[2][64 * 64];
    __shared__ u16 Vs[2][64 * 64];
    const int tid = threadIdx.x;
    const int wid = tid >> 6, lane = tid & 63;
    const int lr = lane & 15, lg = lane >> 4;
    const int l7 = lr & 7;
    const int fid = blockIdx.x;
    const int xcd = fid & 7, n = fid >> 3;
    const int xtA = n & 7;                   // tile A index (0..7)
    const int xtB = 15 - xtA;                // paired tile B (8..15)
    const int bh = (xcd << 4) | (n >> 3);
    const int bidx = bh >> 4, h = bh & 15;
    const u16* Qp = Q  + (size_t)bh * Ll * Dd;
    const u16* Kp = Kb + (size_t)bh * Ll * Dd;
    const u16* Vp = Vt + (size_t)bh * Ll * Dd;     // (Dd, Ll) layout, zinv-scaled
    // shuffle redistribution constants (R14-verified)
    const int src0 = lr + 32 * (lg & 1);
    const int src1 = src0 + 16;
    const bool selHi = (lg & 2) != 0;
    // LDS read chunk offsets (elem units), XOR-swizzled
    const int ch0 = ((lg ^ l7) << 3);
    const int ch1 = (((4 + lg) ^ l7) << 3);
    // staging source: row tid>>3 (+32 on 2nd inst), chunk XOR-swizzled
    const int srow = tid >> 3;               // 0..31
    const int schunk = (tid & 7) ^ (srow & 7);

    const int iwA = xtA * 64 + wid * 16;
    const int iwB = xtB * 64 + wid * 16;
    bf16x8 qaA0 = *(const bf16x8*)&Qp[(iwA + lr) * Dd + lg * 8];
    bf16x8 qaA1 = *(const bf16x8*)&Qp[(iwA + lr) * Dd + 32 + lg * 8];
    bf16x8 qaB0 = *(const bf16x8*)&Qp[(iwB + lr) * Dd + lg * 8];
    bf16x8 qaB1 = *(const bf16x8*)&Qp[(iwB + lr) * Dd + 32 + lg * 8];
    f32x4 yaccA[4] = {};
    f32x4 yaccB[4] = {};

    const int NS = 17;                       // (xtA+1) + (xtB+1) = 17 steps, uniform
#define JOF(s) (((s) <= xtA) ? 64 * (s) : 64 * ((s) - xtA - 1))

#define STGKV(buf, J) do { \
    const u16* gk_ = Kp + (size_t)((J) + srow) * 64 + schunk * 8; \
    const u16* gv_ = Vp + (size_t)srow * Ll + (J) + schunk * 8; \
    u16* lk_ = &Ks[buf][wid * 512]; \
    u16* lv_ = &Vs[buf][wid * 512]; \
    gload16(gk_,                   lk_); \
    gload16(gk_ + (size_t)32 * 64, lk_ + 2048); \
    gload16(gv_,                   lv_); \
    gload16(gv_ + (size_t)32 * Ll, lv_ + 2048); \
} while (0)

#define PV_STEP(buf, J0, IW, QA0, QA1, YACC) do { \
    const u16* Ks_ = &Ks[buf][0]; \
    const u16* Vs_ = &Vs[buf][0]; \
    uint2 w0, w1, w2, w3; \
    _Pragma("unroll") \
    for (int cs = 0; cs < 4; ++cs) { \
        bf16x8 kb0 = *(const bf16x8*)&Ks_[(cs * 16 + lr) * 64 + ch0]; \
        bf16x8 kb1 = *(const bf16x8*)&Ks_[(cs * 16 + lr) * 64 + ch1]; \
        f32x4 s_ = {0.f, 0.f, 0.f, 0.f}; \
        s_ = __builtin_amdgcn_mfma_f32_16x16x32_bf16(kb0, QA0, s_, 0, 0, 0); \
        s_ = __builtin_amdgcn_mfma_f32_16x16x32_bf16(kb1, QA1, s_, 0, 0, 0); \
        int jb = (J0) + cs * 16; \
        float p[4]; \
        if (jb + 15 <= (IW)) { \
            _Pragma("unroll") \
            for (int r = 0; r < 4; ++r) p[r] = exp2f(s_[r]); \
        } else { \
            int ig = (IW) + lr; \
            _Pragma("unroll") \
            for (int r = 0; r < 4; ++r) \
                p[r] = (jb + 4 * lg + r <= ig) ? exp2f(s_[r]) : 0.f; \
        } \
        uint2 w_; \
        w_.x = pack2bf(p[0], p[1]); \
        w_.y = pack2bf(p[2], p[3]); \
        if (cs == 0) w0 = w_; else if (cs == 1) w1 = w_; \
        else if (cs == 2) w2 = w_; else w3 = w_; \
    } \
    u32 a00 = (u32)__shfl((int)w0.x, src0), a01 = (u32)__shfl((int)w0.y, src0); \
    u32 a02 = (u32)__shfl((int)w0.x, src1), a03 = (u32)__shfl((int)w0.y, src1); \
    u32 a10 = (u32)__shfl((int)w1.x, src0), a11 = (u32)__shfl((int)w1.y, src0); \
    u32 a12 = (u32)__shfl((int)w1.x, src1), a13 = (u32)__shfl((int)w1.y, src1); \
    u32 a20 = (u32)__shfl((int)w2.x, src0), a21 = (u32)__shfl((int)w2.y, src0); \
    u32 a22 = (u32)__shfl((int)w2.x, src1), a23 = (u32)__shfl((int)w2.y, src1); \
    u32 a30 = (u32)__shfl((int)w3.x, src0), a31 = (u32)__shfl((int)w3.y, src0); \
    u32 a32 = (u32)__shfl((int)w3.x, src1), a33 = (u32)__shfl((int)w3.y, src1); \
    u32x4 pa0u, pa1u; \
    pa0u[0] = selHi ? a10 : a00;  pa0u[1] = selHi ? a11 : a01; \
    pa0u[2] = selHi ? a12 : a02;  pa0u[3] = selHi ? a13 : a03; \
    pa1u[0] = selHi ? a30 : a20;  pa1u[1] = selHi ? a31 : a21; \
    pa1u[2] = selHi ? a32 : a22;  pa1u[3] = selHi ? a33 : a23; \
    bf16x8 pa0 = __builtin_bit_cast(bf16x8, pa0u); \
    bf16x8 pa1 = __builtin_bit_cast(bf16x8, pa1u); \
    _Pragma("unroll") \
    for (int ns = 0; ns < 4; ++ns) { \
        bf16x8 vb0 = *(const bf16x8*)&Vs_[(ns * 16 + lr) * 64 + ch0]; \
        bf16x8 vb1 = *(const bf16x8*)&Vs_[(ns * 16 + lr) * 64 + ch1]; \
        YACC[ns] = __builtin_amdgcn_mfma_f32_16x16x32_bf16(pa0, vb0, YACC[ns], 0, 0, 0); \
        YACC[ns] = __builtin_amdgcn_mfma_f32_16x16x32_bf16(pa1, vb1, YACC[ns], 0, 0, 0); \
    } \
} while (0)

    STGKV(0, 0);                     // step 0 (tile A, j0 = 0)
    STGKV(1, JOF(1));                // step 1
    asm volatile("s_waitcnt vmcnt(4)" ::: "memory");   // step0's 4 loads landed
    __builtin_amdgcn_s_barrier();
    __builtin_amdgcn_sched_barrier(0);

    for (int s = 0; s < NS; ++s) {
        if (s <= xtA) { PV_STEP((s & 1), 64 * s, iwA, qaA0, qaA1, yaccA); }
        else          { PV_STEP((s & 1), 64 * (s - xtA - 1), iwB, qaB0, qaB1, yaccB); }
        __builtin_amdgcn_s_barrier();          // all waves done reading buf[s&1]
        __builtin_amdgcn_sched_barrier(0);
        if (s + 2 < NS) STGKV((s & 1), JOF(s + 2));
        if (s + 1 < NS) {
            if (s + 2 < NS) { asm volatile("s_waitcnt vmcnt(4)" ::: "memory"); }
            else            { asm volatile("s_waitcnt vmcnt(0)" ::: "memory"); }
            __builtin_amdgcn_s_barrier();      // all waves' step s+1 landed
            __builtin_amdgcn_sched_barrier(0);
        }
    }
#undef STGKV
#undef PV_STEP
#undef JOF

    #pragma unroll
    for (int ns = 0; ns < 4; ++ns)
        #pragma unroll
        for (int r = 0; r < 4; ++r) {
            int l2 = iwA + lg * 4 + r;
            Y[((size_t)bidx * Ll + l2) * Cc + h * Dd + ns * 16 + lr] = f2b(yaccA[ns][r]);
        }
    #pragma unroll
    for (int ns = 0; ns < 4; ++ns)
        #pragma unroll
        for (int r = 0; r < 4; ++r) {
            int l2 = iwB + lg * 4 + r;
            Y[((size_t)bidx * Ll + l2) * Cc + h * Dd + ns * 16 + lr] = f2b(yaccB[ns][r]);
        }
}

extern "C" void kernel_launch(void* const* d_in, const int* in_sizes, int n_in,
                              void* d_out, int out_size, void* d_ws, size_t ws_size,
                              hipStream_t stream)
{
    const float* x     = (const float*)d_in[0];
    const float* Wqkv  = (const float*)d_in[1];
    const float* bqkv  = (const float*)d_in[2];
    const float* Wproj = (const float*)d_in[3];
    const float* bproj = (const float*)d_in[4];
    float* out = (float*)d_out;

    char* ws = (char*)d_ws;
    u16* xb     = (u16*)(ws + 0);            // x as bf16, 8192x1024         (16 MB)
    u16* WqkvT  = (u16*)(ws + 16777216);     // W_qkv^T bf16, 3072x1024      (6 MB)
    u16* WprojT = (u16*)(ws + 23068672);     // W_proj^T bf16, 1024x1024     (2 MB)
    u16* q      = (u16*)(ws + 25165824);     // (B,H,L,D) bf16, pre-scaled   (16 MB)
    u16* k      = (u16*)(ws + 41943040);     // (B,H,L,D) bf16               (16 MB)
    u16* v      = (u16*)(ws + 58720256);     // (B,H,L,D) bf16; reused as Y  (16 MB)
    u16* vt     = (u16*)(ws + 75497472);     // (B,H,D,L) bf16, zinv-scaled  (16 MB)
    float* zinv = (float*)(ws + 92274688);   // (B*H*L) fp32                 (0.5 MB)

    k_f32_to_bf16<<<dim3(2048), dim3(256), 0, stream>>>(x, xb, Mrows * Cc / 16);
    k_transpose_w<<<dim3(128, 32), dim3(32, 8), 0, stream>>>(Wqkv, WqkvT, Wproj, WprojT);
    k_gemm_qkv32<<<dim3(N3 / 128, Mrows / 128), dim3(256), 0, stream>>>(
        xb, WqkvT, bqkv, q, k, v);
    k_attn_colsum<<<dim3(512), dim3(256), 0, stream>>>(q, k, zinv);
    k_transpose_scale_bf16<<<dim3(2, 32, Bb * Hh), dim3(32, 8), 0, stream>>>(v, zinv, vt, Ll, Dd);
    k_attn_pv<<<dim3(1024), dim3(256), 0, stream>>>(q, k, vt, v);
    k_gemm_proj<<<dim3(Cc / 128, Mrows / 128), dim3(256), 0, stream>>>(
        v, WprojT, bproj, out);
}

// Round 17
// 188.819 us; speedup vs baseline: 1.4585x; 1.0501x over previous
//
#include <hip/hip_runtime.h>

typedef unsigned short u16;
typedef unsigned int   u32;
using bf16x8 = __attribute__((ext_vector_type(8))) short;
using f32x4  = __attribute__((ext_vector_type(4))) float;
using f32x16 = __attribute__((ext_vector_type(16))) float;
using u32x4  = __attribute__((ext_vector_type(4))) u32;

static constexpr int Bb = 8, Ll = 1024, Cc = 1024, Hh = 16, Dd = 64;
static constexpr int Mrows = Bb * Ll;   // 8192
static constexpr int N3    = 3 * Cc;    // 3072
// exp(S/8) = 2^(S * 0.125*log2(e)); fold into q at the QKV epilogue
static constexpr float QSCALE = 0.125f * 1.44269504088896f;

__device__ __forceinline__ u16 f2b(float f) {  // fp32 -> bf16 RNE
    u32 u = __builtin_bit_cast(u32, f);
    u += 0x7FFFu + ((u >> 16) & 1u);
    return (u16)(u >> 16);
}
__device__ __forceinline__ float b2f(u16 u) {
    return __builtin_bit_cast(float, (u32)u << 16);
}
__device__ __forceinline__ u32 pack2bf(float a, float b) {
    return (u32)f2b(a) | ((u32)f2b(b) << 16);
}
// async global->LDS, 16B/lane; LDS dest is wave-uniform base (lane*16 HW-added)
__device__ __forceinline__ void gload16(const u16* g, u16* l) {
    __builtin_amdgcn_global_load_lds(
        (const __attribute__((address_space(1))) void*)g,
        (__attribute__((address_space(3))) void*)l, 16, 0, 0);
}

// ---------------- fp32 -> bf16 convert, 16 elems/thread ----------------
__global__ void k_f32_to_bf16(const float* __restrict__ in, u16* __restrict__ out, int n16) {
    int idx = blockIdx.x * blockDim.x + threadIdx.x;
    if (idx >= n16) return;
    #pragma unroll
    for (int h = 0; h < 2; ++h) {
        f32x4 v0 = *((const f32x4*)in + idx * 4 + h * 2);
        f32x4 v1 = *((const f32x4*)in + idx * 4 + h * 2 + 1);
        u32x4 o;
        o[0] = pack2bf(v0[0], v0[1]);
        o[1] = pack2bf(v0[2], v0[3]);
        o[2] = pack2bf(v1[0], v1[1]);
        o[3] = pack2bf(v1[2], v1[3]);
        *((u32x4*)out + idx * 2 + h) = o;
    }
}

// ---- fused weight transpose+convert: W_qkv (1024x3072) and W_proj (1024x1024) ----
__global__ void k_transpose_w(const float* __restrict__ Wqkv, u16* __restrict__ WqkvT,
                              const float* __restrict__ Wproj, u16* __restrict__ WprojT) {
    __shared__ float tile[32][33];
    int bx = blockIdx.x;
    const float* in; u16* out; int Cn;
    if (bx < 96) { in = Wqkv;  out = WqkvT;  Cn = N3; }
    else         { in = Wproj; out = WprojT; Cn = Cc; bx -= 96; }
    const int R = Cc;   // 1024 rows for both
    int tx = threadIdx.x, ty = threadIdx.y;
    int c = bx * 32 + tx;
    int rbase = blockIdx.y * 32;
    #pragma unroll
    for (int rr = 0; rr < 4; ++rr)
        tile[ty + rr * 8][tx] = in[(size_t)(rbase + ty + rr * 8) * Cn + c];
    __syncthreads();
    int ro = bx * 32 + ty;
    #pragma unroll
    for (int rr = 0; rr < 4; ++rr)
        out[(size_t)(ro + rr * 8) * R + rbase + tx] = f2b(tile[tx][ty + rr * 8]);
}

// --- batched bf16 transpose + zinv row-scale: v (bh,L,D) -> vt (bh,D,L)*zinv[l] ---
__global__ void k_transpose_scale_bf16(const u16* __restrict__ in, const float* __restrict__ zinv,
                                       u16* __restrict__ out, int R, int Cn) {
    __shared__ u16 tile[32][33];
    int bh = blockIdx.z;
    size_t base = (size_t)bh * R * Cn;
    int tx = threadIdx.x, ty = threadIdx.y;
    int c = blockIdx.x * 32 + tx;
    int rbase = blockIdx.y * 32;
    #pragma unroll
    for (int rr = 0; rr < 4; ++rr)
        tile[ty + rr * 8][tx] = in[base + (size_t)(rbase + ty + rr * 8) * Cn + c];
    __syncthreads();
    float zv = zinv[(size_t)bh * R + rbase + tx];   // L index is rbase+tx for all rr
    int ro = blockIdx.x * 32 + ty;
    #pragma unroll
    for (int rr = 0; rr < 4; ++rr)
        out[base + (size_t)(ro + rr * 8) * R + rbase + tx] = f2b(b2f(tile[tx][ty + rr * 8]) * zv);
}

// ======== QKV GEMM v3: 32x32x16 MFMA, 128^2 tile, BK=64, dbuf, 2 blocks/CU ========
// R10-proven (took QKV out of the top-5). DO NOT PERTURB.
__global__ __launch_bounds__(256, 2)
void k_gemm_qkv32(const u16* __restrict__ A, const u16* __restrict__ Bt,
                  const float* __restrict__ bias,
                  u16* __restrict__ qo, u16* __restrict__ ko, u16* __restrict__ vo)
{
    const int K = Cc;            // 1024
    const int NT = K / 64;       // 16 K-tiles
    __shared__ u16 As[2][128 * 64];
    __shared__ u16 Bs[2][128 * 64];
    const int tid = threadIdx.x;
    const int wid = tid >> 6, lane = tid & 63;
    const int l31 = lane & 31, lhi = lane >> 5, l7 = lane & 7;
    const int wr = wid >> 1, wc = wid & 1;       // 2x2 waves, 64x64 each
    const int nwg = gridDim.x * gridDim.y;       // 1536, %8==0
    const int flat = blockIdx.y * gridDim.x + blockIdx.x;
    const int swz = (flat & 7) * (nwg >> 3) + (flat >> 3);
    const int bx = swz % gridDim.x, by = swz / gridDim.x;
    const int row0 = by * 128, col0 = bx * 128;

    const int srow = tid >> 3;
    const int schunk = (tid & 7) ^ (srow & 7);
    const u16* gA = A  + (size_t)(row0 + srow) * K + schunk * 8;
    const u16* gB = Bt + (size_t)(col0 + srow) * K + schunk * 8;

#define STG(buf, t) do { \
    const u16* ga_ = gA + (size_t)(t) * 64; \
    const u16* gb_ = gB + (size_t)(t) * 64; \
    u16* la_ = &As[buf][wid * 512]; \
    u16* lb_ = &Bs[buf][wid * 512]; \
    gload16(ga_,                  la_); \
    gload16(ga_ + (size_t)32 * K, la_ + 2048); \
    gload16(ga_ + (size_t)64 * K, la_ + 4096); \
    gload16(ga_ + (size_t)96 * K, la_ + 6144); \
    gload16(gb_,                  lb_); \
    gload16(gb_ + (size_t)32 * K, lb_ + 2048); \
    gload16(gb_ + (size_t)64 * K, lb_ + 4096); \
    gload16(gb_ + (size_t)96 * K, lb_ + 6144); \
} while (0)

    const int coff0 = (((0 + lhi) ^ l7) << 3);
    const int coff1 = (((2 + lhi) ^ l7) << 3);
    const int coff2 = (((4 + lhi) ^ l7) << 3);
    const int coff3 = (((6 + lhi) ^ l7) << 3);
    const int coff[4] = { coff0, coff1, coff2, coff3 };

    f32x16 acc[2][2] = {};

    STG(0, 0);
    STG(1, 1);
    asm volatile("s_waitcnt vmcnt(8)" ::: "memory");   // tile0's 8 loads landed
    __builtin_amdgcn_s_barrier();
    __builtin_amdgcn_sched_barrier(0);

    for (int t = 0; t < NT; ++t) {
        const u16* cA = &As[t & 1][0];
        const u16* cB = &Bs[t & 1][0];
        // ---- phase 0: A frags (held) + B tn=0, 8 MFMA ----
        bf16x8 af[2][4], bf0[4];
        #pragma unroll
        for (int tm = 0; tm < 2; ++tm)
            #pragma unroll
            for (int kc = 0; kc < 4; ++kc)
                af[tm][kc] = *(const bf16x8*)&cA[(wr * 64 + tm * 32 + l31) * 64 + coff[kc]];
        #pragma unroll
        for (int kc = 0; kc < 4; ++kc)
            bf0[kc] = *(const bf16x8*)&cB[(wc * 64 + l31) * 64 + coff[kc]];
        __builtin_amdgcn_s_setprio(1);
        #pragma unroll
        for (int tm = 0; tm < 2; ++tm)
            #pragma unroll
            for (int kc = 0; kc < 4; ++kc)
                acc[tm][0] = __builtin_amdgcn_mfma_f32_32x32x16_bf16(
                    af[tm][kc], bf0[kc], acc[tm][0], 0, 0, 0);
        __builtin_amdgcn_s_setprio(0);
        __builtin_amdgcn_s_barrier();
        // ---- phase 1: B tn=1, 8 MFMA ----
        bf16x8 bf1[4];
        #pragma unroll
        for (int kc = 0; kc < 4; ++kc)
            bf1[kc] = *(const bf16x8*)&cB[(wc * 64 + 32 + l31) * 64 + coff[kc]];
        __builtin_amdgcn_s_setprio(1);
        #pragma unroll
        for (int tm = 0; tm < 2; ++tm)
            #pragma unroll
            for (int kc = 0; kc < 4; ++kc)
                acc[tm][1] = __builtin_amdgcn_mfma_f32_32x32x16_bf16(
                    af[tm][kc], bf1[kc], acc[tm][1], 0, 0, 0);
        __builtin_amdgcn_s_setprio(0);
        __builtin_amdgcn_s_barrier();          // all waves done reading buf[t&1]
        __builtin_amdgcn_sched_barrier(0);
        if (t + 2 < NT) STG(t & 1, t + 2);
        if (t + 1 < NT) {
            if (t + 2 < NT) { asm volatile("s_waitcnt vmcnt(8)" ::: "memory"); }
            else            { asm volatile("s_waitcnt vmcnt(0)" ::: "memory"); }
            __builtin_amdgcn_s_barrier();      // all waves' t+1 landed
            __builtin_amdgcn_sched_barrier(0);
        }
    }
#undef STG

    // epilogue: q/k/v scatter to (B,H,L,D); 32x32 C/D layout
    #pragma unroll
    for (int tm = 0; tm < 2; ++tm) {
        #pragma unroll
        for (int tn = 0; tn < 2; ++tn) {
            int cg = col0 + wc * 64 + tn * 32 + l31;
            float bv = bias[cg];
            int which = cg >> 10;         // 0=q 1=k 2=v
            float sc = (which == 0) ? QSCALE : 1.0f;
            int cc2 = cg & 1023;
            int h = cc2 >> 6, dd = cc2 & 63;
            int rbase = row0 + wr * 64 + tm * 32 + 4 * lhi;
            #pragma unroll
            for (int g = 0; g < 4; ++g) {
                #pragma unroll
                for (int r = 0; r < 4; ++r) {
                    int rg = rbase + 8 * g + r;
                    int bidx = rg >> 10, ll2 = rg & 1023;
                    size_t o = ((size_t)(bidx * Hh + h) * Ll + ll2) * Dd + dd;
                    u16 val = f2b((acc[tm][tn][g * 4 + r] + bv) * sc);
                    if (which == 0) qo[o] = val;
                    else if (which == 1) ko[o] = val;
                    else vo[o] = val;
                }
            }
        }
    }
}

// ---- proj GEMM: 2-phase dbuf + global_load_lds + source-side XOR swizzle ----
__global__ __launch_bounds__(256)
void k_gemm_proj(const u16* __restrict__ A, const u16* __restrict__ Bt,
                 const float* __restrict__ bias, float* __restrict__ outf)
{
    const int N = Cc, K = Cc;
    __shared__ u16 As[2][128 * 32];
    __shared__ u16 Bs[2][128 * 32];
    const int tid = threadIdx.x;
    const int wid = tid >> 6, lane = tid & 63;
    const int lr = lane & 15, lg = lane >> 4;
    const int wr = wid >> 1, wc = wid & 1;
    const int nwg = gridDim.x * gridDim.y;
    const int flat = blockIdx.y * gridDim.x + blockIdx.x;
    const int swz = (flat & 7) * (nwg >> 3) + (flat >> 3);
    const int bx = swz % gridDim.x, by = swz / gridDim.x;
    const int row0 = by * 128, col0 = bx * 128;

    const int srow = wid * 32 + (lane >> 2);
    const int schk = (lane & 3) ^ (srow & 3);
    const u16* aP = A  + (size_t)(row0 + srow) * K + schk * 8;
    const u16* bP = Bt + (size_t)(col0 + srow) * K + schk * 8;
    const size_t r16 = (size_t)16 * K;
    u16* aL0 = &As[0][wid * 32 * 32]; u16* aL0b = aL0 + 16 * 32;
    u16* bL0 = &Bs[0][wid * 32 * 32]; u16* bL0b = bL0 + 16 * 32;
    u16* aL1 = &As[1][wid * 32 * 32]; u16* aL1b = aL1 + 16 * 32;
    u16* bL1 = &Bs[1][wid * 32 * 32]; u16* bL1b = bL1 + 16 * 32;

    f32x4 acc[4][4] = {};

#define STAGE0(kk) { gload16(aP + (kk), aL0); gload16(aP + r16 + (kk), aL0b); \
                     gload16(bP + (kk), bL0); gload16(bP + r16 + (kk), bL0b); }
#define STAGE1(kk) { gload16(aP + (kk), aL1); gload16(aP + r16 + (kk), aL1b); \
                     gload16(bP + (kk), bL1); gload16(bP + r16 + (kk), bL1b); }
#define COMPUTE(bufi) { \
        bf16x8 af[4], bfv[4]; \
        _Pragma("unroll") \
        for (int m = 0; m < 4; ++m) { int rw = wr * 64 + m * 16 + lr; \
            af[m] = *(const bf16x8*)&As[bufi][rw * 32 + ((lg ^ (rw & 3)) * 8)]; } \
        _Pragma("unroll") \
        for (int n = 0; n < 4; ++n) { int rw = wc * 64 + n * 16 + lr; \
            bfv[n] = *(const bf16x8*)&Bs[bufi][rw * 32 + ((lg ^ (rw & 3)) * 8)]; } \
        _Pragma("unroll") \
        for (int m = 0; m < 4; ++m) \
            _Pragma("unroll") \
            for (int n = 0; n < 4; ++n) \
                acc[m][n] = __builtin_amdgcn_mfma_f32_16x16x32_bf16(af[m], bfv[n], acc[m][n], 0, 0, 0); }

    STAGE0(0);
    __syncthreads();
    for (int k0 = 0; k0 < K; k0 += 64) {
        if (k0 + 32 < K) STAGE1(k0 + 32);
        COMPUTE(0);
        __syncthreads();
        if (k0 + 64 < K) STAGE0(k0 + 64);
        COMPUTE(1);
        __syncthreads();
    }
#undef STAGE0
#undef STAGE1
#undef COMPUTE

    #pragma unroll
    for (int m = 0; m < 4; ++m) {
        int rb2 = row0 + wr * 64 + m * 16 + lg * 4;
        #pragma unroll
        for (int n = 0; n < 4; ++n) {
            int cg = col0 + wc * 64 + n * 16 + lr;
            float bv = bias[cg];
            #pragma unroll
            for (int r = 0; r < 4; ++r)
                outf[(size_t)(rb2 + r) * N + cg] = acc[m][n][r] + bv;
        }
    }
}

// ---------------- attention pass 1: column sums (LDS-staged Q pipeline) ----------------
// Ported to the R16-proven async skeleton: per step, stage a 64x64 Q-tile into
// double-buffered LDS (shared by all 4 waves), counted vmcnt(2), raw barriers,
// both-sides XOR swizzle. K frags held in registers per wave (16 cols each).
// Paired 64-col tiles (xt, 15-xt) fused into ONE uniform 17-step pipeline.
// Grid 1024 = 4 blocks/CU. Masking per 16-row subtile: skip (ib<jw), diagonal
// (ib==jw, dmask), else unmasked.
__global__ __launch_bounds__(256, 4)
void k_attn_colsum(const u16* __restrict__ Q, const u16* __restrict__ Kb,
                   float* __restrict__ zinv)
{
    __shared__ u16 Qs[2][64 * 64];
    const int tid = threadIdx.x;
    const int wid = tid >> 6, lane = tid & 63;
    const int lr = lane & 15, lg = lane >> 4;
    const int l7 = lr & 7;
    const int fid = blockIdx.x;
    const int xcd = fid & 7, n = fid >> 3;
    const int xtA = n & 7;                   // col tile A (0..7)
    const int xtB = 15 - xtA;                // paired tile B (8..15)
    const int bh = (xcd << 4) | (n >> 3);
    const u16* Qp = Q  + (size_t)bh * Ll * Dd;
    const u16* Kp = Kb + (size_t)bh * Ll * Dd;
    const int jwA = xtA * 64 + wid * 16;
    const int jwB = xtB * 64 + wid * 16;
    // K fragments held in regs: col j = jw + lr
    bf16x8 kbA0 = *(const bf16x8*)&Kp[(jwA + lr) * Dd + lg * 8];
    bf16x8 kbA1 = *(const bf16x8*)&Kp[(jwA + lr) * Dd + 32 + lg * 8];
    bf16x8 kbB0 = *(const bf16x8*)&Kp[(jwB + lr) * Dd + lg * 8];
    bf16x8 kbB1 = *(const bf16x8*)&Kp[(jwB + lr) * Dd + 32 + lg * 8];
    const bool dmask[4] = { lg * 4 + 0 >= lr, lg * 4 + 1 >= lr,
                            lg * 4 + 2 >= lr, lg * 4 + 3 >= lr };
    const int ch0 = ((lg ^ l7) << 3);
    const int ch1 = (((4 + lg) ^ l7) << 3);
    const int srow = tid >> 3;               // 0..31
    const int schunk = (tid & 7) ^ (srow & 7);
    float zA = 0.f, zB = 0.f;

    const int nA = 16 - xtA;                 // steps for tile A; nB = 16-xtB = 1+xtA
    const int NS = 17;
#define IOF(s) (((s) < nA) ? (xtA * 64 + 64 * (s)) : (xtB * 64 + 64 * ((s) - nA)))

#define STGQ(buf, I0) do { \
    const u16* g_ = Qp + (size_t)((I0) + srow) * 64 + schunk * 8; \
    u16* l_ = &Qs[buf][wid * 512]; \
    gload16(g_,                   l_); \
    gload16(g_ + (size_t)32 * 64, l_ + 2048); \
} while (0)

#define CS_STEP(buf, I0, JW, KB0, KB1, ZACC) do { \
    const u16* Qs_ = &Qs[buf][0]; \
    _Pragma("unroll") \
    for (int ss = 0; ss < 4; ++ss) { \
        int ib = (I0) + ss * 16; \
        if (ib >= (JW)) { \
            bf16x8 qa0 = *(const bf16x8*)&Qs_[(ss * 16 + lr) * 64 + ch0]; \
            bf16x8 qa1 = *(const bf16x8*)&Qs_[(ss * 16 + lr) * 64 + ch1]; \
            f32x4 s_ = {0.f, 0.f, 0.f, 0.f}; \
            s_ = __builtin_amdgcn_mfma_f32_16x16x32_bf16(qa0, KB0, s_, 0, 0, 0); \
            s_ = __builtin_amdgcn_mfma_f32_16x16x32_bf16(qa1, KB1, s_, 0, 0, 0); \
            if (ib >= (JW) + 16) { \
                _Pragma("unroll") \
                for (int r = 0; r < 4; ++r) ZACC += exp2f(s_[r]); \
            } else { \
                _Pragma("unroll") \
                for (int r = 0; r < 4; ++r) ZACC += dmask[r] ? exp2f(s_[r]) : 0.f; \
            } \
        } \
    } \
} while (0)

    STGQ(0, IOF(0));
    STGQ(1, IOF(1));
    asm volatile("s_waitcnt vmcnt(2)" ::: "memory");   // step0's 2 loads landed
    __builtin_amdgcn_s_barrier();
    __builtin_amdgcn_sched_barrier(0);

    for (int s = 0; s < NS; ++s) {
        if (s < nA) { CS_STEP((s & 1), xtA * 64 + 64 * s, jwA, kbA0, kbA1, zA); }
        else        { CS_STEP((s & 1), xtB * 64 + 64 * (s - nA), jwB, kbB0, kbB1, zB); }
        __builtin_amdgcn_s_barrier();          // all waves done reading buf[s&1]
        __builtin_amdgcn_sched_barrier(0);
        if (s + 2 < NS) STGQ((s & 1), IOF(s + 2));
        if (s + 1 < NS) {
            if (s + 2 < NS) { asm volatile("s_waitcnt vmcnt(2)" ::: "memory"); }
            else            { asm volatile("s_waitcnt vmcnt(0)" ::: "memory"); }
            __builtin_amdgcn_s_barrier();      // all waves' step s+1 landed
            __builtin_amdgcn_sched_barrier(0);
        }
    }
#undef STGQ
#undef CS_STEP
#undef IOF

    zA += __shfl_xor(zA, 16); zA += __shfl_xor(zA, 32);
    zB += __shfl_xor(zB, 16); zB += __shfl_xor(zB, 32);
    if (lg == 0) {
        zinv[(size_t)bh * Ll + jwA + lr] = 1.f / zA;
        zinv[(size_t)bh * Ll + jwB + lr] = 1.f / zB;
    }
}

// ---------------- attention pass 2: Y = exp(S') @ V'  (LDS-staged K/V pipeline) ----------------
// R16-proven (pv left the top-5). DO NOT PERTURB.
__global__ __launch_bounds__(256, 4)
void k_attn_pv(const u16* __restrict__ Q, const u16* __restrict__ Kb,
               const u16* __restrict__ Vt, u16* __restrict__ Y)
{
    __shared__ u16 Ks[2][64 * 64];
    __shared__ u16 Vs[2][64 * 64];
    const int tid = threadIdx.x;
    const int wid = tid >> 6, lane = tid & 63;
    const int lr = lane & 15, lg = lane >> 4;
    const int l7 = lr & 7;
    const int fid = blockIdx.x;
    const int xcd = fid & 7, n = fid >> 3;
    const int xtA = n & 7;                   // tile A index (0..7)
    const int xtB = 15 - xtA;                // paired tile B (8..15)
    const int bh = (xcd << 4) | (n >> 3);
    const int bidx = bh >> 4, h = bh & 15;
    const u16* Qp = Q  + (size_t)bh * Ll * Dd;
    const u16* Kp = Kb + (size_t)bh * Ll * Dd;
    const u16* Vp = Vt + (size_t)bh * Ll * Dd;     // (Dd, Ll) layout, zinv-scaled
    const int src0 = lr + 32 * (lg & 1);
    const int src1 = src0 + 16;
    const bool selHi = (lg & 2) != 0;
    const int ch0 = ((lg ^ l7) << 3);
    const int ch1 = (((4 + lg) ^ l7) << 3);
    const int srow = tid >> 3;               // 0..31
    const int schunk = (tid & 7) ^ (srow & 7);

    const int iwA = xtA * 64 + wid * 16;
    const int iwB = xtB * 64 + wid * 16;
    bf16x8 qaA0 = *(const bf16x8*)&Qp[(iwA + lr) * Dd + lg * 8];
    bf16x8 qaA1 = *(const bf16x8*)&Qp[(iwA + lr) * Dd + 32 + lg * 8];
    bf16x8 qaB0 = *(const bf16x8*)&Qp[(iwB + lr) * Dd + lg * 8];
    bf16x8 qaB1 = *(const bf16x8*)&Qp[(iwB + lr) * Dd + 32 + lg * 8];
    f32x4 yaccA[4] = {};
    f32x4 yaccB[4] = {};

    const int NS = 17;                       // (xtA+1) + (xtB+1) = 17 steps, uniform
#define JOF(s) (((s) <= xtA) ? 64 * (s) : 64 * ((s) - xtA - 1))

#define STGKV(buf, J) do { \
    const u16* gk_ = Kp + (size_t)((J) + srow) * 64 + schunk * 8; \
    const u16* gv_ = Vp + (size_t)srow * Ll + (J) + schunk * 8; \
    u16* lk_ = &Ks[buf][wid * 512]; \
    u16* lv_ = &Vs[buf][wid * 512]; \
    gload16(gk_,                   lk_); \
    gload16(gk_ + (size_t)32 * 64, lk_ + 2048); \
    gload16(gv_,                   lv_); \
    gload16(gv_ + (size_t)32 * Ll, lv_ + 2048); \
} while (0)

#define PV_STEP(buf, J0, IW, QA0, QA1, YACC) do { \
    const u16* Ks_ = &Ks[buf][0]; \
    const u16* Vs_ = &Vs[buf][0]; \
    uint2 w0, w1, w2, w3; \
    _Pragma("unroll") \
    for (int cs = 0; cs < 4; ++cs) { \
        bf16x8 kb0 = *(const bf16x8*)&Ks_[(cs * 16 + lr) * 64 + ch0]; \
        bf16x8 kb1 = *(const bf16x8*)&Ks_[(cs * 16 + lr) * 64 + ch1]; \
        f32x4 s_ = {0.f, 0.f, 0.f, 0.f}; \
        s_ = __builtin_amdgcn_mfma_f32_16x16x32_bf16(kb0, QA0, s_, 0, 0, 0); \
        s_ = __builtin_amdgcn_mfma_f32_16x16x32_bf16(kb1, QA1, s_, 0, 0, 0); \
        int jb = (J0) + cs * 16; \
        float p[4]; \
        if (jb + 15 <= (IW)) { \
            _Pragma("unroll") \
            for (int r = 0; r < 4; ++r) p[r] = exp2f(s_[r]); \
        } else { \
            int ig = (IW) + lr; \
            _Pragma("unroll") \
            for (int r = 0; r < 4; ++r) \
                p[r] = (jb + 4 * lg + r <= ig) ? exp2f(s_[r]) : 0.f; \
        } \
        uint2 w_; \
        w_.x = pack2bf(p[0], p[1]); \
        w_.y = pack2bf(p[2], p[3]); \
        if (cs == 0) w0 = w_; else if (cs == 1) w1 = w_; \
        else if (cs == 2) w2 = w_; else w3 = w_; \
    } \
    u32 a00 = (u32)__shfl((int)w0.x, src0), a01 = (u32)__shfl((int)w0.y, src0); \
    u32 a02 = (u32)__shfl((int)w0.x, src1), a03 = (u32)__shfl((int)w0.y, src1); \
    u32 a10 = (u32)__shfl((int)w1.x, src0), a11 = (u32)__shfl((int)w1.y, src0); \
    u32 a12 = (u32)__shfl((int)w1.x, src1), a13 = (u32)__shfl((int)w1.y, src1); \
    u32 a20 = (u32)__shfl((int)w2.x, src0), a21 = (u32)__shfl((int)w2.y, src0); \
    u32 a22 = (u32)__shfl((int)w2.x, src1), a23 = (u32)__shfl((int)w2.y, src1); \
    u32 a30 = (u32)__shfl((int)w3.x, src0), a31 = (u32)__shfl((int)w3.y, src0); \
    u32 a32 = (u32)__shfl((int)w3.x, src1), a33 = (u32)__shfl((int)w3.y, src1); \
    u32x4 pa0u, pa1u; \
    pa0u[0] = selHi ? a10 : a00;  pa0u[1] = selHi ? a11 : a01; \
    pa0u[2] = selHi ? a12 : a02;  pa0u[3] = selHi ? a13 : a03; \
    pa1u[0] = selHi ? a30 : a20;  pa1u[1] = selHi ? a31 : a21; \
    pa1u[2] = selHi ? a32 : a22;  pa1u[3] = selHi ? a33 : a23; \
    bf16x8 pa0 = __builtin_bit_cast(bf16x8, pa0u); \
    bf16x8 pa1 = __builtin_bit_cast(bf16x8, pa1u); \
    _Pragma("unroll") \
    for (int ns = 0; ns < 4; ++ns) { \
        bf16x8 vb0 = *(const bf16x8*)&Vs_[(ns * 16 + lr) * 64 + ch0]; \
        bf16x8 vb1 = *(const bf16x8*)&Vs_[(ns * 16 + lr) * 64 + ch1]; \
        YACC[ns] = __builtin_amdgcn_mfma_f32_16x16x32_bf16(pa0, vb0, YACC[ns], 0, 0, 0); \
        YACC[ns] = __builtin_amdgcn_mfma_f32_16x16x32_bf16(pa1, vb1, YACC[ns], 0, 0, 0); \
    } \
} while (0)

    STGKV(0, 0);                     // step 0 (tile A, j0 = 0)
    STGKV(1, JOF(1));                // step 1
    asm volatile("s_waitcnt vmcnt(4)" ::: "memory");   // step0's 4 loads landed
    __builtin_amdgcn_s_barrier();
    __builtin_amdgcn_sched_barrier(0);

    for (int s = 0; s < NS; ++s) {
        if (s <= xtA) { PV_STEP((s & 1), 64 * s, iwA, qaA0, qaA1, yaccA); }
        else          { PV_STEP((s & 1), 64 * (s - xtA - 1), iwB, qaB0, qaB1, yaccB); }
        __builtin_amdgcn_s_barrier();          // all waves done reading buf[s&1]
        __builtin_amdgcn_sched_barrier(0);
        if (s + 2 < NS) STGKV((s & 1), JOF(s + 2));
        if (s + 1 < NS) {
            if (s + 2 < NS) { asm volatile("s_waitcnt vmcnt(4)" ::: "memory"); }
            else            { asm volatile("s_waitcnt vmcnt(0)" ::: "memory"); }
            __builtin_amdgcn_s_barrier();      // all waves' step s+1 landed
            __builtin_amdgcn_sched_barrier(0);
        }
    }
#undef STGKV
#undef PV_STEP
#undef JOF

    #pragma unroll
    for (int ns = 0; ns < 4; ++ns)
        #pragma unroll
        for (int r = 0; r < 4; ++r) {
            int l2 = iwA + lg * 4 + r;
            Y[((size_t)bidx * Ll + l2) * Cc + h * Dd + ns * 16 + lr] = f2b(yaccA[ns][r]);
        }
    #pragma unroll
    for (int ns = 0; ns < 4; ++ns)
        #pragma unroll
        for (int r = 0; r < 4; ++r) {
            int l2 = iwB + lg * 4 + r;
            Y[((size_t)bidx * Ll + l2) * Cc + h * Dd + ns * 16 + lr] = f2b(yaccB[ns][r]);
        }
}

extern "C" void kernel_launch(void* const* d_in, const int* in_sizes, int n_in,
                              void* d_out, int out_size, void* d_ws, size_t ws_size,
                              hipStream_t stream)
{
    const float* x     = (const float*)d_in[0];
    const float* Wqkv  = (const float*)d_in[1];
    const float* bqkv  = (const float*)d_in[2];
    const float* Wproj = (const float*)d_in[3];
    const float* bproj = (const float*)d_in[4];
    float* out = (float*)d_out;

    char* ws = (char*)d_ws;
    u16* xb     = (u16*)(ws + 0);            // x as bf16, 8192x1024         (16 MB)
    u16* WqkvT  = (u16*)(ws + 16777216);     // W_qkv^T bf16, 3072x1024      (6 MB)
    u16* WprojT = (u16*)(ws + 23068672);     // W_proj^T bf16, 1024x1024     (2 MB)
    u16* q      = (u16*)(ws + 25165824);     // (B,H,L,D) bf16, pre-scaled   (16 MB)
    u16* k      = (u16*)(ws + 41943040);     // (B,H,L,D) bf16               (16 MB)
    u16* v      = (u16*)(ws + 58720256);     // (B,H,L,D) bf16; reused as Y  (16 MB)
    u16* vt     = (u16*)(ws + 75497472);     // (B,H,D,L) bf16, zinv-scaled  (16 MB)
    float* zinv = (float*)(ws + 92274688);   // (B*H*L) fp32                 (0.5 MB)

    k_f32_to_bf16<<<dim3(2048), dim3(256), 0, stream>>>(x, xb, Mrows * Cc / 16);
    k_transpose_w<<<dim3(128, 32), dim3(32, 8), 0, stream>>>(Wqkv, WqkvT, Wproj, WprojT);
    k_gemm_qkv32<<<dim3(N3 / 128, Mrows / 128), dim3(256), 0, stream>>>(
        xb, WqkvT, bqkv, q, k, v);
    k_attn_colsum<<<dim3(1024), dim3(256), 0, stream>>>(q, k, zinv);
    k_transpose_scale_bf16<<<dim3(2, 32, Bb * Hh), dim3(32, 8), 0, stream>>>(v, zinv, vt, Ll, Dd);
    k_attn_pv<<<dim3(1024), dim3(256), 0, stream>>>(q, k, vt, v);
    k_gemm_proj<<<dim3(Cc / 128, Mrows / 128), dim3(256), 0, stream>>>(
        v, WprojT, bproj, out);
}

// Round 18
// 183.893 us; speedup vs baseline: 1.4976x; 1.0268x over previous
//
#include <hip/hip_runtime.h>

typedef unsigned short u16;
typedef unsigned int   u32;
using bf16x8 = __attribute__((ext_vector_type(8))) short;
using f32x4  = __attribute__((ext_vector_type(4))) float;
using f32x16 = __attribute__((ext_vector_type(16))) float;
using u32x4  = __attribute__((ext_vector_type(4))) u32;

static constexpr int Bb = 8, Ll = 1024, Cc = 1024, Hh = 16, Dd = 64;
static constexpr int Mrows = Bb * Ll;   // 8192
static constexpr int N3    = 3 * Cc;    // 3072
// exp(S/8) = 2^(S * 0.125*log2(e)); fold into q at the QKV epilogue
static constexpr float QSCALE = 0.125f * 1.44269504088896f;

__device__ __forceinline__ u16 f2b(float f) {  // fp32 -> bf16 RNE
    u32 u = __builtin_bit_cast(u32, f);
    u += 0x7FFFu + ((u >> 16) & 1u);
    return (u16)(u >> 16);
}
__device__ __forceinline__ float b2f(u16 u) {
    return __builtin_bit_cast(float, (u32)u << 16);
}
__device__ __forceinline__ u32 pack2bf(float a, float b) {
    return (u32)f2b(a) | ((u32)f2b(b) << 16);
}
// async global->LDS, 16B/lane; LDS dest is wave-uniform base (lane*16 HW-added)
__device__ __forceinline__ void gload16(const u16* g, u16* l) {
    __builtin_amdgcn_global_load_lds(
        (const __attribute__((address_space(1))) void*)g,
        (__attribute__((address_space(3))) void*)l, 16, 0, 0);
}

// ---------------- fp32 -> bf16 convert, 16 elems/thread ----------------
__global__ void k_f32_to_bf16(const float* __restrict__ in, u16* __restrict__ out, int n16) {
    int idx = blockIdx.x * blockDim.x + threadIdx.x;
    if (idx >= n16) return;
    #pragma unroll
    for (int h = 0; h < 2; ++h) {
        f32x4 v0 = *((const f32x4*)in + idx * 4 + h * 2);
        f32x4 v1 = *((const f32x4*)in + idx * 4 + h * 2 + 1);
        u32x4 o;
        o[0] = pack2bf(v0[0], v0[1]);
        o[1] = pack2bf(v0[2], v0[3]);
        o[2] = pack2bf(v1[0], v1[1]);
        o[3] = pack2bf(v1[2], v1[3]);
        *((u32x4*)out + idx * 2 + h) = o;
    }
}

// ---- fused weight transpose+convert: W_qkv (1024x3072) and W_proj (1024x1024) ----
__global__ void k_transpose_w(const float* __restrict__ Wqkv, u16* __restrict__ WqkvT,
                              const float* __restrict__ Wproj, u16* __restrict__ WprojT) {
    __shared__ float tile[32][33];
    int bx = blockIdx.x;
    const float* in; u16* out; int Cn;
    if (bx < 96) { in = Wqkv;  out = WqkvT;  Cn = N3; }
    else         { in = Wproj; out = WprojT; Cn = Cc; bx -= 96; }
    const int R = Cc;   // 1024 rows for both
    int tx = threadIdx.x, ty = threadIdx.y;
    int c = bx * 32 + tx;
    int rbase = blockIdx.y * 32;
    #pragma unroll
    for (int rr = 0; rr < 4; ++rr)
        tile[ty + rr * 8][tx] = in[(size_t)(rbase + ty + rr * 8) * Cn + c];
    __syncthreads();
    int ro = bx * 32 + ty;
    #pragma unroll
    for (int rr = 0; rr < 4; ++rr)
        out[(size_t)(ro + rr * 8) * R + rbase + tx] = f2b(tile[tx][ty + rr * 8]);
}

// --- batched bf16 transpose + zinv row-scale: v (bh,L,D) -> vt (bh,D,L)*zinv[l] ---
__global__ void k_transpose_scale_bf16(const u16* __restrict__ in, const float* __restrict__ zinv,
                                       u16* __restrict__ out, int R, int Cn) {
    __shared__ u16 tile[32][33];
    int bh = blockIdx.z;
    size_t base = (size_t)bh * R * Cn;
    int tx = threadIdx.x, ty = threadIdx.y;
    int c = blockIdx.x * 32 + tx;
    int rbase = blockIdx.y * 32;
    #pragma unroll
    for (int rr = 0; rr < 4; ++rr)
        tile[ty + rr * 8][tx] = in[base + (size_t)(rbase + ty + rr * 8) * Cn + c];
    __syncthreads();
    float zv = zinv[(size_t)bh * R + rbase + tx];   // L index is rbase+tx for all rr
    int ro = blockIdx.x * 32 + ty;
    #pragma unroll
    for (int rr = 0; rr < 4; ++rr)
        out[base + (size_t)(ro + rr * 8) * R + rbase + tx] = f2b(b2f(tile[tx][ty + rr * 8]) * zv);
}

// ======== QKV GEMM v3: 32x32x16 MFMA, 128^2 tile, BK=64, dbuf, 2 blocks/CU ========
// R10-proven (took QKV out of the top-5). DO NOT PERTURB.
__global__ __launch_bounds__(256, 2)
void k_gemm_qkv32(const u16* __restrict__ A, const u16* __restrict__ Bt,
                  const float* __restrict__ bias,
                  u16* __restrict__ qo, u16* __restrict__ ko, u16* __restrict__ vo)
{
    const int K = Cc;            // 1024
    const int NT = K / 64;       // 16 K-tiles
    __shared__ u16 As[2][128 * 64];
    __shared__ u16 Bs[2][128 * 64];
    const int tid = threadIdx.x;
    const int wid = tid >> 6, lane = tid & 63;
    const int l31 = lane & 31, lhi = lane >> 5, l7 = lane & 7;
    const int wr = wid >> 1, wc = wid & 1;       // 2x2 waves, 64x64 each
    const int nwg = gridDim.x * gridDim.y;       // 1536, %8==0
    const int flat = blockIdx.y * gridDim.x + blockIdx.x;
    const int swz = (flat & 7) * (nwg >> 3) + (flat >> 3);
    const int bx = swz % gridDim.x, by = swz / gridDim.x;
    const int row0 = by * 128, col0 = bx * 128;

    const int srow = tid >> 3;
    const int schunk = (tid & 7) ^ (srow & 7);
    const u16* gA = A  + (size_t)(row0 + srow) * K + schunk * 8;
    const u16* gB = Bt + (size_t)(col0 + srow) * K + schunk * 8;

#define STG(buf, t) do { \
    const u16* ga_ = gA + (size_t)(t) * 64; \
    const u16* gb_ = gB + (size_t)(t) * 64; \
    u16* la_ = &As[buf][wid * 512]; \
    u16* lb_ = &Bs[buf][wid * 512]; \
    gload16(ga_,                  la_); \
    gload16(ga_ + (size_t)32 * K, la_ + 2048); \
    gload16(ga_ + (size_t)64 * K, la_ + 4096); \
    gload16(ga_ + (size_t)96 * K, la_ + 6144); \
    gload16(gb_,                  lb_); \
    gload16(gb_ + (size_t)32 * K, lb_ + 2048); \
    gload16(gb_ + (size_t)64 * K, lb_ + 4096); \
    gload16(gb_ + (size_t)96 * K, lb_ + 6144); \
} while (0)

    const int coff0 = (((0 + lhi) ^ l7) << 3);
    const int coff1 = (((2 + lhi) ^ l7) << 3);
    const int coff2 = (((4 + lhi) ^ l7) << 3);
    const int coff3 = (((6 + lhi) ^ l7) << 3);
    const int coff[4] = { coff0, coff1, coff2, coff3 };

    f32x16 acc[2][2] = {};

    STG(0, 0);
    STG(1, 1);
    asm volatile("s_waitcnt vmcnt(8)" ::: "memory");   // tile0's 8 loads landed
    __builtin_amdgcn_s_barrier();
    __builtin_amdgcn_sched_barrier(0);

    for (int t = 0; t < NT; ++t) {
        const u16* cA = &As[t & 1][0];
        const u16* cB = &Bs[t & 1][0];
        // ---- phase 0: A frags (held) + B tn=0, 8 MFMA ----
        bf16x8 af[2][4], bf0[4];
        #pragma unroll
        for (int tm = 0; tm < 2; ++tm)
            #pragma unroll
            for (int kc = 0; kc < 4; ++kc)
                af[tm][kc] = *(const bf16x8*)&cA[(wr * 64 + tm * 32 + l31) * 64 + coff[kc]];
        #pragma unroll
        for (int kc = 0; kc < 4; ++kc)
            bf0[kc] = *(const bf16x8*)&cB[(wc * 64 + l31) * 64 + coff[kc]];
        __builtin_amdgcn_s_setprio(1);
        #pragma unroll
        for (int tm = 0; tm < 2; ++tm)
            #pragma unroll
            for (int kc = 0; kc < 4; ++kc)
                acc[tm][0] = __builtin_amdgcn_mfma_f32_32x32x16_bf16(
                    af[tm][kc], bf0[kc], acc[tm][0], 0, 0, 0);
        __builtin_amdgcn_s_setprio(0);
        __builtin_amdgcn_s_barrier();
        // ---- phase 1: B tn=1, 8 MFMA ----
        bf16x8 bf1[4];
        #pragma unroll
        for (int kc = 0; kc < 4; ++kc)
            bf1[kc] = *(const bf16x8*)&cB[(wc * 64 + 32 + l31) * 64 + coff[kc]];
        __builtin_amdgcn_s_setprio(1);
        #pragma unroll
        for (int tm = 0; tm < 2; ++tm)
            #pragma unroll
            for (int kc = 0; kc < 4; ++kc)
                acc[tm][1] = __builtin_amdgcn_mfma_f32_32x32x16_bf16(
                    af[tm][kc], bf1[kc], acc[tm][1], 0, 0, 0);
        __builtin_amdgcn_s_setprio(0);
        __builtin_amdgcn_s_barrier();          // all waves done reading buf[t&1]
        __builtin_amdgcn_sched_barrier(0);
        if (t + 2 < NT) STG(t & 1, t + 2);
        if (t + 1 < NT) {
            if (t + 2 < NT) { asm volatile("s_waitcnt vmcnt(8)" ::: "memory"); }
            else            { asm volatile("s_waitcnt vmcnt(0)" ::: "memory"); }
            __builtin_amdgcn_s_barrier();      // all waves' t+1 landed
            __builtin_amdgcn_sched_barrier(0);
        }
    }
#undef STG

    // epilogue: q/k/v scatter to (B,H,L,D); 32x32 C/D layout
    #pragma unroll
    for (int tm = 0; tm < 2; ++tm) {
        #pragma unroll
        for (int tn = 0; tn < 2; ++tn) {
            int cg = col0 + wc * 64 + tn * 32 + l31;
            float bv = bias[cg];
            int which = cg >> 10;         // 0=q 1=k 2=v
            float sc = (which == 0) ? QSCALE : 1.0f;
            int cc2 = cg & 1023;
            int h = cc2 >> 6, dd = cc2 & 63;
            int rbase = row0 + wr * 64 + tm * 32 + 4 * lhi;
            #pragma unroll
            for (int g = 0; g < 4; ++g) {
                #pragma unroll
                for (int r = 0; r < 4; ++r) {
                    int rg = rbase + 8 * g + r;
                    int bidx = rg >> 10, ll2 = rg & 1023;
                    size_t o = ((size_t)(bidx * Hh + h) * Ll + ll2) * Dd + dd;
                    u16 val = f2b((acc[tm][tn][g * 4 + r] + bv) * sc);
                    if (which == 0) qo[o] = val;
                    else if (which == 1) ko[o] = val;
                    else vo[o] = val;
                }
            }
        }
    }
}

// ======== proj GEMM v2: ported to the qkv32 skeleton (32x32x16, BK=64, dbuf) ========
// Identical pipeline to k_gemm_qkv32 (proven 742 TF); only the epilogue differs:
// fp32 output with bias, coalesced 128B runs (l31 fast axis). Grid 8x64 = 512
// blocks = exactly 2/CU x 1 round.
__global__ __launch_bounds__(256, 2)
void k_gemm_proj32(const u16* __restrict__ A, const u16* __restrict__ Bt,
                   const float* __restrict__ bias, float* __restrict__ outf)
{
    const int K = Cc;            // 1024
    const int N = Cc;
    const int NT = K / 64;       // 16 K-tiles
    __shared__ u16 As[2][128 * 64];
    __shared__ u16 Bs[2][128 * 64];
    const int tid = threadIdx.x;
    const int wid = tid >> 6, lane = tid & 63;
    const int l31 = lane & 31, lhi = lane >> 5, l7 = lane & 7;
    const int wr = wid >> 1, wc = wid & 1;       // 2x2 waves, 64x64 each
    const int nwg = gridDim.x * gridDim.y;       // 512, %8==0
    const int flat = blockIdx.y * gridDim.x + blockIdx.x;
    const int swz = (flat & 7) * (nwg >> 3) + (flat >> 3);
    const int bx = swz % gridDim.x, by = swz / gridDim.x;
    const int row0 = by * 128, col0 = bx * 128;

    const int srow = tid >> 3;
    const int schunk = (tid & 7) ^ (srow & 7);
    const u16* gA = A  + (size_t)(row0 + srow) * K + schunk * 8;
    const u16* gB = Bt + (size_t)(col0 + srow) * K + schunk * 8;

#define STG(buf, t) do { \
    const u16* ga_ = gA + (size_t)(t) * 64; \
    const u16* gb_ = gB + (size_t)(t) * 64; \
    u16* la_ = &As[buf][wid * 512]; \
    u16* lb_ = &Bs[buf][wid * 512]; \
    gload16(ga_,                  la_); \
    gload16(ga_ + (size_t)32 * K, la_ + 2048); \
    gload16(ga_ + (size_t)64 * K, la_ + 4096); \
    gload16(ga_ + (size_t)96 * K, la_ + 6144); \
    gload16(gb_,                  lb_); \
    gload16(gb_ + (size_t)32 * K, lb_ + 2048); \
    gload16(gb_ + (size_t)64 * K, lb_ + 4096); \
    gload16(gb_ + (size_t)96 * K, lb_ + 6144); \
} while (0)

    const int coff0 = (((0 + lhi) ^ l7) << 3);
    const int coff1 = (((2 + lhi) ^ l7) << 3);
    const int coff2 = (((4 + lhi) ^ l7) << 3);
    const int coff3 = (((6 + lhi) ^ l7) << 3);
    const int coff[4] = { coff0, coff1, coff2, coff3 };

    f32x16 acc[2][2] = {};

    STG(0, 0);
    STG(1, 1);
    asm volatile("s_waitcnt vmcnt(8)" ::: "memory");
    __builtin_amdgcn_s_barrier();
    __builtin_amdgcn_sched_barrier(0);

    for (int t = 0; t < NT; ++t) {
        const u16* cA = &As[t & 1][0];
        const u16* cB = &Bs[t & 1][0];
        bf16x8 af[2][4], bf0[4];
        #pragma unroll
        for (int tm = 0; tm < 2; ++tm)
            #pragma unroll
            for (int kc = 0; kc < 4; ++kc)
                af[tm][kc] = *(const bf16x8*)&cA[(wr * 64 + tm * 32 + l31) * 64 + coff[kc]];
        #pragma unroll
        for (int kc = 0; kc < 4; ++kc)
            bf0[kc] = *(const bf16x8*)&cB[(wc * 64 + l31) * 64 + coff[kc]];
        __builtin_amdgcn_s_setprio(1);
        #pragma unroll
        for (int tm = 0; tm < 2; ++tm)
            #pragma unroll
            for (int kc = 0; kc < 4; ++kc)
                acc[tm][0] = __builtin_amdgcn_mfma_f32_32x32x16_bf16(
                    af[tm][kc], bf0[kc], acc[tm][0], 0, 0, 0);
        __builtin_amdgcn_s_setprio(0);
        __builtin_amdgcn_s_barrier();
        bf16x8 bf1[4];
        #pragma unroll
        for (int kc = 0; kc < 4; ++kc)
            bf1[kc] = *(const bf16x8*)&cB[(wc * 64 + 32 + l31) * 64 + coff[kc]];
        __builtin_amdgcn_s_setprio(1);
        #pragma unroll
        for (int tm = 0; tm < 2; ++tm)
            #pragma unroll
            for (int kc = 0; kc < 4; ++kc)
                acc[tm][1] = __builtin_amdgcn_mfma_f32_32x32x16_bf16(
                    af[tm][kc], bf1[kc], acc[tm][1], 0, 0, 0);
        __builtin_amdgcn_s_setprio(0);
        __builtin_amdgcn_s_barrier();
        __builtin_amdgcn_sched_barrier(0);
        if (t + 2 < NT) STG(t & 1, t + 2);
        if (t + 1 < NT) {
            if (t + 2 < NT) { asm volatile("s_waitcnt vmcnt(8)" ::: "memory"); }
            else            { asm volatile("s_waitcnt vmcnt(0)" ::: "memory"); }
            __builtin_amdgcn_s_barrier();
            __builtin_amdgcn_sched_barrier(0);
        }
    }
#undef STG

    // epilogue: fp32 out (M x N) with bias; 32x32 C/D layout, coalesced over l31
    #pragma unroll
    for (int tm = 0; tm < 2; ++tm) {
        #pragma unroll
        for (int tn = 0; tn < 2; ++tn) {
            int cg = col0 + wc * 64 + tn * 32 + l31;
            float bv = bias[cg];
            int rbase = row0 + wr * 64 + tm * 32 + 4 * lhi;
            #pragma unroll
            for (int g = 0; g < 4; ++g) {
                #pragma unroll
                for (int r = 0; r < 4; ++r) {
                    int rg = rbase + 8 * g + r;
                    outf[(size_t)rg * N + cg] = acc[tm][tn][g * 4 + r] + bv;
                }
            }
        }
    }
}

// ---------------- attention pass 1: column sums (LDS-staged Q pipeline) ----------------
// R17-proven. DO NOT PERTURB.
__global__ __launch_bounds__(256, 4)
void k_attn_colsum(const u16* __restrict__ Q, const u16* __restrict__ Kb,
                   float* __restrict__ zinv)
{
    __shared__ u16 Qs[2][64 * 64];
    const int tid = threadIdx.x;
    const int wid = tid >> 6, lane = tid & 63;
    const int lr = lane & 15, lg = lane >> 4;
    const int l7 = lr & 7;
    const int fid = blockIdx.x;
    const int xcd = fid & 7, n = fid >> 3;
    const int xtA = n & 7;                   // col tile A (0..7)
    const int xtB = 15 - xtA;                // paired tile B (8..15)
    const int bh = (xcd << 4) | (n >> 3);
    const u16* Qp = Q  + (size_t)bh * Ll * Dd;
    const u16* Kp = Kb + (size_t)bh * Ll * Dd;
    const int jwA = xtA * 64 + wid * 16;
    const int jwB = xtB * 64 + wid * 16;
    bf16x8 kbA0 = *(const bf16x8*)&Kp[(jwA + lr) * Dd + lg * 8];
    bf16x8 kbA1 = *(const bf16x8*)&Kp[(jwA + lr) * Dd + 32 + lg * 8];
    bf16x8 kbB0 = *(const bf16x8*)&Kp[(jwB + lr) * Dd + lg * 8];
    bf16x8 kbB1 = *(const bf16x8*)&Kp[(jwB + lr) * Dd + 32 + lg * 8];
    const bool dmask[4] = { lg * 4 + 0 >= lr, lg * 4 + 1 >= lr,
                            lg * 4 + 2 >= lr, lg * 4 + 3 >= lr };
    const int ch0 = ((lg ^ l7) << 3);
    const int ch1 = (((4 + lg) ^ l7) << 3);
    const int srow = tid >> 3;               // 0..31
    const int schunk = (tid & 7) ^ (srow & 7);
    float zA = 0.f, zB = 0.f;

    const int nA = 16 - xtA;
    const int NS = 17;
#define IOF(s) (((s) < nA) ? (xtA * 64 + 64 * (s)) : (xtB * 64 + 64 * ((s) - nA)))

#define STGQ(buf, I0) do { \
    const u16* g_ = Qp + (size_t)((I0) + srow) * 64 + schunk * 8; \
    u16* l_ = &Qs[buf][wid * 512]; \
    gload16(g_,                   l_); \
    gload16(g_ + (size_t)32 * 64, l_ + 2048); \
} while (0)

#define CS_STEP(buf, I0, JW, KB0, KB1, ZACC) do { \
    const u16* Qs_ = &Qs[buf][0]; \
    _Pragma("unroll") \
    for (int ss = 0; ss < 4; ++ss) { \
        int ib = (I0) + ss * 16; \
        if (ib >= (JW)) { \
            bf16x8 qa0 = *(const bf16x8*)&Qs_[(ss * 16 + lr) * 64 + ch0]; \
            bf16x8 qa1 = *(const bf16x8*)&Qs_[(ss * 16 + lr) * 64 + ch1]; \
            f32x4 s_ = {0.f, 0.f, 0.f, 0.f}; \
            s_ = __builtin_amdgcn_mfma_f32_16x16x32_bf16(qa0, KB0, s_, 0, 0, 0); \
            s_ = __builtin_amdgcn_mfma_f32_16x16x32_bf16(qa1, KB1, s_, 0, 0, 0); \
            if (ib >= (JW) + 16) { \
                _Pragma("unroll") \
                for (int r = 0; r < 4; ++r) ZACC += exp2f(s_[r]); \
            } else { \
                _Pragma("unroll") \
                for (int r = 0; r < 4; ++r) ZACC += dmask[r] ? exp2f(s_[r]) : 0.f; \
            } \
        } \
    } \
} while (0)

    STGQ(0, IOF(0));
    STGQ(1, IOF(1));
    asm volatile("s_waitcnt vmcnt(2)" ::: "memory");
    __builtin_amdgcn_s_barrier();
    __builtin_amdgcn_sched_barrier(0);

    for (int s = 0; s < NS; ++s) {
        if (s < nA) { CS_STEP((s & 1), xtA * 64 + 64 * s, jwA, kbA0, kbA1, zA); }
        else        { CS_STEP((s & 1), xtB * 64 + 64 * (s - nA), jwB, kbB0, kbB1, zB); }
        __builtin_amdgcn_s_barrier();
        __builtin_amdgcn_sched_barrier(0);
        if (s + 2 < NS) STGQ((s & 1), IOF(s + 2));
        if (s + 1 < NS) {
            if (s + 2 < NS) { asm volatile("s_waitcnt vmcnt(2)" ::: "memory"); }
            else            { asm volatile("s_waitcnt vmcnt(0)" ::: "memory"); }
            __builtin_amdgcn_s_barrier();
            __builtin_amdgcn_sched_barrier(0);
        }
    }
#undef STGQ
#undef CS_STEP
#undef IOF

    zA += __shfl_xor(zA, 16); zA += __shfl_xor(zA, 32);
    zB += __shfl_xor(zB, 16); zB += __shfl_xor(zB, 32);
    if (lg == 0) {
        zinv[(size_t)bh * Ll + jwA + lr] = 1.f / zA;
        zinv[(size_t)bh * Ll + jwB + lr] = 1.f / zB;
    }
}

// ---------------- attention pass 2: Y = exp(S') @ V'  (LDS-staged K/V pipeline) ----------------
// R16-proven (pv left the top-5). DO NOT PERTURB.
__global__ __launch_bounds__(256, 4)
void k_attn_pv(const u16* __restrict__ Q, const u16* __restrict__ Kb,
               const u16* __restrict__ Vt, u16* __restrict__ Y)
{
    __shared__ u16 Ks[2][64 * 64];
    __shared__ u16 Vs[2][64 * 64];
    const int tid = threadIdx.x;
    const int wid = tid >> 6, lane = tid & 63;
    const int lr = lane & 15, lg = lane >> 4;
    const int l7 = lr & 7;
    const int fid = blockIdx.x;
    const int xcd = fid & 7, n = fid >> 3;
    const int xtA = n & 7;                   // tile A index (0..7)
    const int xtB = 15 - xtA;                // paired tile B (8..15)
    const int bh = (xcd << 4) | (n >> 3);
    const int bidx = bh >> 4, h = bh & 15;
    const u16* Qp = Q  + (size_t)bh * Ll * Dd;
    const u16* Kp = Kb + (size_t)bh * Ll * Dd;
    const u16* Vp = Vt + (size_t)bh * Ll * Dd;     // (Dd, Ll) layout, zinv-scaled
    const int src0 = lr + 32 * (lg & 1);
    const int src1 = src0 + 16;
    const bool selHi = (lg & 2) != 0;
    const int ch0 = ((lg ^ l7) << 3);
    const int ch1 = (((4 + lg) ^ l7) << 3);
    const int srow = tid >> 3;               // 0..31
    const int schunk = (tid & 7) ^ (srow & 7);

    const int iwA = xtA * 64 + wid * 16;
    const int iwB = xtB * 64 + wid * 16;
    bf16x8 qaA0 = *(const bf16x8*)&Qp[(iwA + lr) * Dd + lg * 8];
    bf16x8 qaA1 = *(const bf16x8*)&Qp[(iwA + lr) * Dd + 32 + lg * 8];
    bf16x8 qaB0 = *(const bf16x8*)&Qp[(iwB + lr) * Dd + lg * 8];
    bf16x8 qaB1 = *(const bf16x8*)&Qp[(iwB + lr) * Dd + 32 + lg * 8];
    f32x4 yaccA[4] = {};
    f32x4 yaccB[4] = {};

    const int NS = 17;                       // (xtA+1) + (xtB+1) = 17 steps, uniform
#define JOF(s) (((s) <= xtA) ? 64 * (s) : 64 * ((s) - xtA - 1))

#define STGKV(buf, J) do { \
    const u16* gk_ = Kp + (size_t)((J) + srow) * 64 + schunk * 8; \
    const u16* gv_ = Vp + (size_t)srow * Ll + (J) + schunk * 8; \
    u16* lk_ = &Ks[buf][wid * 512]; \
    u16* lv_ = &Vs[buf][wid * 512]; \
    gload16(gk_,                   lk_); \
    gload16(gk_ + (size_t)32 * 64, lk_ + 2048); \
    gload16(gv_,                   lv_); \
    gload16(gv_ + (size_t)32 * Ll, lv_ + 2048); \
} while (0)

#define PV_STEP(buf, J0, IW, QA0, QA1, YACC) do { \
    const u16* Ks_ = &Ks[buf][0]; \
    const u16* Vs_ = &Vs[buf][0]; \
    uint2 w0, w1, w2, w3; \
    _Pragma("unroll") \
    for (int cs = 0; cs < 4; ++cs) { \
        bf16x8 kb0 = *(const bf16x8*)&Ks_[(cs * 16 + lr) * 64 + ch0]; \
        bf16x8 kb1 = *(const bf16x8*)&Ks_[(cs * 16 + lr) * 64 + ch1]; \
        f32x4 s_ = {0.f, 0.f, 0.f, 0.f}; \
        s_ = __builtin_amdgcn_mfma_f32_16x16x32_bf16(kb0, QA0, s_, 0, 0, 0); \
        s_ = __builtin_amdgcn_mfma_f32_16x16x32_bf16(kb1, QA1, s_, 0, 0, 0); \
        int jb = (J0) + cs * 16; \
        float p[4]; \
        if (jb + 15 <= (IW)) { \
            _Pragma("unroll") \
            for (int r = 0; r < 4; ++r) p[r] = exp2f(s_[r]); \
        } else { \
            int ig = (IW) + lr; \
            _Pragma("unroll") \
            for (int r = 0; r < 4; ++r) \
                p[r] = (jb + 4 * lg + r <= ig) ? exp2f(s_[r]) : 0.f; \
        } \
        uint2 w_; \
        w_.x = pack2bf(p[0], p[1]); \
        w_.y = pack2bf(p[2], p[3]); \
        if (cs == 0) w0 = w_; else if (cs == 1) w1 = w_; \
        else if (cs == 2) w2 = w_; else w3 = w_; \
    } \
    u32 a00 = (u32)__shfl((int)w0.x, src0), a01 = (u32)__shfl((int)w0.y, src0); \
    u32 a02 = (u32)__shfl((int)w0.x, src1), a03 = (u32)__shfl((int)w0.y, src1); \
    u32 a10 = (u32)__shfl((int)w1.x, src0), a11 = (u32)__shfl((int)w1.y, src0); \
    u32 a12 = (u32)__shfl((int)w1.x, src1), a13 = (u32)__shfl((int)w1.y, src1); \
    u32 a20 = (u32)__shfl((int)w2.x, src0), a21 = (u32)__shfl((int)w2.y, src0); \
    u32 a22 = (u32)__shfl((int)w2.x, src1), a23 = (u32)__shfl((int)w2.y, src1); \
    u32 a30 = (u32)__shfl((int)w3.x, src0), a31 = (u32)__shfl((int)w3.y, src0); \
    u32 a32 = (u32)__shfl((int)w3.x, src1), a33 = (u32)__shfl((int)w3.y, src1); \
    u32x4 pa0u, pa1u; \
    pa0u[0] = selHi ? a10 : a00;  pa0u[1] = selHi ? a11 : a01; \
    pa0u[2] = selHi ? a12 : a02;  pa0u[3] = selHi ? a13 : a03; \
    pa1u[0] = selHi ? a30 : a20;  pa1u[1] = selHi ? a31 : a21; \
    pa1u[2] = selHi ? a32 : a22;  pa1u[3] = selHi ? a33 : a23; \
    bf16x8 pa0 = __builtin_bit_cast(bf16x8, pa0u); \
    bf16x8 pa1 = __builtin_bit_cast(bf16x8, pa1u); \
    _Pragma("unroll") \
    for (int ns = 0; ns < 4; ++ns) { \
        bf16x8 vb0 = *(const bf16x8*)&Vs_[(ns * 16 + lr) * 64 + ch0]; \
        bf16x8 vb1 = *(const bf16x8*)&Vs_[(ns * 16 + lr) * 64 + ch1]; \
        YACC[ns] = __builtin_amdgcn_mfma_f32_16x16x32_bf16(pa0, vb0, YACC[ns], 0, 0, 0); \
        YACC[ns] = __builtin_amdgcn_mfma_f32_16x16x32_bf16(pa1, vb1, YACC[ns], 0, 0, 0); \
    } \
} while (0)

    STGKV(0, 0);                     // step 0 (tile A, j0 = 0)
    STGKV(1, JOF(1));                // step 1
    asm volatile("s_waitcnt vmcnt(4)" ::: "memory");   // step0's 4 loads landed
    __builtin_amdgcn_s_barrier();
    __builtin_amdgcn_sched_barrier(0);

    for (int s = 0; s < NS; ++s) {
        if (s <= xtA) { PV_STEP((s & 1), 64 * s, iwA, qaA0, qaA1, yaccA); }
        else          { PV_STEP((s & 1), 64 * (s - xtA - 1), iwB, qaB0, qaB1, yaccB); }
        __builtin_amdgcn_s_barrier();          // all waves done reading buf[s&1]
        __builtin_amdgcn_sched_barrier(0);
        if (s + 2 < NS) STGKV((s & 1), JOF(s + 2));
        if (s + 1 < NS) {
            if (s + 2 < NS) { asm volatile("s_waitcnt vmcnt(4)" ::: "memory"); }
            else            { asm volatile("s_waitcnt vmcnt(0)" ::: "memory"); }
            __builtin_amdgcn_s_barrier();      // all waves' step s+1 landed
            __builtin_amdgcn_sched_barrier(0);
        }
    }
#undef STGKV
#undef PV_STEP
#undef JOF

    #pragma unroll
    for (int ns = 0; ns < 4; ++ns)
        #pragma unroll
        for (int r = 0; r < 4; ++r) {
            int l2 = iwA + lg * 4 + r;
            Y[((size_t)bidx * Ll + l2) * Cc + h * Dd + ns * 16 + lr] = f2b(yaccA[ns][r]);
        }
    #pragma unroll
    for (int ns = 0; ns < 4; ++ns)
        #pragma unroll
        for (int r = 0; r < 4; ++r) {
            int l2 = iwB + lg * 4 + r;
            Y[((size_t)bidx * Ll + l2) * Cc + h * Dd + ns * 16 + lr] = f2b(yaccB[ns][r]);
        }
}

extern "C" void kernel_launch(void* const* d_in, const int* in_sizes, int n_in,
                              void* d_out, int out_size, void* d_ws, size_t ws_size,
                              hipStream_t stream)
{
    const float* x     = (const float*)d_in[0];
    const float* Wqkv  = (const float*)d_in[1];
    const float* bqkv  = (const float*)d_in[2];
    const float* Wproj = (const float*)d_in[3];
    const float* bproj = (const float*)d_in[4];
    float* out = (float*)d_out;

    char* ws = (char*)d_ws;
    u16* xb     = (u16*)(ws + 0);            // x as bf16, 8192x1024         (16 MB)
    u16* WqkvT  = (u16*)(ws + 16777216);     // W_qkv^T bf16, 3072x1024      (6 MB)
    u16* WprojT = (u16*)(ws + 23068672);     // W_proj^T bf16, 1024x1024     (2 MB)
    u16* q      = (u16*)(ws + 25165824);     // (B,H,L,D) bf16, pre-scaled   (16 MB)
    u16* k      = (u16*)(ws + 41943040);     // (B,H,L,D) bf16               (16 MB)
    u16* v      = (u16*)(ws + 58720256);     // (B,H,L,D) bf16; reused as Y  (16 MB)
    u16* vt     = (u16*)(ws + 75497472);     // (B,H,D,L) bf16, zinv-scaled  (16 MB)
    float* zinv = (float*)(ws + 92274688);   // (B*H*L) fp32                 (0.5 MB)

    k_f32_to_bf16<<<dim3(2048), dim3(256), 0, stream>>>(x, xb, Mrows * Cc / 16);
    k_transpose_w<<<dim3(128, 32), dim3(32, 8), 0, stream>>>(Wqkv, WqkvT, Wproj, WprojT);
    k_gemm_qkv32<<<dim3(N3 / 128, Mrows / 128), dim3(256), 0, stream>>>(
        xb, WqkvT, bqkv, q, k, v);
    k_attn_colsum<<<dim3(1024), dim3(256), 0, stream>>>(q, k, zinv);
    k_transpose_scale_bf16<<<dim3(2, 32, Bb * Hh), dim3(32, 8), 0, stream>>>(v, zinv, vt, Ll, Dd);
    k_attn_pv<<<dim3(1024), dim3(256), 0, stream>>>(q, k, vt, v);
    k_gemm_proj32<<<dim3(Cc / 128, Mrows / 128), dim3(256), 0, stream>>>(
        v, WprojT, bproj, out);
}

// Round 19
// 174.963 us; speedup vs baseline: 1.5740x; 1.0510x over previous
//
#include <hip/hip_runtime.h>

typedef unsigned short u16;
typedef unsigned int   u32;
using bf16x8 = __attribute__((ext_vector_type(8))) short;
using f32x4  = __attribute__((ext_vector_type(4))) float;
using f32x16 = __attribute__((ext_vector_type(16))) float;
using u32x4  = __attribute__((ext_vector_type(4))) u32;

static constexpr int Bb = 8, Ll = 1024, Cc = 1024, Hh = 16, Dd = 64;
static constexpr int Mrows = Bb * Ll;   // 8192
static constexpr int N3    = 3 * Cc;    // 3072
// exp(S/8) = 2^(S * 0.125*log2(e)); fold into q at the QKV epilogue
static constexpr float QSCALE = 0.125f * 1.44269504088896f;

__device__ __forceinline__ u16 f2b(float f) {  // fp32 -> bf16 RNE
    u32 u = __builtin_bit_cast(u32, f);
    u += 0x7FFFu + ((u >> 16) & 1u);
    return (u16)(u >> 16);
}
__device__ __forceinline__ float b2f(u16 u) {
    return __builtin_bit_cast(float, (u32)u << 16);
}
__device__ __forceinline__ u32 pack2bf(float a, float b) {
    return (u32)f2b(a) | ((u32)f2b(b) << 16);
}
// async global->LDS, 16B/lane; LDS dest is wave-uniform base (lane*16 HW-added)
__device__ __forceinline__ void gload16(const u16* g, u16* l) {
    __builtin_amdgcn_global_load_lds(
        (const __attribute__((address_space(1))) void*)g,
        (__attribute__((address_space(3))) void*)l, 16, 0, 0);
}

// ==== fused prep: x fp32->bf16 convert (blocks 0..2047) + weight transposes ====
// convert: 16 elems/thread. transpose: W_qkv (1024x3072) and W_proj (1024x1024),
// flattened 256-thread indexing (tx=tid&31, ty=tid>>5), same tiles as before.
__global__ void k_prep(const float* __restrict__ x, u16* __restrict__ xb,
                       const float* __restrict__ Wqkv, u16* __restrict__ WqkvT,
                       const float* __restrict__ Wproj, u16* __restrict__ WprojT)
{
    __shared__ float tile[32][33];
    int bid = blockIdx.x;
    int tid = threadIdx.x;
    if (bid < 2048) {                      // ---- convert branch ----
        int idx = bid * 256 + tid;
        #pragma unroll
        for (int h = 0; h < 2; ++h) {
            f32x4 v0 = *((const f32x4*)x + idx * 4 + h * 2);
            f32x4 v1 = *((const f32x4*)x + idx * 4 + h * 2 + 1);
            u32x4 o;
            o[0] = pack2bf(v0[0], v0[1]);
            o[1] = pack2bf(v0[2], v0[3]);
            o[2] = pack2bf(v1[0], v1[1]);
            o[3] = pack2bf(v1[2], v1[3]);
            *((u32x4*)xb + idx * 2 + h) = o;
        }
        return;
    }
    // ---- weight transpose branch ----
    int bz = bid - 2048;                   // 0..4095
    int bx = bz & 127;                     // 0..127 (96 qkv + 32 proj)
    int by = bz >> 7;                      // 0..31
    const float* in; u16* out; int Cn;
    if (bx < 96) { in = Wqkv;  out = WqkvT;  Cn = N3; }
    else         { in = Wproj; out = WprojT; Cn = Cc; bx -= 96; }
    const int R = Cc;
    int tx = tid & 31, ty = tid >> 5;
    int c = bx * 32 + tx;
    int rbase = by * 32;
    #pragma unroll
    for (int rr = 0; rr < 4; ++rr)
        tile[ty + rr * 8][tx] = in[(size_t)(rbase + ty + rr * 8) * Cn + c];
    __syncthreads();
    int ro = bx * 32 + ty;
    #pragma unroll
    for (int rr = 0; rr < 4; ++rr)
        out[(size_t)(ro + rr * 8) * R + rbase + tx] = f2b(tile[tx][ty + rr * 8]);
}

// ======== QKV GEMM v3: 32x32x16 MFMA, 128^2 tile, BK=64, dbuf, 2 blocks/CU ========
// R10-proven (took QKV out of the top-5). DO NOT PERTURB.
__global__ __launch_bounds__(256, 2)
void k_gemm_qkv32(const u16* __restrict__ A, const u16* __restrict__ Bt,
                  const float* __restrict__ bias,
                  u16* __restrict__ qo, u16* __restrict__ ko, u16* __restrict__ vo)
{
    const int K = Cc;            // 1024
    const int NT = K / 64;       // 16 K-tiles
    __shared__ u16 As[2][128 * 64];
    __shared__ u16 Bs[2][128 * 64];
    const int tid = threadIdx.x;
    const int wid = tid >> 6, lane = tid & 63;
    const int l31 = lane & 31, lhi = lane >> 5, l7 = lane & 7;
    const int wr = wid >> 1, wc = wid & 1;       // 2x2 waves, 64x64 each
    const int nwg = gridDim.x * gridDim.y;       // 1536, %8==0
    const int flat = blockIdx.y * gridDim.x + blockIdx.x;
    const int swz = (flat & 7) * (nwg >> 3) + (flat >> 3);
    const int bx = swz % gridDim.x, by = swz / gridDim.x;
    const int row0 = by * 128, col0 = bx * 128;

    const int srow = tid >> 3;
    const int schunk = (tid & 7) ^ (srow & 7);
    const u16* gA = A  + (size_t)(row0 + srow) * K + schunk * 8;
    const u16* gB = Bt + (size_t)(col0 + srow) * K + schunk * 8;

#define STG(buf, t) do { \
    const u16* ga_ = gA + (size_t)(t) * 64; \
    const u16* gb_ = gB + (size_t)(t) * 64; \
    u16* la_ = &As[buf][wid * 512]; \
    u16* lb_ = &Bs[buf][wid * 512]; \
    gload16(ga_,                  la_); \
    gload16(ga_ + (size_t)32 * K, la_ + 2048); \
    gload16(ga_ + (size_t)64 * K, la_ + 4096); \
    gload16(ga_ + (size_t)96 * K, la_ + 6144); \
    gload16(gb_,                  lb_); \
    gload16(gb_ + (size_t)32 * K, lb_ + 2048); \
    gload16(gb_ + (size_t)64 * K, lb_ + 4096); \
    gload16(gb_ + (size_t)96 * K, lb_ + 6144); \
} while (0)

    const int coff0 = (((0 + lhi) ^ l7) << 3);
    const int coff1 = (((2 + lhi) ^ l7) << 3);
    const int coff2 = (((4 + lhi) ^ l7) << 3);
    const int coff3 = (((6 + lhi) ^ l7) << 3);
    const int coff[4] = { coff0, coff1, coff2, coff3 };

    f32x16 acc[2][2] = {};

    STG(0, 0);
    STG(1, 1);
    asm volatile("s_waitcnt vmcnt(8)" ::: "memory");   // tile0's 8 loads landed
    __builtin_amdgcn_s_barrier();
    __builtin_amdgcn_sched_barrier(0);

    for (int t = 0; t < NT; ++t) {
        const u16* cA = &As[t & 1][0];
        const u16* cB = &Bs[t & 1][0];
        // ---- phase 0: A frags (held) + B tn=0, 8 MFMA ----
        bf16x8 af[2][4], bf0[4];
        #pragma unroll
        for (int tm = 0; tm < 2; ++tm)
            #pragma unroll
            for (int kc = 0; kc < 4; ++kc)
                af[tm][kc] = *(const bf16x8*)&cA[(wr * 64 + tm * 32 + l31) * 64 + coff[kc]];
        #pragma unroll
        for (int kc = 0; kc < 4; ++kc)
            bf0[kc] = *(const bf16x8*)&cB[(wc * 64 + l31) * 64 + coff[kc]];
        __builtin_amdgcn_s_setprio(1);
        #pragma unroll
        for (int tm = 0; tm < 2; ++tm)
            #pragma unroll
            for (int kc = 0; kc < 4; ++kc)
                acc[tm][0] = __builtin_amdgcn_mfma_f32_32x32x16_bf16(
                    af[tm][kc], bf0[kc], acc[tm][0], 0, 0, 0);
        __builtin_amdgcn_s_setprio(0);
        __builtin_amdgcn_s_barrier();
        // ---- phase 1: B tn=1, 8 MFMA ----
        bf16x8 bf1[4];
        #pragma unroll
        for (int kc = 0; kc < 4; ++kc)
            bf1[kc] = *(const bf16x8*)&cB[(wc * 64 + 32 + l31) * 64 + coff[kc]];
        __builtin_amdgcn_s_setprio(1);
        #pragma unroll
        for (int tm = 0; tm < 2; ++tm)
            #pragma unroll
            for (int kc = 0; kc < 4; ++kc)
                acc[tm][1] = __builtin_amdgcn_mfma_f32_32x32x16_bf16(
                    af[tm][kc], bf1[kc], acc[tm][1], 0, 0, 0);
        __builtin_amdgcn_s_setprio(0);
        __builtin_amdgcn_s_barrier();          // all waves done reading buf[t&1]
        __builtin_amdgcn_sched_barrier(0);
        if (t + 2 < NT) STG(t & 1, t + 2);
        if (t + 1 < NT) {
            if (t + 2 < NT) { asm volatile("s_waitcnt vmcnt(8)" ::: "memory"); }
            else            { asm volatile("s_waitcnt vmcnt(0)" ::: "memory"); }
            __builtin_amdgcn_s_barrier();      // all waves' t+1 landed
            __builtin_amdgcn_sched_barrier(0);
        }
    }
#undef STG

    // epilogue: q/k/v scatter to (B,H,L,D); 32x32 C/D layout
    #pragma unroll
    for (int tm = 0; tm < 2; ++tm) {
        #pragma unroll
        for (int tn = 0; tn < 2; ++tn) {
            int cg = col0 + wc * 64 + tn * 32 + l31;
            float bv = bias[cg];
            int which = cg >> 10;         // 0=q 1=k 2=v
            float sc = (which == 0) ? QSCALE : 1.0f;
            int cc2 = cg & 1023;
            int h = cc2 >> 6, dd = cc2 & 63;
            int rbase = row0 + wr * 64 + tm * 32 + 4 * lhi;
            #pragma unroll
            for (int g = 0; g < 4; ++g) {
                #pragma unroll
                for (int r = 0; r < 4; ++r) {
                    int rg = rbase + 8 * g + r;
                    int bidx = rg >> 10, ll2 = rg & 1023;
                    size_t o = ((size_t)(bidx * Hh + h) * Ll + ll2) * Dd + dd;
                    u16 val = f2b((acc[tm][tn][g * 4 + r] + bv) * sc);
                    if (which == 0) qo[o] = val;
                    else if (which == 1) ko[o] = val;
                    else vo[o] = val;
                }
            }
        }
    }
}

// ======== proj GEMM v2: qkv32 skeleton (32x32x16, BK=64, dbuf). R18-proven. ========
__global__ __launch_bounds__(256, 2)
void k_gemm_proj32(const u16* __restrict__ A, const u16* __restrict__ Bt,
                   const float* __restrict__ bias, float* __restrict__ outf)
{
    const int K = Cc;            // 1024
    const int N = Cc;
    const int NT = K / 64;       // 16 K-tiles
    __shared__ u16 As[2][128 * 64];
    __shared__ u16 Bs[2][128 * 64];
    const int tid = threadIdx.x;
    const int wid = tid >> 6, lane = tid & 63;
    const int l31 = lane & 31, lhi = lane >> 5, l7 = lane & 7;
    const int wr = wid >> 1, wc = wid & 1;       // 2x2 waves, 64x64 each
    const int nwg = gridDim.x * gridDim.y;       // 512, %8==0
    const int flat = blockIdx.y * gridDim.x + blockIdx.x;
    const int swz = (flat & 7) * (nwg >> 3) + (flat >> 3);
    const int bx = swz % gridDim.x, by = swz / gridDim.x;
    const int row0 = by * 128, col0 = bx * 128;

    const int srow = tid >> 3;
    const int schunk = (tid & 7) ^ (srow & 7);
    const u16* gA = A  + (size_t)(row0 + srow) * K + schunk * 8;
    const u16* gB = Bt + (size_t)(col0 + srow) * K + schunk * 8;

#define STG(buf, t) do { \
    const u16* ga_ = gA + (size_t)(t) * 64; \
    const u16* gb_ = gB + (size_t)(t) * 64; \
    u16* la_ = &As[buf][wid * 512]; \
    u16* lb_ = &Bs[buf][wid * 512]; \
    gload16(ga_,                  la_); \
    gload16(ga_ + (size_t)32 * K, la_ + 2048); \
    gload16(ga_ + (size_t)64 * K, la_ + 4096); \
    gload16(ga_ + (size_t)96 * K, la_ + 6144); \
    gload16(gb_,                  lb_); \
    gload16(gb_ + (size_t)32 * K, lb_ + 2048); \
    gload16(gb_ + (size_t)64 * K, lb_ + 4096); \
    gload16(gb_ + (size_t)96 * K, lb_ + 6144); \
} while (0)

    const int coff0 = (((0 + lhi) ^ l7) << 3);
    const int coff1 = (((2 + lhi) ^ l7) << 3);
    const int coff2 = (((4 + lhi) ^ l7) << 3);
    const int coff3 = (((6 + lhi) ^ l7) << 3);
    const int coff[4] = { coff0, coff1, coff2, coff3 };

    f32x16 acc[2][2] = {};

    STG(0, 0);
    STG(1, 1);
    asm volatile("s_waitcnt vmcnt(8)" ::: "memory");
    __builtin_amdgcn_s_barrier();
    __builtin_amdgcn_sched_barrier(0);

    for (int t = 0; t < NT; ++t) {
        const u16* cA = &As[t & 1][0];
        const u16* cB = &Bs[t & 1][0];
        bf16x8 af[2][4], bf0[4];
        #pragma unroll
        for (int tm = 0; tm < 2; ++tm)
            #pragma unroll
            for (int kc = 0; kc < 4; ++kc)
                af[tm][kc] = *(const bf16x8*)&cA[(wr * 64 + tm * 32 + l31) * 64 + coff[kc]];
        #pragma unroll
        for (int kc = 0; kc < 4; ++kc)
            bf0[kc] = *(const bf16x8*)&cB[(wc * 64 + l31) * 64 + coff[kc]];
        __builtin_amdgcn_s_setprio(1);
        #pragma unroll
        for (int tm = 0; tm < 2; ++tm)
            #pragma unroll
            for (int kc = 0; kc < 4; ++kc)
                acc[tm][0] = __builtin_amdgcn_mfma_f32_32x32x16_bf16(
                    af[tm][kc], bf0[kc], acc[tm][0], 0, 0, 0);
        __builtin_amdgcn_s_setprio(0);
        __builtin_amdgcn_s_barrier();
        bf16x8 bf1[4];
        #pragma unroll
        for (int kc = 0; kc < 4; ++kc)
            bf1[kc] = *(const bf16x8*)&cB[(wc * 64 + 32 + l31) * 64 + coff[kc]];
        __builtin_amdgcn_s_setprio(1);
        #pragma unroll
        for (int tm = 0; tm < 2; ++tm)
            #pragma unroll
            for (int kc = 0; kc < 4; ++kc)
                acc[tm][1] = __builtin_amdgcn_mfma_f32_32x32x16_bf16(
                    af[tm][kc], bf1[kc], acc[tm][1], 0, 0, 0);
        __builtin_amdgcn_s_setprio(0);
        __builtin_amdgcn_s_barrier();
        __builtin_amdgcn_sched_barrier(0);
        if (t + 2 < NT) STG(t & 1, t + 2);
        if (t + 1 < NT) {
            if (t + 2 < NT) { asm volatile("s_waitcnt vmcnt(8)" ::: "memory"); }
            else            { asm volatile("s_waitcnt vmcnt(0)" ::: "memory"); }
            __builtin_amdgcn_s_barrier();
            __builtin_amdgcn_sched_barrier(0);
        }
    }
#undef STG

    // epilogue: fp32 out (M x N) with bias; 32x32 C/D layout, coalesced over l31
    #pragma unroll
    for (int tm = 0; tm < 2; ++tm) {
        #pragma unroll
        for (int tn = 0; tn < 2; ++tn) {
            int cg = col0 + wc * 64 + tn * 32 + l31;
            float bv = bias[cg];
            int rbase = row0 + wr * 64 + tm * 32 + 4 * lhi;
            #pragma unroll
            for (int g = 0; g < 4; ++g) {
                #pragma unroll
                for (int r = 0; r < 4; ++r) {
                    int rg = rbase + 8 * g + r;
                    outf[(size_t)rg * N + cg] = acc[tm][tn][g * 4 + r] + bv;
                }
            }
        }
    }
}

// ---- attention pass 1 + vt: column sums (LDS-staged Q pipeline, R17-proven)
// fused with the v->vt transpose+zinv-scale epilogue. A block computes z for
// col tiles (xtA, xtB) of one bh, then transposes exactly those 64-row slices
// of v into vt (bh,D,L) scaled by 1/z, reusing Qs as scratch. Kills the
// separate k_transpose_scale kernel + its launch gap + the zinv round-trip.
__global__ __launch_bounds__(256, 4)
void k_attn_colsum_vt(const u16* __restrict__ Q, const u16* __restrict__ Kb,
                      const u16* __restrict__ V, u16* __restrict__ vt)
{
    __shared__ u16 Qs[2][64 * 64];
    __shared__ float zlds[2][64];
    const int tid = threadIdx.x;
    const int wid = tid >> 6, lane = tid & 63;
    const int lr = lane & 15, lg = lane >> 4;
    const int l7 = lr & 7;
    const int fid = blockIdx.x;
    const int xcd = fid & 7, n = fid >> 3;
    const int xtA = n & 7;                   // col tile A (0..7)
    const int xtB = 15 - xtA;                // paired tile B (8..15)
    const int bh = (xcd << 4) | (n >> 3);
    const u16* Qp = Q  + (size_t)bh * Ll * Dd;
    const u16* Kp = Kb + (size_t)bh * Ll * Dd;
    const int jwA = xtA * 64 + wid * 16;
    const int jwB = xtB * 64 + wid * 16;
    bf16x8 kbA0 = *(const bf16x8*)&Kp[(jwA + lr) * Dd + lg * 8];
    bf16x8 kbA1 = *(const bf16x8*)&Kp[(jwA + lr) * Dd + 32 + lg * 8];
    bf16x8 kbB0 = *(const bf16x8*)&Kp[(jwB + lr) * Dd + lg * 8];
    bf16x8 kbB1 = *(const bf16x8*)&Kp[(jwB + lr) * Dd + 32 + lg * 8];
    const bool dmask[4] = { lg * 4 + 0 >= lr, lg * 4 + 1 >= lr,
                            lg * 4 + 2 >= lr, lg * 4 + 3 >= lr };
    const int ch0 = ((lg ^ l7) << 3);
    const int ch1 = (((4 + lg) ^ l7) << 3);
    const int srow = tid >> 3;               // 0..31
    const int schunk = (tid & 7) ^ (srow & 7);
    float zA = 0.f, zB = 0.f;

    const int nA = 16 - xtA;
    const int NS = 17;
#define IOF(s) (((s) < nA) ? (xtA * 64 + 64 * (s)) : (xtB * 64 + 64 * ((s) - nA)))

#define STGQ(buf, I0) do { \
    const u16* g_ = Qp + (size_t)((I0) + srow) * 64 + schunk * 8; \
    u16* l_ = &Qs[buf][wid * 512]; \
    gload16(g_,                   l_); \
    gload16(g_ + (size_t)32 * 64, l_ + 2048); \
} while (0)

#define CS_STEP(buf, I0, JW, KB0, KB1, ZACC) do { \
    const u16* Qs_ = &Qs[buf][0]; \
    _Pragma("unroll") \
    for (int ss = 0; ss < 4; ++ss) { \
        int ib = (I0) + ss * 16; \
        if (ib >= (JW)) { \
            bf16x8 qa0 = *(const bf16x8*)&Qs_[(ss * 16 + lr) * 64 + ch0]; \
            bf16x8 qa1 = *(const bf16x8*)&Qs_[(ss * 16 + lr) * 64 + ch1]; \
            f32x4 s_ = {0.f, 0.f, 0.f, 0.f}; \
            s_ = __builtin_amdgcn_mfma_f32_16x16x32_bf16(qa0, KB0, s_, 0, 0, 0); \
            s_ = __builtin_amdgcn_mfma_f32_16x16x32_bf16(qa1, KB1, s_, 0, 0, 0); \
            if (ib >= (JW) + 16) { \
                _Pragma("unroll") \
                for (int r = 0; r < 4; ++r) ZACC += exp2f(s_[r]); \
            } else { \
                _Pragma("unroll") \
                for (int r = 0; r < 4; ++r) ZACC += dmask[r] ? exp2f(s_[r]) : 0.f; \
            } \
        } \
    } \
} while (0)

    STGQ(0, IOF(0));
    STGQ(1, IOF(1));
    asm volatile("s_waitcnt vmcnt(2)" ::: "memory");
    __builtin_amdgcn_s_barrier();
    __builtin_amdgcn_sched_barrier(0);

    for (int s = 0; s < NS; ++s) {
        if (s < nA) { CS_STEP((s & 1), xtA * 64 + 64 * s, jwA, kbA0, kbA1, zA); }
        else        { CS_STEP((s & 1), xtB * 64 + 64 * (s - nA), jwB, kbB0, kbB1, zB); }
        __builtin_amdgcn_s_barrier();
        __builtin_amdgcn_sched_barrier(0);
        if (s + 2 < NS) STGQ((s & 1), IOF(s + 2));
        if (s + 1 < NS) {
            if (s + 2 < NS) { asm volatile("s_waitcnt vmcnt(2)" ::: "memory"); }
            else            { asm volatile("s_waitcnt vmcnt(0)" ::: "memory"); }
            __builtin_amdgcn_s_barrier();
            __builtin_amdgcn_sched_barrier(0);
        }
    }
#undef STGQ
#undef CS_STEP
#undef IOF

    zA += __shfl_xor(zA, 16); zA += __shfl_xor(zA, 32);
    zB += __shfl_xor(zB, 16); zB += __shfl_xor(zB, 32);
    if (lg == 0) {
        zlds[0][wid * 16 + lr] = 1.f / zA;   // cols xtA*64 .. +64 across 4 waves
        zlds[1][wid * 16 + lr] = 1.f / zB;
    }

    // ---- fused epilogue: transpose v[bh][jw0..jw0+64][0..64] -> vt (bh,D,L) * zinv ----
    // scratch: reuse Qs (64 rows x stride 72, 16B-aligned rows)
    u16* sc = &Qs[0][0];
    const u16* Vr = V + (size_t)bh * Ll * Dd;        // (L, D) row-major
    const int lrow = tid >> 2;                        // 0..63
    const int seg  = (tid & 3) << 4;                  // 0,16,32,48
    #pragma unroll
    for (int t = 0; t < 2; ++t) {
        const int jw0 = (t ? xtB : xtA) * 64;
        u32x4 h0 = *(const u32x4*)&Vr[(size_t)(jw0 + lrow) * Dd + seg];
        u32x4 h1 = *(const u32x4*)&Vr[(size_t)(jw0 + lrow) * Dd + seg + 8];
        __syncthreads();                 // pipeline reads / prev iter reads done
        *(u32x4*)&sc[lrow * 72 + seg]     = h0;
        *(u32x4*)&sc[lrow * 72 + seg + 8] = h1;
        __syncthreads();                 // tile + zlds visible
        // write: d = lrow, 16 contiguous l at jw0+seg
        u16 obuf[16];
        #pragma unroll
        for (int j = 0; j < 16; ++j) {
            float zv = zlds[t][seg + j];
            obuf[j] = f2b(b2f(sc[(seg + j) * 72 + lrow]) * zv);
        }
        u16* dst = vt + ((size_t)bh * Dd + lrow) * Ll + jw0 + seg;
        *(u32x4*)dst       = *(u32x4*)&obuf[0];
        *(u32x4*)(dst + 8) = *(u32x4*)&obuf[8];
    }
}

// ---------------- attention pass 2: Y = exp(S') @ V'  (LDS-staged K/V pipeline) ----------------
// R16-proven (pv left the top-5). DO NOT PERTURB.
__global__ __launch_bounds__(256, 4)
void k_attn_pv(const u16* __restrict__ Q, const u16* __restrict__ Kb,
               const u16* __restrict__ Vt, u16* __restrict__ Y)
{
    __shared__ u16 Ks[2][64 * 64];
    __shared__ u16 Vs[2][64 * 64];
    const int tid = threadIdx.x;
    const int wid = tid >> 6, lane = tid & 63;
    const int lr = lane & 15, lg = lane >> 4;
    const int l7 = lr & 7;
    const int fid = blockIdx.x;
    const int xcd = fid & 7, n = fid >> 3;
    const int xtA = n & 7;                   // tile A index (0..7)
    const int xtB = 15 - xtA;                // paired tile B (8..15)
    const int bh = (xcd << 4) | (n >> 3);
    const int bidx = bh >> 4, h = bh & 15;
    const u16* Qp = Q  + (size_t)bh * Ll * Dd;
    const u16* Kp = Kb + (size_t)bh * Ll * Dd;
    const u16* Vp = Vt + (size_t)bh * Ll * Dd;     // (Dd, Ll) layout, zinv-scaled
    const int src0 = lr + 32 * (lg & 1);
    const int src1 = src0 + 16;
    const bool selHi = (lg & 2) != 0;
    const int ch0 = ((lg ^ l7) << 3);
    const int ch1 = (((4 + lg) ^ l7) << 3);
    const int srow = tid >> 3;               // 0..31
    const int schunk = (tid & 7) ^ (srow & 7);

    const int iwA = xtA * 64 + wid * 16;
    const int iwB = xtB * 64 + wid * 16;
    bf16x8 qaA0 = *(const bf16x8*)&Qp[(iwA + lr) * Dd + lg * 8];
    bf16x8 qaA1 = *(const bf16x8*)&Qp[(iwA + lr) * Dd + 32 + lg * 8];
    bf16x8 qaB0 = *(const bf16x8*)&Qp[(iwB + lr) * Dd + lg * 8];
    bf16x8 qaB1 = *(const bf16x8*)&Qp[(iwB + lr) * Dd + 32 + lg * 8];
    f32x4 yaccA[4] = {};
    f32x4 yaccB[4] = {};

    const int NS = 17;                       // (xtA+1) + (xtB+1) = 17 steps, uniform
#define JOF(s) (((s) <= xtA) ? 64 * (s) : 64 * ((s) - xtA - 1))

#define STGKV(buf, J) do { \
    const u16* gk_ = Kp + (size_t)((J) + srow) * 64 + schunk * 8; \
    const u16* gv_ = Vp + (size_t)srow * Ll + (J) + schunk * 8; \
    u16* lk_ = &Ks[buf][wid * 512]; \
    u16* lv_ = &Vs[buf][wid * 512]; \
    gload16(gk_,                   lk_); \
    gload16(gk_ + (size_t)32 * 64, lk_ + 2048); \
    gload16(gv_,                   lv_); \
    gload16(gv_ + (size_t)32 * Ll, lv_ + 2048); \
} while (0)

#define PV_STEP(buf, J0, IW, QA0, QA1, YACC) do { \
    const u16* Ks_ = &Ks[buf][0]; \
    const u16* Vs_ = &Vs[buf][0]; \
    uint2 w0, w1, w2, w3; \
    _Pragma("unroll") \
    for (int cs = 0; cs < 4; ++cs) { \
        bf16x8 kb0 = *(const bf16x8*)&Ks_[(cs * 16 + lr) * 64 + ch0]; \
        bf16x8 kb1 = *(const bf16x8*)&Ks_[(cs * 16 + lr) * 64 + ch1]; \
        f32x4 s_ = {0.f, 0.f, 0.f, 0.f}; \
        s_ = __builtin_amdgcn_mfma_f32_16x16x32_bf16(kb0, QA0, s_, 0, 0, 0); \
        s_ = __builtin_amdgcn_mfma_f32_16x16x32_bf16(kb1, QA1, s_, 0, 0, 0); \
        int jb = (J0) + cs * 16; \
        float p[4]; \
        if (jb + 15 <= (IW)) { \
            _Pragma("unroll") \
            for (int r = 0; r < 4; ++r) p[r] = exp2f(s_[r]); \
        } else { \
            int ig = (IW) + lr; \
            _Pragma("unroll") \
            for (int r = 0; r < 4; ++r) \
                p[r] = (jb + 4 * lg + r <= ig) ? exp2f(s_[r]) : 0.f; \
        } \
        uint2 w_; \
        w_.x = pack2bf(p[0], p[1]); \
        w_.y = pack2bf(p[2], p[3]); \
        if (cs == 0) w0 = w_; else if (cs == 1) w1 = w_; \
        else if (cs == 2) w2 = w_; else w3 = w_; \
    } \
    u32 a00 = (u32)__shfl((int)w0.x, src0), a01 = (u32)__shfl((int)w0.y, src0); \
    u32 a02 = (u32)__shfl((int)w0.x, src1), a03 = (u32)__shfl((int)w0.y, src1); \
    u32 a10 = (u32)__shfl((int)w1.x, src0), a11 = (u32)__shfl((int)w1.y, src0); \
    u32 a12 = (u32)__shfl((int)w1.x, src1), a13 = (u32)__shfl((int)w1.y, src1); \
    u32 a20 = (u32)__shfl((int)w2.x, src0), a21 = (u32)__shfl((int)w2.y, src0); \
    u32 a22 = (u32)__shfl((int)w2.x, src1), a23 = (u32)__shfl((int)w2.y, src1); \
    u32 a30 = (u32)__shfl((int)w3.x, src0), a31 = (u32)__shfl((int)w3.y, src0); \
    u32 a32 = (u32)__shfl((int)w3.x, src1), a33 = (u32)__shfl((int)w3.y, src1); \
    u32x4 pa0u, pa1u; \
    pa0u[0] = selHi ? a10 : a00;  pa0u[1] = selHi ? a11 : a01; \
    pa0u[2] = selHi ? a12 : a02;  pa0u[3] = selHi ? a13 : a03; \
    pa1u[0] = selHi ? a30 : a20;  pa1u[1] = selHi ? a31 : a21; \
    pa1u[2] = selHi ? a32 : a22;  pa1u[3] = selHi ? a33 : a23; \
    bf16x8 pa0 = __builtin_bit_cast(bf16x8, pa0u); \
    bf16x8 pa1 = __builtin_bit_cast(bf16x8, pa1u); \
    _Pragma("unroll") \
    for (int ns = 0; ns < 4; ++ns) { \
        bf16x8 vb0 = *(const bf16x8*)&Vs_[(ns * 16 + lr) * 64 + ch0]; \
        bf16x8 vb1 = *(const bf16x8*)&Vs_[(ns * 16 + lr) * 64 + ch1]; \
        YACC[ns] = __builtin_amdgcn_mfma_f32_16x16x32_bf16(pa0, vb0, YACC[ns], 0, 0, 0); \
        YACC[ns] = __builtin_amdgcn_mfma_f32_16x16x32_bf16(pa1, vb1, YACC[ns], 0, 0, 0); \
    } \
} while (0)

    STGKV(0, 0);                     // step 0 (tile A, j0 = 0)
    STGKV(1, JOF(1));                // step 1
    asm volatile("s_waitcnt vmcnt(4)" ::: "memory");   // step0's 4 loads landed
    __builtin_amdgcn_s_barrier();
    __builtin_amdgcn_sched_barrier(0);

    for (int s = 0; s < NS; ++s) {
        if (s <= xtA) { PV_STEP((s & 1), 64 * s, iwA, qaA0, qaA1, yaccA); }
        else          { PV_STEP((s & 1), 64 * (s - xtA - 1), iwB, qaB0, qaB1, yaccB); }
        __builtin_amdgcn_s_barrier();          // all waves done reading buf[s&1]
        __builtin_amdgcn_sched_barrier(0);
        if (s + 2 < NS) STGKV((s & 1), JOF(s + 2));
        if (s + 1 < NS) {
            if (s + 2 < NS) { asm volatile("s_waitcnt vmcnt(4)" ::: "memory"); }
            else            { asm volatile("s_waitcnt vmcnt(0)" ::: "memory"); }
            __builtin_amdgcn_s_barrier();      // all waves' step s+1 landed
            __builtin_amdgcn_sched_barrier(0);
        }
    }
#undef STGKV
#undef PV_STEP
#undef JOF

    #pragma unroll
    for (int ns = 0; ns < 4; ++ns)
        #pragma unroll
        for (int r = 0; r < 4; ++r) {
            int l2 = iwA + lg * 4 + r;
            Y[((size_t)bidx * Ll + l2) * Cc + h * Dd + ns * 16 + lr] = f2b(yaccA[ns][r]);
        }
    #pragma unroll
    for (int ns = 0; ns < 4; ++ns)
        #pragma unroll
        for (int r = 0; r < 4; ++r) {
            int l2 = iwB + lg * 4 + r;
            Y[((size_t)bidx * Ll + l2) * Cc + h * Dd + ns * 16 + lr] = f2b(yaccB[ns][r]);
        }
}

extern "C" void kernel_launch(void* const* d_in, const int* in_sizes, int n_in,
                              void* d_out, int out_size, void* d_ws, size_t ws_size,
                              hipStream_t stream)
{
    const float* x     = (const float*)d_in[0];
    const float* Wqkv  = (const float*)d_in[1];
    const float* bqkv  = (const float*)d_in[2];
    const float* Wproj = (const float*)d_in[3];
    const float* bproj = (const float*)d_in[4];
    float* out = (float*)d_out;

    char* ws = (char*)d_ws;
    u16* xb     = (u16*)(ws + 0);            // x as bf16, 8192x1024         (16 MB)
    u16* WqkvT  = (u16*)(ws + 16777216);     // W_qkv^T bf16, 3072x1024      (6 MB)
    u16* WprojT = (u16*)(ws + 23068672);     // W_proj^T bf16, 1024x1024     (2 MB)
    u16* q      = (u16*)(ws + 25165824);     // (B,H,L,D) bf16, pre-scaled   (16 MB)
    u16* k      = (u16*)(ws + 41943040);     // (B,H,L,D) bf16               (16 MB)
    u16* v      = (u16*)(ws + 58720256);     // (B,H,L,D) bf16; reused as Y  (16 MB)
    u16* vt     = (u16*)(ws + 75497472);     // (B,H,D,L) bf16, zinv-scaled  (16 MB)

    k_prep<<<dim3(2048 + 4096), dim3(256), 0, stream>>>(x, xb, Wqkv, WqkvT, Wproj, WprojT);
    k_gemm_qkv32<<<dim3(N3 / 128, Mrows / 128), dim3(256), 0, stream>>>(
        xb, WqkvT, bqkv, q, k, v);
    k_attn_colsum_vt<<<dim3(1024), dim3(256), 0, stream>>>(q, k, v, vt);
    k_attn_pv<<<dim3(1024), dim3(256), 0, stream>>>(q, k, vt, v);
    k_gemm_proj32<<<dim3(Cc / 128, Mrows / 128), dim3(256), 0, stream>>>(
        v, WprojT, bproj, out);
}

// Round 20
// 174.730 us; speedup vs baseline: 1.5761x; 1.0013x over previous
//
#include <hip/hip_runtime.h>

typedef unsigned short u16;
typedef unsigned int   u32;
using bf16x8 = __attribute__((ext_vector_type(8))) short;
using f32x4  = __attribute__((ext_vector_type(4))) float;
using f32x16 = __attribute__((ext_vector_type(16))) float;
using u32x4  = __attribute__((ext_vector_type(4))) u32;

static constexpr int Bb = 8, Ll = 1024, Cc = 1024, Hh = 16, Dd = 64;
static constexpr int Mrows = Bb * Ll;   // 8192
static constexpr int N3    = 3 * Cc;    // 3072
// exp(S/8) = 2^(S * 0.125*log2(e)); fold into q at the QKV epilogue
static constexpr float QSCALE = 0.125f * 1.44269504088896f;

__device__ __forceinline__ u16 f2b(float f) {  // fp32 -> bf16 RNE
    u32 u = __builtin_bit_cast(u32, f);
    u += 0x7FFFu + ((u >> 16) & 1u);
    return (u16)(u >> 16);
}
__device__ __forceinline__ float b2f(u16 u) {
    return __builtin_bit_cast(float, (u32)u << 16);
}
__device__ __forceinline__ u32 pack2bf(float a, float b) {
    return (u32)f2b(a) | ((u32)f2b(b) << 16);
}
// async global->LDS, 16B/lane; LDS dest is wave-uniform base (lane*16 HW-added)
__device__ __forceinline__ void gload16(const u16* g, u16* l) {
    __builtin_amdgcn_global_load_lds(
        (const __attribute__((address_space(1))) void*)g,
        (__attribute__((address_space(3))) void*)l, 16, 0, 0);
}

// ==== fused prep: x fp32->bf16 convert (blocks 0..2047) + weight transposes ====
// convert: 16 elems/thread. transpose: W_qkv (1024x3072) and W_proj (1024x1024),
// flattened 256-thread indexing (tx=tid&31, ty=tid>>5), same tiles as before.
__global__ void k_prep(const float* __restrict__ x, u16* __restrict__ xb,
                       const float* __restrict__ Wqkv, u16* __restrict__ WqkvT,
                       const float* __restrict__ Wproj, u16* __restrict__ WprojT)
{
    __shared__ float tile[32][33];
    int bid = blockIdx.x;
    int tid = threadIdx.x;
    if (bid < 2048) {                      // ---- convert branch ----
        int idx = bid * 256 + tid;
        #pragma unroll
        for (int h = 0; h < 2; ++h) {
            f32x4 v0 = *((const f32x4*)x + idx * 4 + h * 2);
            f32x4 v1 = *((const f32x4*)x + idx * 4 + h * 2 + 1);
            u32x4 o;
            o[0] = pack2bf(v0[0], v0[1]);
            o[1] = pack2bf(v0[2], v0[3]);
            o[2] = pack2bf(v1[0], v1[1]);
            o[3] = pack2bf(v1[2], v1[3]);
            *((u32x4*)xb + idx * 2 + h) = o;
        }
        return;
    }
    // ---- weight transpose branch ----
    int bz = bid - 2048;                   // 0..4095
    int bx = bz & 127;                     // 0..127 (96 qkv + 32 proj)
    int by = bz >> 7;                      // 0..31
    const float* in; u16* out; int Cn;
    if (bx < 96) { in = Wqkv;  out = WqkvT;  Cn = N3; }
    else         { in = Wproj; out = WprojT; Cn = Cc; bx -= 96; }
    const int R = Cc;
    int tx = tid & 31, ty = tid >> 5;
    int c = bx * 32 + tx;
    int rbase = by * 32;
    #pragma unroll
    for (int rr = 0; rr < 4; ++rr)
        tile[ty + rr * 8][tx] = in[(size_t)(rbase + ty + rr * 8) * Cn + c];
    __syncthreads();
    int ro = bx * 32 + ty;
    #pragma unroll
    for (int rr = 0; rr < 4; ++rr)
        out[(size_t)(ro + rr * 8) * R + rbase + tx] = f2b(tile[tx][ty + rr * 8]);
}

// ======== QKV GEMM v3: 32x32x16 MFMA, 128^2 tile, BK=64, dbuf, 2 blocks/CU ========
// R10-proven (took QKV out of the top-5). DO NOT PERTURB.
__global__ __launch_bounds__(256, 2)
void k_gemm_qkv32(const u16* __restrict__ A, const u16* __restrict__ Bt,
                  const float* __restrict__ bias,
                  u16* __restrict__ qo, u16* __restrict__ ko, u16* __restrict__ vo)
{
    const int K = Cc;            // 1024
    const int NT = K / 64;       // 16 K-tiles
    __shared__ u16 As[2][128 * 64];
    __shared__ u16 Bs[2][128 * 64];
    const int tid = threadIdx.x;
    const int wid = tid >> 6, lane = tid & 63;
    const int l31 = lane & 31, lhi = lane >> 5, l7 = lane & 7;
    const int wr = wid >> 1, wc = wid & 1;       // 2x2 waves, 64x64 each
    const int nwg = gridDim.x * gridDim.y;       // 1536, %8==0
    const int flat = blockIdx.y * gridDim.x + blockIdx.x;
    const int swz = (flat & 7) * (nwg >> 3) + (flat >> 3);
    const int bx = swz % gridDim.x, by = swz / gridDim.x;
    const int row0 = by * 128, col0 = bx * 128;

    const int srow = tid >> 3;
    const int schunk = (tid & 7) ^ (srow & 7);
    const u16* gA = A  + (size_t)(row0 + srow) * K + schunk * 8;
    const u16* gB = Bt + (size_t)(col0 + srow) * K + schunk * 8;

#define STG(buf, t) do { \
    const u16* ga_ = gA + (size_t)(t) * 64; \
    const u16* gb_ = gB + (size_t)(t) * 64; \
    u16* la_ = &As[buf][wid * 512]; \
    u16* lb_ = &Bs[buf][wid * 512]; \
    gload16(ga_,                  la_); \
    gload16(ga_ + (size_t)32 * K, la_ + 2048); \
    gload16(ga_ + (size_t)64 * K, la_ + 4096); \
    gload16(ga_ + (size_t)96 * K, la_ + 6144); \
    gload16(gb_,                  lb_); \
    gload16(gb_ + (size_t)32 * K, lb_ + 2048); \
    gload16(gb_ + (size_t)64 * K, lb_ + 4096); \
    gload16(gb_ + (size_t)96 * K, lb_ + 6144); \
} while (0)

    const int coff0 = (((0 + lhi) ^ l7) << 3);
    const int coff1 = (((2 + lhi) ^ l7) << 3);
    const int coff2 = (((4 + lhi) ^ l7) << 3);
    const int coff3 = (((6 + lhi) ^ l7) << 3);
    const int coff[4] = { coff0, coff1, coff2, coff3 };

    f32x16 acc[2][2] = {};

    STG(0, 0);
    STG(1, 1);
    asm volatile("s_waitcnt vmcnt(8)" ::: "memory");   // tile0's 8 loads landed
    __builtin_amdgcn_s_barrier();
    __builtin_amdgcn_sched_barrier(0);

    for (int t = 0; t < NT; ++t) {
        const u16* cA = &As[t & 1][0];
        const u16* cB = &Bs[t & 1][0];
        // ---- phase 0: A frags (held) + B tn=0, 8 MFMA ----
        bf16x8 af[2][4], bf0[4];
        #pragma unroll
        for (int tm = 0; tm < 2; ++tm)
            #pragma unroll
            for (int kc = 0; kc < 4; ++kc)
                af[tm][kc] = *(const bf16x8*)&cA[(wr * 64 + tm * 32 + l31) * 64 + coff[kc]];
        #pragma unroll
        for (int kc = 0; kc < 4; ++kc)
            bf0[kc] = *(const bf16x8*)&cB[(wc * 64 + l31) * 64 + coff[kc]];
        __builtin_amdgcn_s_setprio(1);
        #pragma unroll
        for (int tm = 0; tm < 2; ++tm)
            #pragma unroll
            for (int kc = 0; kc < 4; ++kc)
                acc[tm][0] = __builtin_amdgcn_mfma_f32_32x32x16_bf16(
                    af[tm][kc], bf0[kc], acc[tm][0], 0, 0, 0);
        __builtin_amdgcn_s_setprio(0);
        __builtin_amdgcn_s_barrier();
        // ---- phase 1: B tn=1, 8 MFMA ----
        bf16x8 bf1[4];
        #pragma unroll
        for (int kc = 0; kc < 4; ++kc)
            bf1[kc] = *(const bf16x8*)&cB[(wc * 64 + 32 + l31) * 64 + coff[kc]];
        __builtin_amdgcn_s_setprio(1);
        #pragma unroll
        for (int tm = 0; tm < 2; ++tm)
            #pragma unroll
            for (int kc = 0; kc < 4; ++kc)
                acc[tm][1] = __builtin_amdgcn_mfma_f32_32x32x16_bf16(
                    af[tm][kc], bf1[kc], acc[tm][1], 0, 0, 0);
        __builtin_amdgcn_s_setprio(0);
        __builtin_amdgcn_s_barrier();          // all waves done reading buf[t&1]
        __builtin_amdgcn_sched_barrier(0);
        if (t + 2 < NT) STG(t & 1, t + 2);
        if (t + 1 < NT) {
            if (t + 2 < NT) { asm volatile("s_waitcnt vmcnt(8)" ::: "memory"); }
            else            { asm volatile("s_waitcnt vmcnt(0)" ::: "memory"); }
            __builtin_amdgcn_s_barrier();      // all waves' t+1 landed
            __builtin_amdgcn_sched_barrier(0);
        }
    }
#undef STG

    // epilogue: q/k/v scatter to (B,H,L,D); 32x32 C/D layout
    #pragma unroll
    for (int tm = 0; tm < 2; ++tm) {
        #pragma unroll
        for (int tn = 0; tn < 2; ++tn) {
            int cg = col0 + wc * 64 + tn * 32 + l31;
            float bv = bias[cg];
            int which = cg >> 10;         // 0=q 1=k 2=v
            float sc = (which == 0) ? QSCALE : 1.0f;
            int cc2 = cg & 1023;
            int h = cc2 >> 6, dd = cc2 & 63;
            int rbase = row0 + wr * 64 + tm * 32 + 4 * lhi;
            #pragma unroll
            for (int g = 0; g < 4; ++g) {
                #pragma unroll
                for (int r = 0; r < 4; ++r) {
                    int rg = rbase + 8 * g + r;
                    int bidx = rg >> 10, ll2 = rg & 1023;
                    size_t o = ((size_t)(bidx * Hh + h) * Ll + ll2) * Dd + dd;
                    u16 val = f2b((acc[tm][tn][g * 4 + r] + bv) * sc);
                    if (which == 0) qo[o] = val;
                    else if (which == 1) ko[o] = val;
                    else vo[o] = val;
                }
            }
        }
    }
}

// ======== proj GEMM v2: qkv32 skeleton (32x32x16, BK=64, dbuf). R18-proven. ========
__global__ __launch_bounds__(256, 2)
void k_gemm_proj32(const u16* __restrict__ A, const u16* __restrict__ Bt,
                   const float* __restrict__ bias, float* __restrict__ outf)
{
    const int K = Cc;            // 1024
    const int N = Cc;
    const int NT = K / 64;       // 16 K-tiles
    __shared__ u16 As[2][128 * 64];
    __shared__ u16 Bs[2][128 * 64];
    const int tid = threadIdx.x;
    const int wid = tid >> 6, lane = tid & 63;
    const int l31 = lane & 31, lhi = lane >> 5, l7 = lane & 7;
    const int wr = wid >> 1, wc = wid & 1;       // 2x2 waves, 64x64 each
    const int nwg = gridDim.x * gridDim.y;       // 512, %8==0
    const int flat = blockIdx.y * gridDim.x + blockIdx.x;
    const int swz = (flat & 7) * (nwg >> 3) + (flat >> 3);
    const int bx = swz % gridDim.x, by = swz / gridDim.x;
    const int row0 = by * 128, col0 = bx * 128;

    const int srow = tid >> 3;
    const int schunk = (tid & 7) ^ (srow & 7);
    const u16* gA = A  + (size_t)(row0 + srow) * K + schunk * 8;
    const u16* gB = Bt + (size_t)(col0 + srow) * K + schunk * 8;

#define STG(buf, t) do { \
    const u16* ga_ = gA + (size_t)(t) * 64; \
    const u16* gb_ = gB + (size_t)(t) * 64; \
    u16* la_ = &As[buf][wid * 512]; \
    u16* lb_ = &Bs[buf][wid * 512]; \
    gload16(ga_,                  la_); \
    gload16(ga_ + (size_t)32 * K, la_ + 2048); \
    gload16(ga_ + (size_t)64 * K, la_ + 4096); \
    gload16(ga_ + (size_t)96 * K, la_ + 6144); \
    gload16(gb_,                  lb_); \
    gload16(gb_ + (size_t)32 * K, lb_ + 2048); \
    gload16(gb_ + (size_t)64 * K, lb_ + 4096); \
    gload16(gb_ + (size_t)96 * K, lb_ + 6144); \
} while (0)

    const int coff0 = (((0 + lhi) ^ l7) << 3);
    const int coff1 = (((2 + lhi) ^ l7) << 3);
    const int coff2 = (((4 + lhi) ^ l7) << 3);
    const int coff3 = (((6 + lhi) ^ l7) << 3);
    const int coff[4] = { coff0, coff1, coff2, coff3 };

    f32x16 acc[2][2] = {};

    STG(0, 0);
    STG(1, 1);
    asm volatile("s_waitcnt vmcnt(8)" ::: "memory");
    __builtin_amdgcn_s_barrier();
    __builtin_amdgcn_sched_barrier(0);

    for (int t = 0; t < NT; ++t) {
        const u16* cA = &As[t & 1][0];
        const u16* cB = &Bs[t & 1][0];
        bf16x8 af[2][4], bf0[4];
        #pragma unroll
        for (int tm = 0; tm < 2; ++tm)
            #pragma unroll
            for (int kc = 0; kc < 4; ++kc)
                af[tm][kc] = *(const bf16x8*)&cA[(wr * 64 + tm * 32 + l31) * 64 + coff[kc]];
        #pragma unroll
        for (int kc = 0; kc < 4; ++kc)
            bf0[kc] = *(const bf16x8*)&cB[(wc * 64 + l31) * 64 + coff[kc]];
        __builtin_amdgcn_s_setprio(1);
        #pragma unroll
        for (int tm = 0; tm < 2; ++tm)
            #pragma unroll
            for (int kc = 0; kc < 4; ++kc)
                acc[tm][0] = __builtin_amdgcn_mfma_f32_32x32x16_bf16(
                    af[tm][kc], bf0[kc], acc[tm][0], 0, 0, 0);
        __builtin_amdgcn_s_setprio(0);
        __builtin_amdgcn_s_barrier();
        bf16x8 bf1[4];
        #pragma unroll
        for (int kc = 0; kc < 4; ++kc)
            bf1[kc] = *(const bf16x8*)&cB[(wc * 64 + 32 + l31) * 64 + coff[kc]];
        __builtin_amdgcn_s_setprio(1);
        #pragma unroll
        for (int tm = 0; tm < 2; ++tm)
            #pragma unroll
            for (int kc = 0; kc < 4; ++kc)
                acc[tm][1] = __builtin_amdgcn_mfma_f32_32x32x16_bf16(
                    af[tm][kc], bf1[kc], acc[tm][1], 0, 0, 0);
        __builtin_amdgcn_s_setprio(0);
        __builtin_amdgcn_s_barrier();
        __builtin_amdgcn_sched_barrier(0);
        if (t + 2 < NT) STG(t & 1, t + 2);
        if (t + 1 < NT) {
            if (t + 2 < NT) { asm volatile("s_waitcnt vmcnt(8)" ::: "memory"); }
            else            { asm volatile("s_waitcnt vmcnt(0)" ::: "memory"); }
            __builtin_amdgcn_s_barrier();
            __builtin_amdgcn_sched_barrier(0);
        }
    }
#undef STG

    // epilogue: fp32 out (M x N) with bias; 32x32 C/D layout, coalesced over l31
    #pragma unroll
    for (int tm = 0; tm < 2; ++tm) {
        #pragma unroll
        for (int tn = 0; tn < 2; ++tn) {
            int cg = col0 + wc * 64 + tn * 32 + l31;
            float bv = bias[cg];
            int rbase = row0 + wr * 64 + tm * 32 + 4 * lhi;
            #pragma unroll
            for (int g = 0; g < 4; ++g) {
                #pragma unroll
                for (int r = 0; r < 4; ++r) {
                    int rg = rbase + 8 * g + r;
                    outf[(size_t)rg * N + cg] = acc[tm][tn][g * 4 + r] + bv;
                }
            }
        }
    }
}

// ---- attention pass 1 + vt: column sums (LDS-staged Q pipeline, R17-proven)
// fused with the v->vt transpose+zinv-scale epilogue. A block computes z for
// col tiles (xtA, xtB) of one bh, then transposes exactly those 64-row slices
// of v into vt (bh,D,L) scaled by 1/z, reusing Qs as scratch. Kills the
// separate k_transpose_scale kernel + its launch gap + the zinv round-trip.
__global__ __launch_bounds__(256, 4)
void k_attn_colsum_vt(const u16* __restrict__ Q, const u16* __restrict__ Kb,
                      const u16* __restrict__ V, u16* __restrict__ vt)
{
    __shared__ u16 Qs[2][64 * 64];
    __shared__ float zlds[2][64];
    const int tid = threadIdx.x;
    const int wid = tid >> 6, lane = tid & 63;
    const int lr = lane & 15, lg = lane >> 4;
    const int l7 = lr & 7;
    const int fid = blockIdx.x;
    const int xcd = fid & 7, n = fid >> 3;
    const int xtA = n & 7;                   // col tile A (0..7)
    const int xtB = 15 - xtA;                // paired tile B (8..15)
    const int bh = (xcd << 4) | (n >> 3);
    const u16* Qp = Q  + (size_t)bh * Ll * Dd;
    const u16* Kp = Kb + (size_t)bh * Ll * Dd;
    const int jwA = xtA * 64 + wid * 16;
    const int jwB = xtB * 64 + wid * 16;
    bf16x8 kbA0 = *(const bf16x8*)&Kp[(jwA + lr) * Dd + lg * 8];
    bf16x8 kbA1 = *(const bf16x8*)&Kp[(jwA + lr) * Dd + 32 + lg * 8];
    bf16x8 kbB0 = *(const bf16x8*)&Kp[(jwB + lr) * Dd + lg * 8];
    bf16x8 kbB1 = *(const bf16x8*)&Kp[(jwB + lr) * Dd + 32 + lg * 8];
    const bool dmask[4] = { lg * 4 + 0 >= lr, lg * 4 + 1 >= lr,
                            lg * 4 + 2 >= lr, lg * 4 + 3 >= lr };
    const int ch0 = ((lg ^ l7) << 3);
    const int ch1 = (((4 + lg) ^ l7) << 3);
    const int srow = tid >> 3;               // 0..31
    const int schunk = (tid & 7) ^ (srow & 7);
    float zA = 0.f, zB = 0.f;

    const int nA = 16 - xtA;
    const int NS = 17;
#define IOF(s) (((s) < nA) ? (xtA * 64 + 64 * (s)) : (xtB * 64 + 64 * ((s) - nA)))

#define STGQ(buf, I0) do { \
    const u16* g_ = Qp + (size_t)((I0) + srow) * 64 + schunk * 8; \
    u16* l_ = &Qs[buf][wid * 512]; \
    gload16(g_,                   l_); \
    gload16(g_ + (size_t)32 * 64, l_ + 2048); \
} while (0)

#define CS_STEP(buf, I0, JW, KB0, KB1, ZACC) do { \
    const u16* Qs_ = &Qs[buf][0]; \
    _Pragma("unroll") \
    for (int ss = 0; ss < 4; ++ss) { \
        int ib = (I0) + ss * 16; \
        if (ib >= (JW)) { \
            bf16x8 qa0 = *(const bf16x8*)&Qs_[(ss * 16 + lr) * 64 + ch0]; \
            bf16x8 qa1 = *(const bf16x8*)&Qs_[(ss * 16 + lr) * 64 + ch1]; \
            f32x4 s_ = {0.f, 0.f, 0.f, 0.f}; \
            s_ = __builtin_amdgcn_mfma_f32_16x16x32_bf16(qa0, KB0, s_, 0, 0, 0); \
            s_ = __builtin_amdgcn_mfma_f32_16x16x32_bf16(qa1, KB1, s_, 0, 0, 0); \
            if (ib >= (JW) + 16) { \
                _Pragma("unroll") \
                for (int r = 0; r < 4; ++r) ZACC += exp2f(s_[r]); \
            } else { \
                _Pragma("unroll") \
                for (int r = 0; r < 4; ++r) ZACC += dmask[r] ? exp2f(s_[r]) : 0.f; \
            } \
        } \
    } \
} while (0)

    STGQ(0, IOF(0));
    STGQ(1, IOF(1));
    asm volatile("s_waitcnt vmcnt(2)" ::: "memory");
    __builtin_amdgcn_s_barrier();
    __builtin_amdgcn_sched_barrier(0);

    for (int s = 0; s < NS; ++s) {
        if (s < nA) { CS_STEP((s & 1), xtA * 64 + 64 * s, jwA, kbA0, kbA1, zA); }
        else        { CS_STEP((s & 1), xtB * 64 + 64 * (s - nA), jwB, kbB0, kbB1, zB); }
        __builtin_amdgcn_s_barrier();
        __builtin_amdgcn_sched_barrier(0);
        if (s + 2 < NS) STGQ((s & 1), IOF(s + 2));
        if (s + 1 < NS) {
            if (s + 2 < NS) { asm volatile("s_waitcnt vmcnt(2)" ::: "memory"); }
            else            { asm volatile("s_waitcnt vmcnt(0)" ::: "memory"); }
            __builtin_amdgcn_s_barrier();
            __builtin_amdgcn_sched_barrier(0);
        }
    }
#undef STGQ
#undef CS_STEP
#undef IOF

    zA += __shfl_xor(zA, 16); zA += __shfl_xor(zA, 32);
    zB += __shfl_xor(zB, 16); zB += __shfl_xor(zB, 32);
    if (lg == 0) {
        zlds[0][wid * 16 + lr] = 1.f / zA;   // cols xtA*64 .. +64 across 4 waves
        zlds[1][wid * 16 + lr] = 1.f / zB;
    }

    // ---- fused epilogue: transpose v[bh][jw0..jw0+64][0..64] -> vt (bh,D,L) * zinv ----
    // scratch: reuse Qs (64 rows x stride 72, 16B-aligned rows)
    u16* sc = &Qs[0][0];
    const u16* Vr = V + (size_t)bh * Ll * Dd;        // (L, D) row-major
    const int lrow = tid >> 2;                        // 0..63
    const int seg  = (tid & 3) << 4;                  // 0,16,32,48
    #pragma unroll
    for (int t = 0; t < 2; ++t) {
        const int jw0 = (t ? xtB : xtA) * 64;
        u32x4 h0 = *(const u32x4*)&Vr[(size_t)(jw0 + lrow) * Dd + seg];
        u32x4 h1 = *(const u32x4*)&Vr[(size_t)(jw0 + lrow) * Dd + seg + 8];
        __syncthreads();                 // pipeline reads / prev iter reads done
        *(u32x4*)&sc[lrow * 72 + seg]     = h0;
        *(u32x4*)&sc[lrow * 72 + seg + 8] = h1;
        __syncthreads();                 // tile + zlds visible
        // write: d = lrow, 16 contiguous l at jw0+seg
        u16 obuf[16];
        #pragma unroll
        for (int j = 0; j < 16; ++j) {
            float zv = zlds[t][seg + j];
            obuf[j] = f2b(b2f(sc[(seg + j) * 72 + lrow]) * zv);
        }
        u16* dst = vt + ((size_t)bh * Dd + lrow) * Ll + jw0 + seg;
        *(u32x4*)dst       = *(u32x4*)&obuf[0];
        *(u32x4*)(dst + 8) = *(u32x4*)&obuf[8];
    }
}

// ---------------- attention pass 2: Y = exp(S') @ V'  (LDS-staged K/V pipeline) ----------------
// R16-proven (pv left the top-5). DO NOT PERTURB.
__global__ __launch_bounds__(256, 4)
void k_attn_pv(const u16* __restrict__ Q, const u16* __restrict__ Kb,
               const u16* __restrict__ Vt, u16* __restrict__ Y)
{
    __shared__ u16 Ks[2][64 * 64];
    __shared__ u16 Vs[2][64 * 64];
    const int tid = threadIdx.x;
    const int wid = tid >> 6, lane = tid & 63;
    const int lr = lane & 15, lg = lane >> 4;
    const int l7 = lr & 7;
    const int fid = blockIdx.x;
    const int xcd = fid & 7, n = fid >> 3;
    const int xtA = n & 7;                   // tile A index (0..7)
    const int xtB = 15 - xtA;                // paired tile B (8..15)
    const int bh = (xcd << 4) | (n >> 3);
    const int bidx = bh >> 4, h = bh & 15;
    const u16* Qp = Q  + (size_t)bh * Ll * Dd;
    const u16* Kp = Kb + (size_t)bh * Ll * Dd;
    const u16* Vp = Vt + (size_t)bh * Ll * Dd;     // (Dd, Ll) layout, zinv-scaled
    const int src0 = lr + 32 * (lg & 1);
    const int src1 = src0 + 16;
    const bool selHi = (lg & 2) != 0;
    const int ch0 = ((lg ^ l7) << 3);
    const int ch1 = (((4 + lg) ^ l7) << 3);
    const int srow = tid >> 3;               // 0..31
    const int schunk = (tid & 7) ^ (srow & 7);

    const int iwA = xtA * 64 + wid * 16;
    const int iwB = xtB * 64 + wid * 16;
    bf16x8 qaA0 = *(const bf16x8*)&Qp[(iwA + lr) * Dd + lg * 8];
    bf16x8 qaA1 = *(const bf16x8*)&Qp[(iwA + lr) * Dd + 32 + lg * 8];
    bf16x8 qaB0 = *(const bf16x8*)&Qp[(iwB + lr) * Dd + lg * 8];
    bf16x8 qaB1 = *(const bf16x8*)&Qp[(iwB + lr) * Dd + 32 + lg * 8];
    f32x4 yaccA[4] = {};
    f32x4 yaccB[4] = {};

    const int NS = 17;                       // (xtA+1) + (xtB+1) = 17 steps, uniform
#define JOF(s) (((s) <= xtA) ? 64 * (s) : 64 * ((s) - xtA - 1))

#define STGKV(buf, J) do { \
    const u16* gk_ = Kp + (size_t)((J) + srow) * 64 + schunk * 8; \
    const u16* gv_ = Vp + (size_t)srow * Ll + (J) + schunk * 8; \
    u16* lk_ = &Ks[buf][wid * 512]; \
    u16* lv_ = &Vs[buf][wid * 512]; \
    gload16(gk_,                   lk_); \
    gload16(gk_ + (size_t)32 * 64, lk_ + 2048); \
    gload16(gv_,                   lv_); \
    gload16(gv_ + (size_t)32 * Ll, lv_ + 2048); \
} while (0)

#define PV_STEP(buf, J0, IW, QA0, QA1, YACC) do { \
    const u16* Ks_ = &Ks[buf][0]; \
    const u16* Vs_ = &Vs[buf][0]; \
    uint2 w0, w1, w2, w3; \
    _Pragma("unroll") \
    for (int cs = 0; cs < 4; ++cs) { \
        bf16x8 kb0 = *(const bf16x8*)&Ks_[(cs * 16 + lr) * 64 + ch0]; \
        bf16x8 kb1 = *(const bf16x8*)&Ks_[(cs * 16 + lr) * 64 + ch1]; \
        f32x4 s_ = {0.f, 0.f, 0.f, 0.f}; \
        s_ = __builtin_amdgcn_mfma_f32_16x16x32_bf16(kb0, QA0, s_, 0, 0, 0); \
        s_ = __builtin_amdgcn_mfma_f32_16x16x32_bf16(kb1, QA1, s_, 0, 0, 0); \
        int jb = (J0) + cs * 16; \
        float p[4]; \
        if (jb + 15 <= (IW)) { \
            _Pragma("unroll") \
            for (int r = 0; r < 4; ++r) p[r] = exp2f(s_[r]); \
        } else { \
            int ig = (IW) + lr; \
            _Pragma("unroll") \
            for (int r = 0; r < 4; ++r) \
                p[r] = (jb + 4 * lg + r <= ig) ? exp2f(s_[r]) : 0.f; \
        } \
        uint2 w_; \
        w_.x = pack2bf(p[0], p[1]); \
        w_.y = pack2bf(p[2], p[3]); \
        if (cs == 0) w0 = w_; else if (cs == 1) w1 = w_; \
        else if (cs == 2) w2 = w_; else w3 = w_; \
    } \
    u32 a00 = (u32)__shfl((int)w0.x, src0), a01 = (u32)__shfl((int)w0.y, src0); \
    u32 a02 = (u32)__shfl((int)w0.x, src1), a03 = (u32)__shfl((int)w0.y, src1); \
    u32 a10 = (u32)__shfl((int)w1.x, src0), a11 = (u32)__shfl((int)w1.y, src0); \
    u32 a12 = (u32)__shfl((int)w1.x, src1), a13 = (u32)__shfl((int)w1.y, src1); \
    u32 a20 = (u32)__shfl((int)w2.x, src0), a21 = (u32)__shfl((int)w2.y, src0); \
    u32 a22 = (u32)__shfl((int)w2.x, src1), a23 = (u32)__shfl((int)w2.y, src1); \
    u32 a30 = (u32)__shfl((int)w3.x, src0), a31 = (u32)__shfl((int)w3.y, src0); \
    u32 a32 = (u32)__shfl((int)w3.x, src1), a33 = (u32)__shfl((int)w3.y, src1); \
    u32x4 pa0u, pa1u; \
    pa0u[0] = selHi ? a10 : a00;  pa0u[1] = selHi ? a11 : a01; \
    pa0u[2] = selHi ? a12 : a02;  pa0u[3] = selHi ? a13 : a03; \
    pa1u[0] = selHi ? a30 : a20;  pa1u[1] = selHi ? a31 : a21; \
    pa1u[2] = selHi ? a32 : a22;  pa1u[3] = selHi ? a33 : a23; \
    bf16x8 pa0 = __builtin_bit_cast(bf16x8, pa0u); \
    bf16x8 pa1 = __builtin_bit_cast(bf16x8, pa1u); \
    _Pragma("unroll") \
    for (int ns = 0; ns < 4; ++ns) { \
        bf16x8 vb0 = *(const bf16x8*)&Vs_[(ns * 16 + lr) * 64 + ch0]; \
        bf16x8 vb1 = *(const bf16x8*)&Vs_[(ns * 16 + lr) * 64 + ch1]; \
        YACC[ns] = __builtin_amdgcn_mfma_f32_16x16x32_bf16(pa0, vb0, YACC[ns], 0, 0, 0); \
        YACC[ns] = __builtin_amdgcn_mfma_f32_16x16x32_bf16(pa1, vb1, YACC[ns], 0, 0, 0); \
    } \
} while (0)

    STGKV(0, 0);                     // step 0 (tile A, j0 = 0)
    STGKV(1, JOF(1));                // step 1
    asm volatile("s_waitcnt vmcnt(4)" ::: "memory");   // step0's 4 loads landed
    __builtin_amdgcn_s_barrier();
    __builtin_amdgcn_sched_barrier(0);

    for (int s = 0; s < NS; ++s) {
        if (s <= xtA) { PV_STEP((s & 1), 64 * s, iwA, qaA0, qaA1, yaccA); }
        else          { PV_STEP((s & 1), 64 * (s - xtA - 1), iwB, qaB0, qaB1, yaccB); }
        __builtin_amdgcn_s_barrier();          // all waves done reading buf[s&1]
        __builtin_amdgcn_sched_barrier(0);
        if (s + 2 < NS) STGKV((s & 1), JOF(s + 2));
        if (s + 1 < NS) {
            if (s + 2 < NS) { asm volatile("s_waitcnt vmcnt(4)" ::: "memory"); }
            else            { asm volatile("s_waitcnt vmcnt(0)" ::: "memory"); }
            __builtin_amdgcn_s_barrier();      // all waves' step s+1 landed
            __builtin_amdgcn_sched_barrier(0);
        }
    }
#undef STGKV
#undef PV_STEP
#undef JOF

    #pragma unroll
    for (int ns = 0; ns < 4; ++ns)
        #pragma unroll
        for (int r = 0; r < 4; ++r) {
            int l2 = iwA + lg * 4 + r;
            Y[((size_t)bidx * Ll + l2) * Cc + h * Dd + ns * 16 + lr] = f2b(yaccA[ns][r]);
        }
    #pragma unroll
    for (int ns = 0; ns < 4; ++ns)
        #pragma unroll
        for (int r = 0; r < 4; ++r) {
            int l2 = iwB + lg * 4 + r;
            Y[((size_t)bidx * Ll + l2) * Cc + h * Dd + ns * 16 + lr] = f2b(yaccB[ns][r]);
        }
}

extern "C" void kernel_launch(void* const* d_in, const int* in_sizes, int n_in,
                              void* d_out, int out_size, void* d_ws, size_t ws_size,
                              hipStream_t stream)
{
    const float* x     = (const float*)d_in[0];
    const float* Wqkv  = (const float*)d_in[1];
    const float* bqkv  = (const float*)d_in[2];
    const float* Wproj = (const float*)d_in[3];
    const float* bproj = (const float*)d_in[4];
    float* out = (float*)d_out;

    char* ws = (char*)d_ws;
    u16* xb     = (u16*)(ws + 0);            // x as bf16, 8192x1024         (16 MB)
    u16* WqkvT  = (u16*)(ws + 16777216);     // W_qkv^T bf16, 3072x1024      (6 MB)
    u16* WprojT = (u16*)(ws + 23068672);     // W_proj^T bf16, 1024x1024     (2 MB)
    u16* q      = (u16*)(ws + 25165824);     // (B,H,L,D) bf16, pre-scaled   (16 MB)
    u16* k      = (u16*)(ws + 41943040);     // (B,H,L,D) bf16               (16 MB)
    u16* v      = (u16*)(ws + 58720256);     // (B,H,L,D) bf16; reused as Y  (16 MB)
    u16* vt     = (u16*)(ws + 75497472);     // (B,H,D,L) bf16, zinv-scaled  (16 MB)

    k_prep<<<dim3(2048 + 4096), dim3(256), 0, stream>>>(x, xb, Wqkv, WqkvT, Wproj, WprojT);
    k_gemm_qkv32<<<dim3(N3 / 128, Mrows / 128), dim3(256), 0, stream>>>(
        xb, WqkvT, bqkv, q, k, v);
    k_attn_colsum_vt<<<dim3(1024), dim3(256), 0, stream>>>(q, k, v, vt);
    k_attn_pv<<<dim3(1024), dim3(256), 0, stream>>>(q, k, vt, v);
    k_gemm_proj32<<<dim3(Cc / 128, Mrows / 128), dim3(256), 0, stream>>>(
        v, WprojT, bproj, out);
}